// Round 9
// baseline (265.407 us; speedup 1.0000x reference)
//
#include <hip/hip_runtime.h>
#include <hip/hip_bf16.h>

static constexpr int F = 128;
static constexpr int H = 128;
static constexpr int NPART = 128;   // partition blocks (contiguous edge chunks)

typedef __attribute__((ext_vector_type(8))) short short8;
typedef __attribute__((ext_vector_type(4))) float f32x4;

__device__ __forceinline__ unsigned short f2bf(float f) {
  union { float f; unsigned u; } a; a.f = f;
  unsigned r = a.u + 0x7FFF + ((a.u >> 16) & 1);
  return (unsigned short)(r >> 16);
}
__device__ __forceinline__ float bf2f(unsigned short h) {
  union { unsigned u; float f; } a; a.u = ((unsigned)h) << 16;
  return a.f;
}
__device__ __forceinline__ float bits2f(unsigned u) {
  union { unsigned u; float f; } a; a.u = u;
  return a.f;
}

// int64-vs-int32 edge_index detection (values < 2^17 -> int64 hi words all 0)
__device__ __forceinline__ int detect64(const void* eiv) {
  const unsigned* u = (const unsigned*)eiv;
  int is64 = 1;
  for (int i = 0; i < 64; ++i) is64 &= (u[2 * i + 1] == 0u);
  return is64;
}

__global__ void detect_dtype(const unsigned* __restrict__ ei, int* __restrict__ flag) {
  if (blockIdx.x == 0 && threadIdx.x == 0) {
    int is64 = 1;
    for (int i = 0; i < 64; ++i) {
      if (ei[2 * i + 1] != 0u) { is64 = 0; break; }
    }
    *flag = is64;
  }
}

__device__ __forceinline__ int load_idx(const void* eiv, int is64, long long pos) {
  return is64 ? (int)((const long long*)eiv)[pos] : ((const int*)eiv)[pos];
}

// ---------------------------------------------------------------------------
// Two-pass atomic-free partition into 64-node dst buckets.
// pack = (src << 6) | (dst & 63)
// ---------------------------------------------------------------------------
__global__ __launch_bounds__(512) void part_hist(const void* __restrict__ eiv,
                                                 int* __restrict__ cmat,
                                                 int E, int nbuck, int chunk) {
  __shared__ int h[2048];
  const int t = threadIdx.x, b = blockIdx.x;
  for (int i = t; i < nbuck; i += 512) h[i] = 0;
  __syncthreads();
  int is64 = detect64(eiv);
  int s = b * chunk, e = min(E, s + chunk);
  for (int i = s + t; i < e; i += 512) {
    int dst = load_idx(eiv, is64, (long long)E + i);
    atomicAdd(&h[dst >> 6], 1);
  }
  __syncthreads();
  for (int i = t; i < nbuck; i += 512) cmat[i * NPART + b] = h[i];
}

__global__ __launch_bounds__(256) void scan1(const int* __restrict__ in,
                                             int* __restrict__ outx,
                                             int* __restrict__ blocksum, int n) {
  __shared__ int sm[256];
  int idx = blockIdx.x * 256 + threadIdx.x;
  int v = (idx < n) ? in[idx] : 0;
  sm[threadIdx.x] = v;
  __syncthreads();
  #pragma unroll
  for (int off = 1; off < 256; off <<= 1) {
    int t = (threadIdx.x >= off) ? sm[threadIdx.x - off] : 0;
    __syncthreads();
    sm[threadIdx.x] += t;
    __syncthreads();
  }
  if (idx < n) outx[idx] = sm[threadIdx.x] - v;
  if (threadIdx.x == 255) blocksum[blockIdx.x] = sm[255];
}

__global__ __launch_bounds__(1024) void scan2big(const int* __restrict__ blocksum,
                                                 int* __restrict__ blockoff, int nb) {
  __shared__ int sm[1024];
  int t = threadIdx.x;
  int v = (t < nb) ? blocksum[t] : 0;
  sm[t] = v;
  __syncthreads();
  for (int off = 1; off < 1024; off <<= 1) {
    int u = (t >= off) ? sm[t - off] : 0;
    __syncthreads();
    sm[t] += u;
    __syncthreads();
  }
  if (t < nb) blockoff[t] = sm[t] - v;
}

// finalize partition scan: base matrix in place + bucket segment starts.
// Block 0 also zeroes colsum/colsq (256 contiguous floats).
__global__ __launch_bounds__(256) void scan3p(int* __restrict__ obuf,
                                              const int* __restrict__ blockoff,
                                              int* __restrict__ bbase,
                                              float* __restrict__ colzero,
                                              int L, int nbuck, int E) {
  if (blockIdx.x == 0) colzero[threadIdx.x] = 0.0f;
  int idx = blockIdx.x * 256 + threadIdx.x;
  if (idx >= L) return;
  int v = obuf[idx] + blockoff[idx >> 8];
  obuf[idx] = v;
  if ((idx & (NPART - 1)) == 0) bbase[idx / NPART] = v;
  if (idx == 0) bbase[nbuck] = E;
}

__global__ __launch_bounds__(512) void part_scatter(const void* __restrict__ eiv,
                                                    const int* __restrict__ base,
                                                    int* __restrict__ ebuf,
                                                    int E, int nbuck, int chunk) {
  __shared__ int cur[2048];
  const int t = threadIdx.x, b = blockIdx.x;
  for (int i = t; i < nbuck; i += 512) cur[i] = base[i * NPART + b];
  __syncthreads();
  int is64 = detect64(eiv);
  int s = b * chunk, e = min(E, s + chunk);
  for (int i = s + t; i < e; i += 512) {
    int src = load_idx(eiv, is64, i);
    int dst = load_idx(eiv, is64, (long long)E + i);
    int pos = atomicAdd(&cur[dst >> 6], 1);
    ebuf[pos] = (src << 6) | (dst & 63);
  }
}

// ---------------------------------------------------------------------------
// gather_half<LOWP>: one block per 32-node HALF-bucket (grid = 2*nbuck).
// LDS exact adjacency for our 32 nodes; Y gather with 4 nodes/wave
// (16 lanes x uint4 = one full 256B row per group), 8-deep unroll.
// Fused epilogue: v = P + agg; row-L2-norm (4 x shfl within 16-lane group);
// ReLU; store u; BN col stats.
// LOWP=true : P read bf16 (Pbf), u written bf16 (Ubf).
// LOWP=false: P read / u write f32 in pio (d_out).
// ---------------------------------------------------------------------------
#define GCAP 2048
template <bool LOWP>
__global__ __launch_bounds__(256) void gather_half(
    const unsigned short* __restrict__ Y, const int* __restrict__ ebuf,
    const int* __restrict__ bbase, float* __restrict__ pio,
    const unsigned short* __restrict__ Pbf, unsigned short* __restrict__ Ubf,
    float* __restrict__ colsum, float* __restrict__ colsq, int n) {
  __shared__ int lsrc[GCAP];
  __shared__ int hist[32];
  __shared__ int loff[32];
  __shared__ int cur[32];
  __shared__ float csm[128], cqm[128];

  const int t = threadIdx.x;
  const int blk = blockIdx.x;
  const int b = blk >> 1;
  const int hb = blk & 1;
  const int node0 = (b << 6) + (hb << 5);
  const int s = bbase[b], e = bbase[b + 1];

  if (t < 32) hist[t] = 0;
  if (t < 128) { csm[t] = 0.f; cqm[t] = 0.f; }
  __syncthreads();

  for (int i = s + t; i < e; i += 256) {
    int ln = (ebuf[i] & 63) - (hb << 5);
    if ((unsigned)ln < 32u) atomicAdd(&hist[ln], 1);
  }
  __syncthreads();
  if (t < 32) loff[t] = hist[t];
  __syncthreads();
  #pragma unroll
  for (int off = 1; off < 32; off <<= 1) {
    int u = (t >= off && t < 32) ? loff[t - off] : 0;
    __syncthreads();
    if (t < 32) loff[t] += u;
    __syncthreads();
  }
  if (t < 32) cur[t] = loff[t] - hist[t];   // exclusive start
  __syncthreads();
  const bool fast = (loff[31] <= GCAP);
  if (fast) {
    for (int i = s + t; i < e; i += 256) {
      int p = ebuf[i];
      int ln = (p & 63) - (hb << 5);
      if ((unsigned)ln < 32u) {
        int pos = atomicAdd(&cur[ln], 1);
        lsrc[pos] = p >> 6;
      }
    }
    __syncthreads();
  }

  const int lane = t & 63;
  const int w = t >> 6;        // wave 0..3
  const int g = lane >> 4;     // 16-lane group 0..3
  const int c8 = (lane & 15) * 8;

  float lcs[8], lcq[8];
  #pragma unroll
  for (int q = 0; q < 8; ++q) { lcs[q] = 0.f; lcq[q] = 0.f; }

  #pragma unroll
  for (int it = 0; it < 2; ++it) {
    int ln = it * 16 + w * 4 + g;
    int node = node0 + ln;
    if (node >= n) continue;

    float a[8];
    #pragma unroll
    for (int q = 0; q < 8; ++q) a[q] = 0.f;
    float deg = 0.0f;

    if (fast) {
      int ls = loff[ln] - hist[ln];
      int le = loff[ln];
      deg = (float)(le - ls);
      float acc[8][8];
      #pragma unroll
      for (int u = 0; u < 8; ++u)
        #pragma unroll
        for (int q = 0; q < 8; ++q) acc[u][q] = 0.f;

      int j = ls;
      for (; j + 7 < le; j += 8) {
        #pragma unroll
        for (int u = 0; u < 8; ++u) {
          int sj = lsrc[j + u];
          uint4 uv = *(const uint4*)(Y + (size_t)sj * H + c8);
          acc[u][0] += bits2f(uv.x << 16);
          acc[u][1] += bits2f(uv.x & 0xFFFF0000u);
          acc[u][2] += bits2f(uv.y << 16);
          acc[u][3] += bits2f(uv.y & 0xFFFF0000u);
          acc[u][4] += bits2f(uv.z << 16);
          acc[u][5] += bits2f(uv.z & 0xFFFF0000u);
          acc[u][6] += bits2f(uv.w << 16);
          acc[u][7] += bits2f(uv.w & 0xFFFF0000u);
        }
      }
      for (; j + 1 < le; j += 2) {
        #pragma unroll
        for (int u = 0; u < 2; ++u) {
          int sj = lsrc[j + u];
          uint4 uv = *(const uint4*)(Y + (size_t)sj * H + c8);
          acc[u][0] += bits2f(uv.x << 16);
          acc[u][1] += bits2f(uv.x & 0xFFFF0000u);
          acc[u][2] += bits2f(uv.y << 16);
          acc[u][3] += bits2f(uv.y & 0xFFFF0000u);
          acc[u][4] += bits2f(uv.z << 16);
          acc[u][5] += bits2f(uv.z & 0xFFFF0000u);
          acc[u][6] += bits2f(uv.w << 16);
          acc[u][7] += bits2f(uv.w & 0xFFFF0000u);
        }
      }
      if (j < le) {
        int sj = lsrc[j];
        uint4 uv = *(const uint4*)(Y + (size_t)sj * H + c8);
        acc[0][0] += bits2f(uv.x << 16);
        acc[0][1] += bits2f(uv.x & 0xFFFF0000u);
        acc[0][2] += bits2f(uv.y << 16);
        acc[0][3] += bits2f(uv.y & 0xFFFF0000u);
        acc[0][4] += bits2f(uv.z << 16);
        acc[0][5] += bits2f(uv.z & 0xFFFF0000u);
        acc[0][6] += bits2f(uv.w << 16);
        acc[0][7] += bits2f(uv.w & 0xFFFF0000u);
      }
      #pragma unroll
      for (int u = 4; u < 8; ++u)
        #pragma unroll
        for (int q = 0; q < 8; ++q) acc[u - 4][q] += acc[u][q];
      #pragma unroll
      for (int q = 0; q < 8; ++q)
        a[q] = (acc[0][q] + acc[1][q]) + (acc[2][q] + acc[3][q]);
    } else {
      // slow path (statistically unreachable): scan whole bucket segment
      int lnfull = ln + (hb << 5);
      for (int jj = s; jj < e; ++jj) {
        int p = ebuf[jj];
        if ((p & 63) == lnfull) {
          deg += 1.0f;
          uint4 uv = *(const uint4*)(Y + (size_t)(p >> 6) * H + c8);
          a[0] += bits2f(uv.x << 16);
          a[1] += bits2f(uv.x & 0xFFFF0000u);
          a[2] += bits2f(uv.y << 16);
          a[3] += bits2f(uv.y & 0xFFFF0000u);
          a[4] += bits2f(uv.z << 16);
          a[5] += bits2f(uv.z & 0xFFFF0000u);
          a[6] += bits2f(uv.w << 16);
          a[7] += bits2f(uv.w & 0xFFFF0000u);
        }
      }
    }

    float inv = 1.0f / fmaxf(deg, 1.0f);
    float v[8];
    if (LOWP) {
      uint4 pv = *(const uint4*)(Pbf + (size_t)node * H + c8);
      v[0] = bits2f(pv.x << 16)         + a[0] * inv;
      v[1] = bits2f(pv.x & 0xFFFF0000u) + a[1] * inv;
      v[2] = bits2f(pv.y << 16)         + a[2] * inv;
      v[3] = bits2f(pv.y & 0xFFFF0000u) + a[3] * inv;
      v[4] = bits2f(pv.z << 16)         + a[4] * inv;
      v[5] = bits2f(pv.z & 0xFFFF0000u) + a[5] * inv;
      v[6] = bits2f(pv.w << 16)         + a[6] * inv;
      v[7] = bits2f(pv.w & 0xFFFF0000u) + a[7] * inv;
    } else {
      float4 pa = *(const float4*)(pio + (size_t)node * H + c8);
      float4 pb = *(const float4*)(pio + (size_t)node * H + c8 + 4);
      v[0] = pa.x + a[0] * inv; v[1] = pa.y + a[1] * inv;
      v[2] = pa.z + a[2] * inv; v[3] = pa.w + a[3] * inv;
      v[4] = pb.x + a[4] * inv; v[5] = pb.y + a[5] * inv;
      v[6] = pb.z + a[6] * inv; v[7] = pb.w + a[7] * inv;
    }

    float sq = 0.f;
    #pragma unroll
    for (int q = 0; q < 8; ++q) sq += v[q] * v[q];
    sq += __shfl_xor(sq, 1, 64);
    sq += __shfl_xor(sq, 2, 64);
    sq += __shfl_xor(sq, 4, 64);
    sq += __shfl_xor(sq, 8, 64);
    float rs = 1.0f / fmaxf(sqrtf(sq), 1e-12f);

    float u_[8];
    #pragma unroll
    for (int q = 0; q < 8; ++q) u_[q] = fmaxf(v[q] * rs, 0.f);

    if (LOWP) {
      uint4 ov;
      ov.x = (unsigned)f2bf(u_[0]) | ((unsigned)f2bf(u_[1]) << 16);
      ov.y = (unsigned)f2bf(u_[2]) | ((unsigned)f2bf(u_[3]) << 16);
      ov.z = (unsigned)f2bf(u_[4]) | ((unsigned)f2bf(u_[5]) << 16);
      ov.w = (unsigned)f2bf(u_[6]) | ((unsigned)f2bf(u_[7]) << 16);
      *(uint4*)(Ubf + (size_t)node * H + c8) = ov;
    } else {
      float4 oa = {u_[0], u_[1], u_[2], u_[3]};
      float4 ob = {u_[4], u_[5], u_[6], u_[7]};
      *(float4*)(pio + (size_t)node * H + c8) = oa;
      *(float4*)(pio + (size_t)node * H + c8 + 4) = ob;
    }
    #pragma unroll
    for (int q = 0; q < 8; ++q) {
      lcs[q] += u_[q];
      lcq[q] += u_[q] * u_[q];
    }
  }

  #pragma unroll
  for (int q = 0; q < 8; ++q) {
    atomicAdd(&csm[c8 + q], lcs[q]);
    atomicAdd(&cqm[c8 + q], lcq[q]);
  }
  __syncthreads();
  if (t < 128) {
    atomicAdd(&colsum[t], csm[t]);
    atomicAdd(&colsq[t], cqm[t]);
  }
}

// ---------------------------------------------------------------------------
// CSR build (mid fallback path)
// ---------------------------------------------------------------------------
__global__ __launch_bounds__(256) void deg_count(const void* __restrict__ eiv,
                                                 const int* __restrict__ flag,
                                                 int* __restrict__ degi, int E) {
  int e = blockIdx.x * blockDim.x + threadIdx.x;
  if (e >= E) return;
  int dst = load_idx(eiv, *flag, (long long)E + e);
  atomicAdd(&degi[dst], 1);
}

__global__ __launch_bounds__(256) void scan3(int* __restrict__ offsets,
                                             const int* __restrict__ blockoff,
                                             int* __restrict__ cursor, int n, int E) {
  int idx = blockIdx.x * 256 + threadIdx.x;
  if (idx >= n) return;
  int off = offsets[idx] + blockoff[idx >> 8];
  offsets[idx] = off;
  cursor[idx] = off;
  if (idx == 0) offsets[n] = E;
}

__global__ __launch_bounds__(256) void bucket_fill(const void* __restrict__ eiv,
                                                   const int* __restrict__ flag,
                                                   int* __restrict__ cursor,
                                                   int* __restrict__ csr_src, int E) {
  int e = blockIdx.x * blockDim.x + threadIdx.x;
  if (e >= E) return;
  int is64 = *flag;
  int src = load_idx(eiv, is64, e);
  int dst = load_idx(eiv, is64, (long long)E + e);
  int pos = atomicAdd(&cursor[dst], 1);
  csr_src[pos] = src;
}

// ---------------------------------------------------------------------------
// prep_w: split Wl/Wr into bf16 hi/lo in MFMA fragment-blob order.
// ---------------------------------------------------------------------------
__global__ __launch_bounds__(256) void prep_w(const float* __restrict__ Wl,
                                              const float* __restrict__ Wr,
                                              unsigned short* __restrict__ Wcat) {
  int tid = blockIdx.x * 256 + threadIdx.x;
  if (tid >= 4 * 4 * 8 * 64) return;
  int lane = tid & 63;
  int nf   = (tid >> 6) & 7;
  int kc   = (tid >> 9) & 3;
  int part = tid >> 11;
  const float* W = (part < 2) ? Wl : Wr;
  bool lo = (part & 1);
  int ncol = nf * 16 + (lane & 15);
  int k0 = kc * 32 + (lane >> 4) * 8;
  unsigned short ov[8];
  #pragma unroll
  for (int j = 0; j < 8; ++j) {
    float v = W[(k0 + j) * H + ncol];
    unsigned short h = f2bf(v);
    ov[j] = lo ? f2bf(v - bf2f(h)) : h;
  }
  uint4 pack;
  pack.x = (unsigned)ov[0] | ((unsigned)ov[1] << 16);
  pack.y = (unsigned)ov[2] | ((unsigned)ov[3] << 16);
  pack.z = (unsigned)ov[4] | ((unsigned)ov[5] << 16);
  pack.w = (unsigned)ov[6] | ((unsigned)ov[7] << 16);
  *(uint4*)(Wcat + (size_t)tid * 8) = pack;
}

// ---------------------------------------------------------------------------
// dual_gemm<LOWP>: one pass over x computes BOTH
//   Y = bf16(x @ Wl) -> Y (ws)
//   P = x @ Wr + bl  -> bf16 Pbf (ws) if LOWP, else f32 pout (d_out)
// ---------------------------------------------------------------------------
template <bool LOWP>
__global__ __launch_bounds__(256) void dual_gemm(
    const float* __restrict__ x, const unsigned short* __restrict__ Wcat,
    const float* __restrict__ bl, unsigned short* __restrict__ Y,
    float* __restrict__ pout, unsigned short* __restrict__ Pbf, int n) {
  __shared__ unsigned short As[2][64][128];  // x_hi, x_lo

  const int t = threadIdx.x;
  const int i0 = blockIdx.x * 64;

  #pragma unroll
  for (int it = 0; it < 8; ++it) {
    int idx = it * 256 + t;
    int r = idx >> 5;
    int c4 = (idx & 31) * 4;
    int row_g = i0 + r; if (row_g >= n) row_g = n - 1;
    int boff = (((c4 >> 3) ^ (r & 7)) << 3) + (c4 & 7);
    float4 vx = *(const float4*)(x + (size_t)row_g * F + c4);
    unsigned short h0 = f2bf(vx.x), h1 = f2bf(vx.y), h2 = f2bf(vx.z), h3 = f2bf(vx.w);
    uint2 hv = { (unsigned)h0 | ((unsigned)h1 << 16), (unsigned)h2 | ((unsigned)h3 << 16) };
    *(uint2*)&As[0][r][boff] = hv;
    unsigned short l0 = f2bf(vx.x - bf2f(h0)), l1 = f2bf(vx.y - bf2f(h1));
    unsigned short l2 = f2bf(vx.z - bf2f(h2)), l3 = f2bf(vx.w - bf2f(h3));
    uint2 lv = { (unsigned)l0 | ((unsigned)l1 << 16), (unsigned)l2 | ((unsigned)l3 << 16) };
    *(uint2*)&As[1][r][boff] = lv;
  }
  __syncthreads();

  const int w = t >> 6;
  const int lane = t & 63;

  f32x4 accL[4][2], accR[4][2];
  #pragma unroll
  for (int rf = 0; rf < 4; ++rf)
    #pragma unroll
    for (int nfi = 0; nfi < 2; ++nfi) {
      accL[rf][nfi] = (f32x4){0.f, 0.f, 0.f, 0.f};
      accR[rf][nfi] = (f32x4){0.f, 0.f, 0.f, 0.f};
    }

  const int APM[3] = {0, 1, 0};
  const int BL[3]  = {0, 0, 1};   // Wl_hi, Wl_hi, Wl_lo
  const int BR[3]  = {2, 2, 3};   // Wr_hi, Wr_hi, Wr_lo

  #pragma unroll
  for (int pass = 0; pass < 3; ++pass) {
    const int ap = APM[pass];
    #pragma unroll
    for (int kc = 0; kc < 4; ++kc) {
      short8 afr[4];
      int chunk = kc * 4 + (lane >> 4);
      #pragma unroll
      for (int rf = 0; rf < 4; ++rf) {
        int row = rf * 16 + (lane & 15);
        afr[rf] = *(const short8*)(&As[ap][row][(chunk ^ (row & 7)) * 8]);
      }
      short8 bfrL[2], bfrR[2];
      #pragma unroll
      for (int nfi = 0; nfi < 2; ++nfi) {
        int blobL = (BL[pass] * 4 + kc) * 8 + (w * 2 + nfi);
        int blobR = (BR[pass] * 4 + kc) * 8 + (w * 2 + nfi);
        bfrL[nfi] = *(const short8*)(Wcat + (size_t)blobL * 512 + lane * 8);
        bfrR[nfi] = *(const short8*)(Wcat + (size_t)blobR * 512 + lane * 8);
      }
      #pragma unroll
      for (int rf = 0; rf < 4; ++rf)
        #pragma unroll
        for (int nfi = 0; nfi < 2; ++nfi) {
          accL[rf][nfi] = __builtin_amdgcn_mfma_f32_16x16x32_bf16(
              afr[rf], bfrL[nfi], accL[rf][nfi], 0, 0, 0);
          accR[rf][nfi] = __builtin_amdgcn_mfma_f32_16x16x32_bf16(
              afr[rf], bfrR[nfi], accR[rf][nfi], 0, 0, 0);
        }
    }
  }

  const float b0 = bl[w * 32 + (lane & 15)];
  const float b1 = bl[w * 32 + 16 + (lane & 15)];

  #pragma unroll
  for (int rf = 0; rf < 4; ++rf) {
    #pragma unroll
    for (int r4 = 0; r4 < 4; ++r4) {
      int rl = rf * 16 + (lane >> 4) * 4 + r4;
      int row = i0 + rl;
      if (row < n) {
        Y[(size_t)row * H + w * 32 + (lane & 15)]      = f2bf(accL[rf][0][r4]);
        Y[(size_t)row * H + w * 32 + 16 + (lane & 15)] = f2bf(accL[rf][1][r4]);
        if (LOWP) {
          Pbf[(size_t)row * H + w * 32 + (lane & 15)]      = f2bf(accR[rf][0][r4] + b0);
          Pbf[(size_t)row * H + w * 32 + 16 + (lane & 15)] = f2bf(accR[rf][1][r4] + b1);
        } else {
          pout[(size_t)row * H + w * 32 + (lane & 15)]      = accR[rf][0][r4] + b0;
          pout[(size_t)row * H + w * 32 + 16 + (lane & 15)] = accR[rf][1][r4] + b1;
        }
      }
    }
  }
}

// ---------------------------------------------------------------------------
// Mid path: f32 gather + double MFMA gemm.
// ---------------------------------------------------------------------------
__global__ __launch_bounds__(256) void gather_mean(const float* __restrict__ x,
                                                   const int* __restrict__ offsets,
                                                   const int* __restrict__ csr_src,
                                                   float* __restrict__ out, int n) {
  int node = (int)(((long long)blockIdx.x * blockDim.x + threadIdx.x) >> 6);
  int lane = threadIdx.x & 63;
  if (node >= n) return;
  int s = offsets[node], e = offsets[node + 1];
  float ax = 0.0f, ay = 0.0f, bx = 0.0f, by = 0.0f;
  int j = s;
  for (; j + 1 < e; j += 2) {
    int s0 = csr_src[j], s1 = csr_src[j + 1];
    float2 v0 = *(const float2*)(x + (size_t)s0 * F + lane * 2);
    float2 v1 = *(const float2*)(x + (size_t)s1 * F + lane * 2);
    ax += v0.x; ay += v0.y;
    bx += v1.x; by += v1.y;
  }
  if (j < e) {
    int s0 = csr_src[j];
    float2 v0 = *(const float2*)(x + (size_t)s0 * F + lane * 2);
    ax += v0.x; ay += v0.y;
  }
  float inv = 1.0f / fmaxf((float)(e - s), 1.0f);
  float2 r; r.x = (ax + bx) * inv; r.y = (ay + by) * inv;
  *(float2*)(out + (size_t)node * H + lane * 2) = r;
}

__global__ __launch_bounds__(256) void mfma_gemm(
    const float* __restrict__ x, const unsigned short* __restrict__ Wcat,
    const float* __restrict__ bl, float* __restrict__ out,
    float* __restrict__ colsum, float* __restrict__ colsq, int n) {
  __shared__ unsigned short As[4][64][128];
  __shared__ float rowsq[64][4];
  __shared__ float rscale[64];

  const int t = threadIdx.x;
  const int i0 = blockIdx.x * 64;

  #pragma unroll
  for (int it = 0; it < 8; ++it) {
    int idx = it * 256 + t;
    int r = idx >> 5;
    int c4 = (idx & 31) * 4;
    int row_g = i0 + r; if (row_g >= n) row_g = n - 1;
    int boff = (((c4 >> 3) ^ (r & 7)) << 3) + (c4 & 7);
    float4 va = *(const float4*)(out + (size_t)row_g * H + c4);
    float4 vx = *(const float4*)(x + (size_t)row_g * H + c4);
    unsigned short h0 = f2bf(va.x), h1 = f2bf(va.y), h2 = f2bf(va.z), h3 = f2bf(va.w);
    uint2 hv = { (unsigned)h0 | ((unsigned)h1 << 16), (unsigned)h2 | ((unsigned)h3 << 16) };
    *(uint2*)&As[0][r][boff] = hv;
    unsigned short l0 = f2bf(va.x - bf2f(h0)), l1 = f2bf(va.y - bf2f(h1));
    unsigned short l2 = f2bf(va.z - bf2f(h2)), l3 = f2bf(va.w - bf2f(h3));
    uint2 lv = { (unsigned)l0 | ((unsigned)l1 << 16), (unsigned)l2 | ((unsigned)l3 << 16) };
    *(uint2*)&As[1][r][boff] = lv;
    h0 = f2bf(vx.x); h1 = f2bf(vx.y); h2 = f2bf(vx.z); h3 = f2bf(vx.w);
    uint2 hx = { (unsigned)h0 | ((unsigned)h1 << 16), (unsigned)h2 | ((unsigned)h3 << 16) };
    *(uint2*)&As[2][r][boff] = hx;
    l0 = f2bf(vx.x - bf2f(h0)); l1 = f2bf(vx.y - bf2f(h1));
    l2 = f2bf(vx.z - bf2f(h2)); l3 = f2bf(vx.w - bf2f(h3));
    uint2 lx = { (unsigned)l0 | ((unsigned)l1 << 16), (unsigned)l2 | ((unsigned)l3 << 16) };
    *(uint2*)&As[3][r][boff] = lx;
  }
  __syncthreads();

  const int w = t >> 6;
  const int lane = t & 63;

  f32x4 acc[4][2];
  #pragma unroll
  for (int rf = 0; rf < 4; ++rf)
    #pragma unroll
    for (int nfi = 0; nfi < 2; ++nfi)
      acc[rf][nfi] = (f32x4){0.f, 0.f, 0.f, 0.f};

  const int APM[6] = {0, 1, 0, 2, 3, 2};
  const int BPM[6] = {0, 0, 1, 2, 2, 3};

  #pragma unroll
  for (int pass = 0; pass < 6; ++pass) {
    const int ap = APM[pass], bp = BPM[pass];
    #pragma unroll
    for (int kc = 0; kc < 4; ++kc) {
      short8 bfr[2];
      #pragma unroll
      for (int nfi = 0; nfi < 2; ++nfi) {
        int blob = (bp * 4 + kc) * 8 + (w * 2 + nfi);
        bfr[nfi] = *(const short8*)(Wcat + (size_t)blob * 512 + lane * 8);
      }
      short8 afr[4];
      int chunk = kc * 4 + (lane >> 4);
      #pragma unroll
      for (int rf = 0; rf < 4; ++rf) {
        int row = rf * 16 + (lane & 15);
        afr[rf] = *(const short8*)(&As[ap][row][(chunk ^ (row & 7)) * 8]);
      }
      #pragma unroll
      for (int rf = 0; rf < 4; ++rf)
        #pragma unroll
        for (int nfi = 0; nfi < 2; ++nfi)
          acc[rf][nfi] = __builtin_amdgcn_mfma_f32_16x16x32_bf16(
              afr[rf], bfr[nfi], acc[rf][nfi], 0, 0, 0);
    }
  }

  const float b0 = bl[w * 32 + (lane & 15)];
  const float b1 = bl[w * 32 + 16 + (lane & 15)];

  #pragma unroll
  for (int rf = 0; rf < 4; ++rf) {
    #pragma unroll
    for (int r4 = 0; r4 < 4; ++r4) {
      float v0 = acc[rf][0][r4] + b0;
      float v1 = acc[rf][1][r4] + b1;
      acc[rf][0][r4] = v0;
      acc[rf][1][r4] = v1;
      float sq = v0 * v0 + v1 * v1;
      sq += __shfl_xor(sq, 1, 64);
      sq += __shfl_xor(sq, 2, 64);
      sq += __shfl_xor(sq, 4, 64);
      sq += __shfl_xor(sq, 8, 64);
      if ((lane & 15) == 0) rowsq[rf * 16 + (lane >> 4) * 4 + r4][w] = sq;
    }
  }
  __syncthreads();
  if (t < 64) {
    float s = rowsq[t][0] + rowsq[t][1] + rowsq[t][2] + rowsq[t][3];
    rscale[t] = 1.0f / fmaxf(sqrtf(s), 1e-12f);
  }
  __syncthreads();

  float cs0 = 0.f, cq0 = 0.f, cs1 = 0.f, cq1 = 0.f;
  #pragma unroll
  for (int rf = 0; rf < 4; ++rf) {
    #pragma unroll
    for (int r4 = 0; r4 < 4; ++r4) {
      int rl = rf * 16 + (lane >> 4) * 4 + r4;
      int row = i0 + rl;
      float s = rscale[rl];
      float u0 = fmaxf(acc[rf][0][r4] * s, 0.f);
      float u1 = fmaxf(acc[rf][1][r4] * s, 0.f);
      if (row < n) {
        out[(size_t)row * H + w * 32 + (lane & 15)] = u0;
        out[(size_t)row * H + w * 32 + 16 + (lane & 15)] = u1;
        cs0 += u0; cq0 += u0 * u0;
        cs1 += u1; cq1 += u1 * u1;
      }
    }
  }
  cs0 += __shfl_xor(cs0, 16, 64); cs0 += __shfl_xor(cs0, 32, 64);
  cq0 += __shfl_xor(cq0, 16, 64); cq0 += __shfl_xor(cq0, 32, 64);
  cs1 += __shfl_xor(cs1, 16, 64); cs1 += __shfl_xor(cs1, 32, 64);
  cq1 += __shfl_xor(cq1, 16, 64); cq1 += __shfl_xor(cq1, 32, 64);
  if (lane < 16) {
    atomicAdd(&colsum[w * 32 + lane], cs0);
    atomicAdd(&colsq[w * 32 + lane], cq0);
    atomicAdd(&colsum[w * 32 + 16 + lane], cs1);
    atomicAdd(&colsq[w * 32 + 16 + lane], cq1);
  }
}

// ---------------------------------------------------------------------------
// Fallback path (tiny ws): atomic scatter + divide + scalar fused gemm.
// ---------------------------------------------------------------------------
__global__ __launch_bounds__(256) void scatter_mean(
    const float* __restrict__ x, const void* __restrict__ eiv,
    const int* __restrict__ flag, float* __restrict__ agg,
    float* __restrict__ deg, int E) {
  long long gid = (long long)blockIdx.x * blockDim.x + threadIdx.x;
  int e = (int)(gid >> 5);
  int ch = (int)(gid & 31);
  if (e >= E) return;
  int is64 = *flag;
  int src = load_idx(eiv, is64, e);
  int dst = load_idx(eiv, is64, (long long)E + e);
  float4 v = *(const float4*)(x + (size_t)src * F + ch * 4);
  float* a = agg + (size_t)dst * H + ch * 4;
  atomicAdd(a + 0, v.x);
  atomicAdd(a + 1, v.y);
  atomicAdd(a + 2, v.z);
  atomicAdd(a + 3, v.w);
  if (ch == 0) atomicAdd(deg + dst, 1.0f);
}

__global__ __launch_bounds__(256) void divide_deg(float* __restrict__ out,
                                                  const float* __restrict__ deg,
                                                  long long n4) {
  long long i = (long long)blockIdx.x * blockDim.x + threadIdx.x;
  if (i >= n4) return;
  int node = (int)(i >> 5);
  float s = 1.0f / fmaxf(deg[node], 1.0f);
  float4 v = ((float4*)out)[i];
  v.x *= s; v.y *= s; v.z *= s; v.w *= s;
  ((float4*)out)[i] = v;
}

__global__ __launch_bounds__(256) void fused_gemm(
    const float* __restrict__ x, const float* __restrict__ Wl,
    const float* __restrict__ bl, const float* __restrict__ Wr,
    float* __restrict__ out, float* __restrict__ colsum, float* __restrict__ colsq) {
  __shared__ float As[16][256];
  __shared__ float rp[4][8];
  __shared__ float rscale[16];
  __shared__ float cs[128], cs2[128];

  const int t = threadIdx.x;
  const int i0 = blockIdx.x * 16;

  #pragma unroll
  for (int it = 0; it < 2; ++it) {
    int idx = (it * 256 + t) * 4;
    int r = idx >> 7, c = idx & 127;
    float4 va = *(const float4*)(out + (size_t)(i0 + r) * H + c);
    As[r][c + 0] = va.x; As[r][c + 1] = va.y;
    As[r][c + 2] = va.z; As[r][c + 3] = va.w;
    float4 vx = *(const float4*)(x + (size_t)(i0 + r) * F + c);
    As[r][128 + c + 0] = vx.x; As[r][128 + c + 1] = vx.y;
    As[r][128 + c + 2] = vx.z; As[r][128 + c + 3] = vx.w;
  }
  __syncthreads();

  const int c = t & 127;
  const int half = t >> 7;
  float acc[8];
  #pragma unroll
  for (int r = 0; r < 8; ++r) acc[r] = 0.0f;

  #pragma unroll 4
  for (int k = 0; k < 128; ++k) {
    float w = Wl[k * H + c];
    #pragma unroll
    for (int r = 0; r < 8; ++r) acc[r] = fmaf(As[half * 8 + r][k], w, acc[r]);
  }
  #pragma unroll 4
  for (int k = 0; k < 128; ++k) {
    float w = Wr[k * H + c];
    #pragma unroll
    for (int r = 0; r < 8; ++r) acc[r] = fmaf(As[half * 8 + r][128 + k], w, acc[r]);
  }
  const float bias = bl[c];
  #pragma unroll
  for (int r = 0; r < 8; ++r) acc[r] += bias;

  float sq[8];
  #pragma unroll
  for (int r = 0; r < 8; ++r) sq[r] = acc[r] * acc[r];
  #pragma unroll
  for (int off = 32; off > 0; off >>= 1) {
    #pragma unroll
    for (int r = 0; r < 8; ++r) sq[r] += __shfl_down(sq[r], off, 64);
  }
  const int wv = t >> 6;
  if ((t & 63) == 0) {
    #pragma unroll
    for (int r = 0; r < 8; ++r) rp[wv][r] = sq[r];
  }
  __syncthreads();
  if (t < 16) {
    int base = (t >> 3) * 2, rr = t & 7;
    float s = rp[base][rr] + rp[base + 1][rr];
    rscale[t] = 1.0f / fmaxf(sqrtf(s), 1e-12f);
  }
  __syncthreads();

  float csum = 0.0f, csq = 0.0f;
  #pragma unroll
  for (int r = 0; r < 8; ++r) {
    float v = fmaxf(acc[r] * rscale[half * 8 + r], 0.0f);
    out[(size_t)(i0 + half * 8 + r) * H + c] = v;
    csum += v;
    csq += v * v;
  }
  if (half == 1) { cs[c] = csum; cs2[c] = csq; }
  __syncthreads();
  if (half == 0) {
    atomicAdd(&colsum[c], csum + cs[c]);
    atomicAdd(&colsq[c], csq + cs2[c]);
  }
}

__global__ void bn_stats(const float* __restrict__ colsum, const float* __restrict__ colsq,
                         const float* __restrict__ gamma, const float* __restrict__ beta,
                         float* __restrict__ scale, float* __restrict__ shift, int n) {
  int c = threadIdx.x;
  if (c < H) {
    float inv_n = 1.0f / (float)n;
    float mean = colsum[c] * inv_n;
    float var = colsq[c] * inv_n - mean * mean;  // biased (torch BN)
    float istd = rsqrtf(var + 1e-5f);
    float sc = gamma[c] * istd;
    scale[c] = sc;
    shift[c] = beta[c] - mean * sc;
  }
}

__global__ __launch_bounds__(256) void bn_apply(
    float* __restrict__ out, const float* __restrict__ scale,
    const float* __restrict__ shift, long long n4) {
  long long i = (long long)blockIdx.x * blockDim.x + threadIdx.x;
  if (i >= n4) return;
  float4 v = ((float4*)out)[i];
  int c = (int)((i * 4) & (H - 1));
  v.x = fmaf(v.x, scale[c + 0], shift[c + 0]);
  v.y = fmaf(v.y, scale[c + 1], shift[c + 1]);
  v.z = fmaf(v.z, scale[c + 2], shift[c + 2]);
  v.w = fmaf(v.w, scale[c + 3], shift[c + 3]);
  ((float4*)out)[i] = v;
}

// reads pre-BN u (bf16 in ws), writes final f32 to out
__global__ __launch_bounds__(256) void bn_apply_lo(
    const unsigned short* __restrict__ U, float* __restrict__ out,
    const float* __restrict__ scale, const float* __restrict__ shift,
    long long n4) {
  long long i = (long long)blockIdx.x * blockDim.x + threadIdx.x;
  if (i >= n4) return;
  uint2 uv = ((const uint2*)U)[i];
  int c = (int)((i * 4) & (H - 1));
  float4 v;
  v.x = fmaf(bits2f(uv.x << 16),          scale[c + 0], shift[c + 0]);
  v.y = fmaf(bits2f(uv.x & 0xFFFF0000u),  scale[c + 1], shift[c + 1]);
  v.z = fmaf(bits2f(uv.y << 16),          scale[c + 2], shift[c + 2]);
  v.w = fmaf(bits2f(uv.y & 0xFFFF0000u),  scale[c + 3], shift[c + 3]);
  ((float4*)out)[i] = v;
}

extern "C" void kernel_launch(void* const* d_in, const int* in_sizes, int n_in,
                              void* d_out, int out_size, void* d_ws, size_t ws_size,
                              hipStream_t stream) {
  const float* x     = (const float*)d_in[0];
  const void*  ei    = d_in[1];
  const float* Wl    = (const float*)d_in[2];
  const float* bl    = (const float*)d_in[3];
  const float* Wr    = (const float*)d_in[4];
  const float* gamma = (const float*)d_in[5];
  const float* beta  = (const float*)d_in[6];
  float* out = (float*)d_out;

  const int n = in_sizes[0] / F;   // 100000
  const int E = in_sizes[1] / 2;   // 1600000
  const int nb = (n + 255) / 256;
  const int nbuck = (n + 63) >> 6; // 64-node buckets

  char* ws = (char*)d_ws;
  int* flag = (int*)ws;
  unsigned short* Wcat = (unsigned short*)(ws + 256);
  char* after_w = ws + 256 + 4 * 128 * 128 * 2;

  // ---- fast-path layout: two-pass partition + bucket gather + Y (+P,U bf16) ----
  int*   cmat    = (int*)after_w;
  int*   obuf    = cmat + 2048 * NPART;
  int*   bsum    = obuf + 2048 * NPART;
  int*   boff    = bsum + 1024;
  int*   bbase   = boff + 1024;
  float* fcs     = (float*)(bbase + 2049);
  float* fcq     = fcs + H;
  float* fsc     = fcq + H;
  float* fsh     = fsc + H;
  int*   ebuf    = (int*)(fsh + H);
  unsigned short* Yws = (unsigned short*)(ebuf + E);
  unsigned short* Pws = Yws + (size_t)n * H;
  unsigned short* Uws = Pws + (size_t)n * H;
  size_t need_fast  = (size_t)((char*)(Yws + (size_t)n * H) - ws);
  size_t need_fast2 = (size_t)((char*)(Uws + (size_t)n * H) - ws);

  // ---- mid-path layout: CSR ----
  int*   degi     = (int*)after_w;
  int*   offsets  = degi + n;
  int*   cursor   = offsets + n + 1;
  int*   blocksum = cursor + n;
  int*   blockoff = blocksum + nb;
  float* mcs      = (float*)(blockoff + nb);
  float* mcq      = mcs + H;
  float* msc      = mcq + H;
  float* msh      = msc + H;
  int*   csr_src  = (int*)(msh + H);
  size_t need_mid = (size_t)((char*)(csr_src + E) - ws);

  float *colsum, *colsq, *scale, *shift;

  const int eb = (E + 255) / 256;
  const int gb = (n + 63) / 64;
  const long long n4 = (long long)n * H / 4;

  if (ws_size >= need_fast && nbuck <= 2048) {
    const bool lowp = (ws_size >= need_fast2);
    colsum = fcs; colsq = fcq; scale = fsc; shift = fsh;

    prep_w<<<32, 256, 0, stream>>>(Wl, Wr, Wcat);
    if (lowp)
      dual_gemm<true><<<gb, 256, 0, stream>>>(x, Wcat, bl, Yws, out, Pws, n);
    else
      dual_gemm<false><<<gb, 256, 0, stream>>>(x, Wcat, bl, Yws, out, Pws, n);

    const int chunk = (E + NPART - 1) / NPART;
    const int L = nbuck * NPART;
    const int nb2 = (L + 255) / 256;   // <= 1024
    part_hist<<<NPART, 512, 0, stream>>>(ei, cmat, E, nbuck, chunk);
    scan1<<<nb2, 256, 0, stream>>>(cmat, obuf, bsum, L);
    scan2big<<<1, 1024, 0, stream>>>(bsum, boff, nb2);
    scan3p<<<nb2, 256, 0, stream>>>(obuf, boff, bbase, colsum, L, nbuck, E);
    part_scatter<<<NPART, 512, 0, stream>>>(ei, obuf, ebuf, E, nbuck, chunk);

    if (lowp)
      gather_half<true><<<2 * nbuck, 256, 0, stream>>>(
          Yws, ebuf, bbase, out, Pws, Uws, colsum, colsq, n);
    else
      gather_half<false><<<2 * nbuck, 256, 0, stream>>>(
          Yws, ebuf, bbase, out, Pws, Uws, colsum, colsq, n);

    bn_stats<<<1, 128, 0, stream>>>(colsum, colsq, gamma, beta, scale, shift, n);
    if (lowp)
      bn_apply_lo<<<(int)((n4 + 255) / 256), 256, 0, stream>>>(
          Uws, out, scale, shift, n4);
    else
      bn_apply<<<(int)((n4 + 255) / 256), 256, 0, stream>>>(out, scale, shift, n4);
  } else if (ws_size >= need_mid) {
    colsum = mcs; colsq = mcq; scale = msc; shift = msh;
    detect_dtype<<<1, 64, 0, stream>>>((const unsigned*)ei, flag);
    hipMemsetAsync(degi, 0, (size_t)n * 4, stream);
    hipMemsetAsync(colsum, 0, 2 * H * 4, stream);

    prep_w<<<32, 256, 0, stream>>>(Wl, Wr, Wcat);

    deg_count<<<eb, 256, 0, stream>>>(ei, flag, degi, E);
    scan1<<<nb, 256, 0, stream>>>(degi, offsets, blocksum, n);
    scan2big<<<1, 1024, 0, stream>>>(blocksum, blockoff, nb);
    scan3<<<nb, 256, 0, stream>>>(offsets, blockoff, cursor, n, E);
    bucket_fill<<<eb, 256, 0, stream>>>(ei, flag, cursor, csr_src, E);

    long long gthreads = (long long)n * 64;
    gather_mean<<<(int)((gthreads + 255) / 256), 256, 0, stream>>>(
        x, offsets, csr_src, out, n);

    mfma_gemm<<<gb, 256, 0, stream>>>(x, Wcat, bl, out, colsum, colsq, n);
    bn_stats<<<1, 128, 0, stream>>>(colsum, colsq, gamma, beta, scale, shift, n);
    bn_apply<<<(int)((n4 + 255) / 256), 256, 0, stream>>>(out, scale, shift, n4);
  } else {
    float* deg = (float*)(ws + 256);
    colsum = deg + n; colsq = colsum + H; scale = colsq + H; shift = scale + H;
    detect_dtype<<<1, 64, 0, stream>>>((const unsigned*)ei, flag);
    hipMemsetAsync(d_out, 0, (size_t)out_size * sizeof(float), stream);
    hipMemsetAsync(deg, 0, (size_t)n * 4 + 4 * H * 4, stream);
    long long sthreads = (long long)E * 32;
    scatter_mean<<<(int)((sthreads + 255) / 256), 256, 0, stream>>>(x, ei, flag, out, deg, E);
    long long n4f = (long long)n * H / 4;
    divide_deg<<<(int)((n4f + 255) / 256), 256, 0, stream>>>(out, deg, n4f);
    fused_gemm<<<n / 16, 256, 0, stream>>>(x, Wl, bl, Wr, out, colsum, colsq);
    bn_stats<<<1, 128, 0, stream>>>(colsum, colsq, gamma, beta, scale, shift, n);
    bn_apply<<<(int)((n4 + 255) / 256), 256, 0, stream>>>(out, scale, shift, n4);
  }
}

// Round 10
// 226.198 us; speedup vs baseline: 1.1733x; 1.1733x over previous
//
#include <hip/hip_runtime.h>
#include <hip/hip_bf16.h>

static constexpr int F = 128;
static constexpr int H = 128;
static constexpr int NPART = 128;   // partition blocks (contiguous edge chunks)

typedef __attribute__((ext_vector_type(8))) short short8;
typedef __attribute__((ext_vector_type(4))) float f32x4;

__device__ __forceinline__ unsigned short f2bf(float f) {
  union { float f; unsigned u; } a; a.f = f;
  unsigned r = a.u + 0x7FFF + ((a.u >> 16) & 1);
  return (unsigned short)(r >> 16);
}
__device__ __forceinline__ float bf2f(unsigned short h) {
  union { unsigned u; float f; } a; a.u = ((unsigned)h) << 16;
  return a.f;
}
__device__ __forceinline__ float bits2f(unsigned u) {
  union { unsigned u; float f; } a; a.u = u;
  return a.f;
}

// f32 -> fp8 e4m3fn (RNE, flush-to-zero below 2^-6, clamp to 448)
__device__ __forceinline__ unsigned f2fp8(float f) {
  union { float f; unsigned u; } a; a.f = f;
  unsigned s = (a.u >> 24) & 0x80u;
  unsigned m = a.u & 0x7FFFFFFFu;
  if (m < 0x3C800000u) return s;                 // |f| < 2^-6 -> signed zero
  unsigned r = m + 0x7FFFFu + ((m >> 20) & 1u);  // RNE to 3 mantissa bits
  if (r > 0x43E00000u) r = 0x43E00000u;          // clamp to 448 (max finite)
  return s | ((((r >> 23) - 120u) & 15u) << 3) | ((r >> 20) & 7u);
}
// fp8 e4m3fn byte -> f32 (subnormals were flushed at encode)
__device__ __forceinline__ float fp82f(unsigned b) {
  unsigned mag = b & 0x7Fu;
  unsigned hb = ((b << 24) & 0x80000000u) | ((mag << 20) + 0x3C000000u);
  return mag ? bits2f(hb) : 0.0f;
}

// int64-vs-int32 edge_index detection (values < 2^17 -> int64 hi words all 0)
__device__ __forceinline__ int detect64(const void* eiv) {
  const unsigned* u = (const unsigned*)eiv;
  int is64 = 1;
  for (int i = 0; i < 64; ++i) is64 &= (u[2 * i + 1] == 0u);
  return is64;
}

__global__ void detect_dtype(const unsigned* __restrict__ ei, int* __restrict__ flag) {
  if (blockIdx.x == 0 && threadIdx.x == 0) {
    int is64 = 1;
    for (int i = 0; i < 64; ++i) {
      if (ei[2 * i + 1] != 0u) { is64 = 0; break; }
    }
    *flag = is64;
  }
}

__device__ __forceinline__ int load_idx(const void* eiv, int is64, long long pos) {
  return is64 ? (int)((const long long*)eiv)[pos] : ((const int*)eiv)[pos];
}

// ---------------------------------------------------------------------------
// Two-pass atomic-free partition into 64-node dst buckets.
// pack = (src << 6) | (dst & 63)
// ---------------------------------------------------------------------------
__global__ __launch_bounds__(512) void part_hist(const void* __restrict__ eiv,
                                                 int* __restrict__ cmat,
                                                 int E, int nbuck, int chunk) {
  __shared__ int h[2048];
  const int t = threadIdx.x, b = blockIdx.x;
  for (int i = t; i < nbuck; i += 512) h[i] = 0;
  __syncthreads();
  int is64 = detect64(eiv);
  int s = b * chunk, e = min(E, s + chunk);
  for (int i = s + t; i < e; i += 512) {
    int dst = load_idx(eiv, is64, (long long)E + i);
    atomicAdd(&h[dst >> 6], 1);
  }
  __syncthreads();
  for (int i = t; i < nbuck; i += 512) cmat[i * NPART + b] = h[i];
}

__global__ __launch_bounds__(256) void scan1(const int* __restrict__ in,
                                             int* __restrict__ outx,
                                             int* __restrict__ blocksum, int n) {
  __shared__ int sm[256];
  int idx = blockIdx.x * 256 + threadIdx.x;
  int v = (idx < n) ? in[idx] : 0;
  sm[threadIdx.x] = v;
  __syncthreads();
  #pragma unroll
  for (int off = 1; off < 256; off <<= 1) {
    int t = (threadIdx.x >= off) ? sm[threadIdx.x - off] : 0;
    __syncthreads();
    sm[threadIdx.x] += t;
    __syncthreads();
  }
  if (idx < n) outx[idx] = sm[threadIdx.x] - v;
  if (threadIdx.x == 255) blocksum[blockIdx.x] = sm[255];
}

__global__ __launch_bounds__(1024) void scan2big(const int* __restrict__ blocksum,
                                                 int* __restrict__ blockoff, int nb) {
  __shared__ int sm[1024];
  int t = threadIdx.x;
  int v = (t < nb) ? blocksum[t] : 0;
  sm[t] = v;
  __syncthreads();
  for (int off = 1; off < 1024; off <<= 1) {
    int u = (t >= off) ? sm[t - off] : 0;
    __syncthreads();
    sm[t] += u;
    __syncthreads();
  }
  if (t < nb) blockoff[t] = sm[t] - v;
}

// finalize partition scan: base matrix in place + bucket segment starts.
// Block 0 also zeroes colsum/colsq (256 contiguous floats).
__global__ __launch_bounds__(256) void scan3p(int* __restrict__ obuf,
                                              const int* __restrict__ blockoff,
                                              int* __restrict__ bbase,
                                              float* __restrict__ colzero,
                                              int L, int nbuck, int E) {
  if (blockIdx.x == 0) colzero[threadIdx.x] = 0.0f;
  int idx = blockIdx.x * 256 + threadIdx.x;
  if (idx >= L) return;
  int v = obuf[idx] + blockoff[idx >> 8];
  obuf[idx] = v;
  if ((idx & (NPART - 1)) == 0) bbase[idx / NPART] = v;
  if (idx == 0) bbase[nbuck] = E;
}

__global__ __launch_bounds__(512) void part_scatter(const void* __restrict__ eiv,
                                                    const int* __restrict__ base,
                                                    int* __restrict__ ebuf,
                                                    int E, int nbuck, int chunk) {
  __shared__ int cur[2048];
  const int t = threadIdx.x, b = blockIdx.x;
  for (int i = t; i < nbuck; i += 512) cur[i] = base[i * NPART + b];
  __syncthreads();
  int is64 = detect64(eiv);
  int s = b * chunk, e = min(E, s + chunk);
  for (int i = s + t; i < e; i += 512) {
    int src = load_idx(eiv, is64, i);
    int dst = load_idx(eiv, is64, (long long)E + i);
    int pos = atomicAdd(&cur[dst >> 6], 1);
    ebuf[pos] = (src << 6) | (dst & 63);
  }
}

// ---------------------------------------------------------------------------
// gather_bucket<LOWP>: one block per 64-node bucket (round-8 proven layout:
// 2 nodes/wave, 32 lanes/node, 8-deep unroll). Y is fp8 e4m3 (4 B/lane/row).
// Fused epilogue: v = P + agg; row-L2-norm; ReLU; store u; BN col stats.
// LOWP=true : P read bf16 (Pbf), u written bf16 (Ubf).
// LOWP=false: P read / u write f32 in pio (d_out).
// ---------------------------------------------------------------------------
#define GCAP 2048
template <bool LOWP>
__global__ __launch_bounds__(256) void gather_bucket(
    const unsigned char* __restrict__ Yf8, const int* __restrict__ ebuf,
    const int* __restrict__ bbase, float* __restrict__ pio,
    const unsigned short* __restrict__ Pbf, unsigned short* __restrict__ Ubf,
    float* __restrict__ colsum, float* __restrict__ colsq, int n) {
  __shared__ int lsrc[GCAP];
  __shared__ int hist[65];
  __shared__ int loff[65];
  __shared__ int cur[64];
  __shared__ float csm[128], cqm[128];

  const int t = threadIdx.x;
  const int b = blockIdx.x;
  const int node0 = b << 6;
  const int s = bbase[b], e = bbase[b + 1];
  const int cnt = e - s;

  if (t < 65) hist[t] = 0;
  if (t < 128) { csm[t] = 0.f; cqm[t] = 0.f; }
  __syncthreads();

  const bool fast = (cnt <= GCAP);
  if (fast) {
    for (int i = s + t; i < e; i += 256)
      atomicAdd(&hist[ebuf[i] & 63], 1);
    __syncthreads();
    if (t < 64) loff[t] = hist[t];
    __syncthreads();
    #pragma unroll
    for (int off = 1; off < 64; off <<= 1) {
      int u = (t >= off && t < 64) ? loff[t - off] : 0;
      __syncthreads();
      if (t < 64) loff[t] += u;
      __syncthreads();
    }
    if (t < 64) cur[t] = loff[t] - hist[t];
    __syncthreads();
    for (int i = s + t; i < e; i += 256) {
      int p = ebuf[i];
      int pos = atomicAdd(&cur[p & 63], 1);
      lsrc[pos] = p >> 6;
    }
    __syncthreads();
  }

  const int lane = t & 63;
  const int w = t >> 6;
  const int half = lane >> 5;
  const int c = (lane & 31) * 4;   // element/byte column (4 per lane)

  float lcs[4] = {0.f, 0.f, 0.f, 0.f};
  float lcq[4] = {0.f, 0.f, 0.f, 0.f};

  #pragma unroll
  for (int it = 0; it < 8; ++it) {
    int ln = it * 8 + w * 2 + half;
    int node = node0 + ln;
    if (node >= n) continue;
    int ls, le;
    if (fast) { ls = loff[ln] - hist[ln]; le = loff[ln]; }
    else      { ls = 0; le = 0; }

    float acc[8][4];
    #pragma unroll
    for (int u = 0; u < 8; ++u)
      #pragma unroll
      for (int q = 0; q < 4; ++q) acc[u][q] = 0.0f;

    int j = ls;
    for (; j + 7 < le; j += 8) {
      #pragma unroll
      for (int u = 0; u < 8; ++u) {
        int sj = lsrc[j + u];
        unsigned wv = *(const unsigned*)(Yf8 + (size_t)sj * H + c);
        acc[u][0] += fp82f(wv & 0xFF);
        acc[u][1] += fp82f((wv >> 8) & 0xFF);
        acc[u][2] += fp82f((wv >> 16) & 0xFF);
        acc[u][3] += fp82f(wv >> 24);
      }
    }
    for (; j + 1 < le; j += 2) {
      #pragma unroll
      for (int u = 0; u < 2; ++u) {
        int sj = lsrc[j + u];
        unsigned wv = *(const unsigned*)(Yf8 + (size_t)sj * H + c);
        acc[u][0] += fp82f(wv & 0xFF);
        acc[u][1] += fp82f((wv >> 8) & 0xFF);
        acc[u][2] += fp82f((wv >> 16) & 0xFF);
        acc[u][3] += fp82f(wv >> 24);
      }
    }
    if (j < le) {
      int sj = lsrc[j];
      unsigned wv = *(const unsigned*)(Yf8 + (size_t)sj * H + c);
      acc[0][0] += fp82f(wv & 0xFF);
      acc[0][1] += fp82f((wv >> 8) & 0xFF);
      acc[0][2] += fp82f((wv >> 16) & 0xFF);
      acc[0][3] += fp82f(wv >> 24);
    }

    float deg = 0.0f;
    float a0, a1, a2, a3;
    if (fast) {
      deg = (float)(le - ls);
      #pragma unroll
      for (int u = 4; u < 8; ++u) {
        acc[u - 4][0] += acc[u][0]; acc[u - 4][1] += acc[u][1];
        acc[u - 4][2] += acc[u][2]; acc[u - 4][3] += acc[u][3];
      }
      a0 = (acc[0][0] + acc[1][0]) + (acc[2][0] + acc[3][0]);
      a1 = (acc[0][1] + acc[1][1]) + (acc[2][1] + acc[3][1]);
      a2 = (acc[0][2] + acc[1][2]) + (acc[2][2] + acc[3][2]);
      a3 = (acc[0][3] + acc[1][3]) + (acc[2][3] + acc[3][3]);
    } else {
      // slow path (statistically unreachable): scan whole bucket
      a0 = a1 = a2 = a3 = 0.0f;
      for (int jj = s; jj < e; ++jj) {
        int p = ebuf[jj];
        if ((p & 63) == ln) {
          deg += 1.0f;
          unsigned wv = *(const unsigned*)(Yf8 + (size_t)(p >> 6) * H + c);
          a0 += fp82f(wv & 0xFF);
          a1 += fp82f((wv >> 8) & 0xFF);
          a2 += fp82f((wv >> 16) & 0xFF);
          a3 += fp82f(wv >> 24);
        }
      }
    }

    float inv = 1.0f / fmaxf(deg, 1.0f);
    float p0, p1, p2, p3;
    if (LOWP) {
      uint2 pv = *(const uint2*)(Pbf + (size_t)node * H + c);
      p0 = bits2f(pv.x << 16);
      p1 = bits2f(pv.x & 0xFFFF0000u);
      p2 = bits2f(pv.y << 16);
      p3 = bits2f(pv.y & 0xFFFF0000u);
    } else {
      float4 p = *(const float4*)(pio + (size_t)node * H + c);
      p0 = p.x; p1 = p.y; p2 = p.z; p3 = p.w;
    }
    float v0 = p0 + a0 * inv;
    float v1 = p1 + a1 * inv;
    float v2 = p2 + a2 * inv;
    float v3 = p3 + a3 * inv;
    float sq = v0 * v0 + v1 * v1 + v2 * v2 + v3 * v3;
    sq += __shfl_xor(sq, 1, 64);
    sq += __shfl_xor(sq, 2, 64);
    sq += __shfl_xor(sq, 4, 64);
    sq += __shfl_xor(sq, 8, 64);
    sq += __shfl_xor(sq, 16, 64);
    float rs = 1.0f / fmaxf(sqrtf(sq), 1e-12f);
    float u0 = fmaxf(v0 * rs, 0.f), u1 = fmaxf(v1 * rs, 0.f);
    float u2 = fmaxf(v2 * rs, 0.f), u3 = fmaxf(v3 * rs, 0.f);
    if (LOWP) {
      uint2 ov;
      ov.x = (unsigned)f2bf(u0) | ((unsigned)f2bf(u1) << 16);
      ov.y = (unsigned)f2bf(u2) | ((unsigned)f2bf(u3) << 16);
      *(uint2*)(Ubf + (size_t)node * H + c) = ov;
    } else {
      float4 o = {u0, u1, u2, u3};
      *(float4*)(pio + (size_t)node * H + c) = o;
    }
    lcs[0] += u0; lcq[0] += u0 * u0;
    lcs[1] += u1; lcq[1] += u1 * u1;
    lcs[2] += u2; lcq[2] += u2 * u2;
    lcs[3] += u3; lcq[3] += u3 * u3;
  }

  #pragma unroll
  for (int q = 0; q < 4; ++q) {
    atomicAdd(&csm[c + q], lcs[q]);
    atomicAdd(&cqm[c + q], lcq[q]);
  }
  __syncthreads();
  if (t < 128) {
    atomicAdd(&colsum[t], csm[t]);
    atomicAdd(&colsq[t], cqm[t]);
  }
}

// ---------------------------------------------------------------------------
// CSR build (mid fallback path)
// ---------------------------------------------------------------------------
__global__ __launch_bounds__(256) void deg_count(const void* __restrict__ eiv,
                                                 const int* __restrict__ flag,
                                                 int* __restrict__ degi, int E) {
  int e = blockIdx.x * blockDim.x + threadIdx.x;
  if (e >= E) return;
  int dst = load_idx(eiv, *flag, (long long)E + e);
  atomicAdd(&degi[dst], 1);
}

__global__ __launch_bounds__(256) void scan3(int* __restrict__ offsets,
                                             const int* __restrict__ blockoff,
                                             int* __restrict__ cursor, int n, int E) {
  int idx = blockIdx.x * 256 + threadIdx.x;
  if (idx >= n) return;
  int off = offsets[idx] + blockoff[idx >> 8];
  offsets[idx] = off;
  cursor[idx] = off;
  if (idx == 0) offsets[n] = E;
}

__global__ __launch_bounds__(256) void bucket_fill(const void* __restrict__ eiv,
                                                   const int* __restrict__ flag,
                                                   int* __restrict__ cursor,
                                                   int* __restrict__ csr_src, int E) {
  int e = blockIdx.x * blockDim.x + threadIdx.x;
  if (e >= E) return;
  int is64 = *flag;
  int src = load_idx(eiv, is64, e);
  int dst = load_idx(eiv, is64, (long long)E + e);
  int pos = atomicAdd(&cursor[dst], 1);
  csr_src[pos] = src;
}

// ---------------------------------------------------------------------------
// prep_w: split Wl/Wr into bf16 hi/lo in MFMA fragment-blob order.
// ---------------------------------------------------------------------------
__global__ __launch_bounds__(256) void prep_w(const float* __restrict__ Wl,
                                              const float* __restrict__ Wr,
                                              unsigned short* __restrict__ Wcat) {
  int tid = blockIdx.x * 256 + threadIdx.x;
  if (tid >= 4 * 4 * 8 * 64) return;
  int lane = tid & 63;
  int nf   = (tid >> 6) & 7;
  int kc   = (tid >> 9) & 3;
  int part = tid >> 11;
  const float* W = (part < 2) ? Wl : Wr;
  bool lo = (part & 1);
  int ncol = nf * 16 + (lane & 15);
  int k0 = kc * 32 + (lane >> 4) * 8;
  unsigned short ov[8];
  #pragma unroll
  for (int j = 0; j < 8; ++j) {
    float v = W[(k0 + j) * H + ncol];
    unsigned short h = f2bf(v);
    ov[j] = lo ? f2bf(v - bf2f(h)) : h;
  }
  uint4 pack;
  pack.x = (unsigned)ov[0] | ((unsigned)ov[1] << 16);
  pack.y = (unsigned)ov[2] | ((unsigned)ov[3] << 16);
  pack.z = (unsigned)ov[4] | ((unsigned)ov[5] << 16);
  pack.w = (unsigned)ov[6] | ((unsigned)ov[7] << 16);
  *(uint4*)(Wcat + (size_t)tid * 8) = pack;
}

// ---------------------------------------------------------------------------
// dual_gemm<LOWP>: one pass over x computes BOTH
//   Y = fp8(x @ Wl)  -> Yf8 (ws)
//   P = x @ Wr + bl  -> bf16 Pbf (ws) if LOWP, else f32 pout (d_out)
// ---------------------------------------------------------------------------
template <bool LOWP>
__global__ __launch_bounds__(256) void dual_gemm(
    const float* __restrict__ x, const unsigned short* __restrict__ Wcat,
    const float* __restrict__ bl, unsigned char* __restrict__ Yf8,
    float* __restrict__ pout, unsigned short* __restrict__ Pbf, int n) {
  __shared__ unsigned short As[2][64][128];  // x_hi, x_lo

  const int t = threadIdx.x;
  const int i0 = blockIdx.x * 64;

  #pragma unroll
  for (int it = 0; it < 8; ++it) {
    int idx = it * 256 + t;
    int r = idx >> 5;
    int c4 = (idx & 31) * 4;
    int row_g = i0 + r; if (row_g >= n) row_g = n - 1;
    int boff = (((c4 >> 3) ^ (r & 7)) << 3) + (c4 & 7);
    float4 vx = *(const float4*)(x + (size_t)row_g * F + c4);
    unsigned short h0 = f2bf(vx.x), h1 = f2bf(vx.y), h2 = f2bf(vx.z), h3 = f2bf(vx.w);
    uint2 hv = { (unsigned)h0 | ((unsigned)h1 << 16), (unsigned)h2 | ((unsigned)h3 << 16) };
    *(uint2*)&As[0][r][boff] = hv;
    unsigned short l0 = f2bf(vx.x - bf2f(h0)), l1 = f2bf(vx.y - bf2f(h1));
    unsigned short l2 = f2bf(vx.z - bf2f(h2)), l3 = f2bf(vx.w - bf2f(h3));
    uint2 lv = { (unsigned)l0 | ((unsigned)l1 << 16), (unsigned)l2 | ((unsigned)l3 << 16) };
    *(uint2*)&As[1][r][boff] = lv;
  }
  __syncthreads();

  const int w = t >> 6;
  const int lane = t & 63;

  f32x4 accL[4][2], accR[4][2];
  #pragma unroll
  for (int rf = 0; rf < 4; ++rf)
    #pragma unroll
    for (int nfi = 0; nfi < 2; ++nfi) {
      accL[rf][nfi] = (f32x4){0.f, 0.f, 0.f, 0.f};
      accR[rf][nfi] = (f32x4){0.f, 0.f, 0.f, 0.f};
    }

  const int APM[3] = {0, 1, 0};
  const int BL[3]  = {0, 0, 1};   // Wl_hi, Wl_hi, Wl_lo
  const int BR[3]  = {2, 2, 3};   // Wr_hi, Wr_hi, Wr_lo

  #pragma unroll
  for (int pass = 0; pass < 3; ++pass) {
    const int ap = APM[pass];
    #pragma unroll
    for (int kc = 0; kc < 4; ++kc) {
      short8 afr[4];
      int chunk = kc * 4 + (lane >> 4);
      #pragma unroll
      for (int rf = 0; rf < 4; ++rf) {
        int row = rf * 16 + (lane & 15);
        afr[rf] = *(const short8*)(&As[ap][row][(chunk ^ (row & 7)) * 8]);
      }
      short8 bfrL[2], bfrR[2];
      #pragma unroll
      for (int nfi = 0; nfi < 2; ++nfi) {
        int blobL = (BL[pass] * 4 + kc) * 8 + (w * 2 + nfi);
        int blobR = (BR[pass] * 4 + kc) * 8 + (w * 2 + nfi);
        bfrL[nfi] = *(const short8*)(Wcat + (size_t)blobL * 512 + lane * 8);
        bfrR[nfi] = *(const short8*)(Wcat + (size_t)blobR * 512 + lane * 8);
      }
      #pragma unroll
      for (int rf = 0; rf < 4; ++rf)
        #pragma unroll
        for (int nfi = 0; nfi < 2; ++nfi) {
          accL[rf][nfi] = __builtin_amdgcn_mfma_f32_16x16x32_bf16(
              afr[rf], bfrL[nfi], accL[rf][nfi], 0, 0, 0);
          accR[rf][nfi] = __builtin_amdgcn_mfma_f32_16x16x32_bf16(
              afr[rf], bfrR[nfi], accR[rf][nfi], 0, 0, 0);
        }
    }
  }

  const float b0 = bl[w * 32 + (lane & 15)];
  const float b1 = bl[w * 32 + 16 + (lane & 15)];

  #pragma unroll
  for (int rf = 0; rf < 4; ++rf) {
    #pragma unroll
    for (int r4 = 0; r4 < 4; ++r4) {
      int rl = rf * 16 + (lane >> 4) * 4 + r4;
      int row = i0 + rl;
      if (row < n) {
        Yf8[(size_t)row * H + w * 32 + (lane & 15)]      = (unsigned char)f2fp8(accL[rf][0][r4]);
        Yf8[(size_t)row * H + w * 32 + 16 + (lane & 15)] = (unsigned char)f2fp8(accL[rf][1][r4]);
        if (LOWP) {
          Pbf[(size_t)row * H + w * 32 + (lane & 15)]      = f2bf(accR[rf][0][r4] + b0);
          Pbf[(size_t)row * H + w * 32 + 16 + (lane & 15)] = f2bf(accR[rf][1][r4] + b1);
        } else {
          pout[(size_t)row * H + w * 32 + (lane & 15)]      = accR[rf][0][r4] + b0;
          pout[(size_t)row * H + w * 32 + 16 + (lane & 15)] = accR[rf][1][r4] + b1;
        }
      }
    }
  }
}

// ---------------------------------------------------------------------------
// Mid path: f32 gather + double MFMA gemm.
// ---------------------------------------------------------------------------
__global__ __launch_bounds__(256) void gather_mean(const float* __restrict__ x,
                                                   const int* __restrict__ offsets,
                                                   const int* __restrict__ csr_src,
                                                   float* __restrict__ out, int n) {
  int node = (int)(((long long)blockIdx.x * blockDim.x + threadIdx.x) >> 6);
  int lane = threadIdx.x & 63;
  if (node >= n) return;
  int s = offsets[node], e = offsets[node + 1];
  float ax = 0.0f, ay = 0.0f, bx = 0.0f, by = 0.0f;
  int j = s;
  for (; j + 1 < e; j += 2) {
    int s0 = csr_src[j], s1 = csr_src[j + 1];
    float2 v0 = *(const float2*)(x + (size_t)s0 * F + lane * 2);
    float2 v1 = *(const float2*)(x + (size_t)s1 * F + lane * 2);
    ax += v0.x; ay += v0.y;
    bx += v1.x; by += v1.y;
  }
  if (j < e) {
    int s0 = csr_src[j];
    float2 v0 = *(const float2*)(x + (size_t)s0 * F + lane * 2);
    ax += v0.x; ay += v0.y;
  }
  float inv = 1.0f / fmaxf((float)(e - s), 1.0f);
  float2 r; r.x = (ax + bx) * inv; r.y = (ay + by) * inv;
  *(float2*)(out + (size_t)node * H + lane * 2) = r;
}

__global__ __launch_bounds__(256) void mfma_gemm(
    const float* __restrict__ x, const unsigned short* __restrict__ Wcat,
    const float* __restrict__ bl, float* __restrict__ out,
    float* __restrict__ colsum, float* __restrict__ colsq, int n) {
  __shared__ unsigned short As[4][64][128];
  __shared__ float rowsq[64][4];
  __shared__ float rscale[64];

  const int t = threadIdx.x;
  const int i0 = blockIdx.x * 64;

  #pragma unroll
  for (int it = 0; it < 8; ++it) {
    int idx = it * 256 + t;
    int r = idx >> 5;
    int c4 = (idx & 31) * 4;
    int row_g = i0 + r; if (row_g >= n) row_g = n - 1;
    int boff = (((c4 >> 3) ^ (r & 7)) << 3) + (c4 & 7);
    float4 va = *(const float4*)(out + (size_t)row_g * H + c4);
    float4 vx = *(const float4*)(x + (size_t)row_g * H + c4);
    unsigned short h0 = f2bf(va.x), h1 = f2bf(va.y), h2 = f2bf(va.z), h3 = f2bf(va.w);
    uint2 hv = { (unsigned)h0 | ((unsigned)h1 << 16), (unsigned)h2 | ((unsigned)h3 << 16) };
    *(uint2*)&As[0][r][boff] = hv;
    unsigned short l0 = f2bf(va.x - bf2f(h0)), l1 = f2bf(va.y - bf2f(h1));
    unsigned short l2 = f2bf(va.z - bf2f(h2)), l3 = f2bf(va.w - bf2f(h3));
    uint2 lv = { (unsigned)l0 | ((unsigned)l1 << 16), (unsigned)l2 | ((unsigned)l3 << 16) };
    *(uint2*)&As[1][r][boff] = lv;
    h0 = f2bf(vx.x); h1 = f2bf(vx.y); h2 = f2bf(vx.z); h3 = f2bf(vx.w);
    uint2 hx = { (unsigned)h0 | ((unsigned)h1 << 16), (unsigned)h2 | ((unsigned)h3 << 16) };
    *(uint2*)&As[2][r][boff] = hx;
    l0 = f2bf(vx.x - bf2f(h0)); l1 = f2bf(vx.y - bf2f(h1));
    l2 = f2bf(vx.z - bf2f(h2)); l3 = f2bf(vx.w - bf2f(h3));
    uint2 lx = { (unsigned)l0 | ((unsigned)l1 << 16), (unsigned)l2 | ((unsigned)l3 << 16) };
    *(uint2*)&As[3][r][boff] = lx;
  }
  __syncthreads();

  const int w = t >> 6;
  const int lane = t & 63;

  f32x4 acc[4][2];
  #pragma unroll
  for (int rf = 0; rf < 4; ++rf)
    #pragma unroll
    for (int nfi = 0; nfi < 2; ++nfi)
      acc[rf][nfi] = (f32x4){0.f, 0.f, 0.f, 0.f};

  const int APM[6] = {0, 1, 0, 2, 3, 2};
  const int BPM[6] = {0, 0, 1, 2, 2, 3};

  #pragma unroll
  for (int pass = 0; pass < 6; ++pass) {
    const int ap = APM[pass], bp = BPM[pass];
    #pragma unroll
    for (int kc = 0; kc < 4; ++kc) {
      short8 bfr[2];
      #pragma unroll
      for (int nfi = 0; nfi < 2; ++nfi) {
        int blob = (bp * 4 + kc) * 8 + (w * 2 + nfi);
        bfr[nfi] = *(const short8*)(Wcat + (size_t)blob * 512 + lane * 8);
      }
      short8 afr[4];
      int chunk = kc * 4 + (lane >> 4);
      #pragma unroll
      for (int rf = 0; rf < 4; ++rf) {
        int row = rf * 16 + (lane & 15);
        afr[rf] = *(const short8*)(&As[ap][row][(chunk ^ (row & 7)) * 8]);
      }
      #pragma unroll
      for (int rf = 0; rf < 4; ++rf)
        #pragma unroll
        for (int nfi = 0; nfi < 2; ++nfi)
          acc[rf][nfi] = __builtin_amdgcn_mfma_f32_16x16x32_bf16(
              afr[rf], bfr[nfi], acc[rf][nfi], 0, 0, 0);
    }
  }

  const float b0 = bl[w * 32 + (lane & 15)];
  const float b1 = bl[w * 32 + 16 + (lane & 15)];

  #pragma unroll
  for (int rf = 0; rf < 4; ++rf) {
    #pragma unroll
    for (int r4 = 0; r4 < 4; ++r4) {
      float v0 = acc[rf][0][r4] + b0;
      float v1 = acc[rf][1][r4] + b1;
      acc[rf][0][r4] = v0;
      acc[rf][1][r4] = v1;
      float sq = v0 * v0 + v1 * v1;
      sq += __shfl_xor(sq, 1, 64);
      sq += __shfl_xor(sq, 2, 64);
      sq += __shfl_xor(sq, 4, 64);
      sq += __shfl_xor(sq, 8, 64);
      if ((lane & 15) == 0) rowsq[rf * 16 + (lane >> 4) * 4 + r4][w] = sq;
    }
  }
  __syncthreads();
  if (t < 64) {
    float s = rowsq[t][0] + rowsq[t][1] + rowsq[t][2] + rowsq[t][3];
    rscale[t] = 1.0f / fmaxf(sqrtf(s), 1e-12f);
  }
  __syncthreads();

  float cs0 = 0.f, cq0 = 0.f, cs1 = 0.f, cq1 = 0.f;
  #pragma unroll
  for (int rf = 0; rf < 4; ++rf) {
    #pragma unroll
    for (int r4 = 0; r4 < 4; ++r4) {
      int rl = rf * 16 + (lane >> 4) * 4 + r4;
      int row = i0 + rl;
      float s = rscale[rl];
      float u0 = fmaxf(acc[rf][0][r4] * s, 0.f);
      float u1 = fmaxf(acc[rf][1][r4] * s, 0.f);
      if (row < n) {
        out[(size_t)row * H + w * 32 + (lane & 15)] = u0;
        out[(size_t)row * H + w * 32 + 16 + (lane & 15)] = u1;
        cs0 += u0; cq0 += u0 * u0;
        cs1 += u1; cq1 += u1 * u1;
      }
    }
  }
  cs0 += __shfl_xor(cs0, 16, 64); cs0 += __shfl_xor(cs0, 32, 64);
  cq0 += __shfl_xor(cq0, 16, 64); cq0 += __shfl_xor(cq0, 32, 64);
  cs1 += __shfl_xor(cs1, 16, 64); cs1 += __shfl_xor(cs1, 32, 64);
  cq1 += __shfl_xor(cq1, 16, 64); cq1 += __shfl_xor(cq1, 32, 64);
  if (lane < 16) {
    atomicAdd(&colsum[w * 32 + lane], cs0);
    atomicAdd(&colsq[w * 32 + lane], cq0);
    atomicAdd(&colsum[w * 32 + 16 + lane], cs1);
    atomicAdd(&colsq[w * 32 + 16 + lane], cq1);
  }
}

// ---------------------------------------------------------------------------
// Fallback path (tiny ws): atomic scatter + divide + scalar fused gemm.
// ---------------------------------------------------------------------------
__global__ __launch_bounds__(256) void scatter_mean(
    const float* __restrict__ x, const void* __restrict__ eiv,
    const int* __restrict__ flag, float* __restrict__ agg,
    float* __restrict__ deg, int E) {
  long long gid = (long long)blockIdx.x * blockDim.x + threadIdx.x;
  int e = (int)(gid >> 5);
  int ch = (int)(gid & 31);
  if (e >= E) return;
  int is64 = *flag;
  int src = load_idx(eiv, is64, e);
  int dst = load_idx(eiv, is64, (long long)E + e);
  float4 v = *(const float4*)(x + (size_t)src * F + ch * 4);
  float* a = agg + (size_t)dst * H + ch * 4;
  atomicAdd(a + 0, v.x);
  atomicAdd(a + 1, v.y);
  atomicAdd(a + 2, v.z);
  atomicAdd(a + 3, v.w);
  if (ch == 0) atomicAdd(deg + dst, 1.0f);
}

__global__ __launch_bounds__(256) void divide_deg(float* __restrict__ out,
                                                  const float* __restrict__ deg,
                                                  long long n4) {
  long long i = (long long)blockIdx.x * blockDim.x + threadIdx.x;
  if (i >= n4) return;
  int node = (int)(i >> 5);
  float s = 1.0f / fmaxf(deg[node], 1.0f);
  float4 v = ((float4*)out)[i];
  v.x *= s; v.y *= s; v.z *= s; v.w *= s;
  ((float4*)out)[i] = v;
}

__global__ __launch_bounds__(256) void fused_gemm(
    const float* __restrict__ x, const float* __restrict__ Wl,
    const float* __restrict__ bl, const float* __restrict__ Wr,
    float* __restrict__ out, float* __restrict__ colsum, float* __restrict__ colsq) {
  __shared__ float As[16][256];
  __shared__ float rp[4][8];
  __shared__ float rscale[16];
  __shared__ float cs[128], cs2[128];

  const int t = threadIdx.x;
  const int i0 = blockIdx.x * 16;

  #pragma unroll
  for (int it = 0; it < 2; ++it) {
    int idx = (it * 256 + t) * 4;
    int r = idx >> 7, c = idx & 127;
    float4 va = *(const float4*)(out + (size_t)(i0 + r) * H + c);
    As[r][c + 0] = va.x; As[r][c + 1] = va.y;
    As[r][c + 2] = va.z; As[r][c + 3] = va.w;
    float4 vx = *(const float4*)(x + (size_t)(i0 + r) * F + c);
    As[r][128 + c + 0] = vx.x; As[r][128 + c + 1] = vx.y;
    As[r][128 + c + 2] = vx.z; As[r][128 + c + 3] = vx.w;
  }
  __syncthreads();

  const int c = t & 127;
  const int half = t >> 7;
  float acc[8];
  #pragma unroll
  for (int r = 0; r < 8; ++r) acc[r] = 0.0f;

  #pragma unroll 4
  for (int k = 0; k < 128; ++k) {
    float w = Wl[k * H + c];
    #pragma unroll
    for (int r = 0; r < 8; ++r) acc[r] = fmaf(As[half * 8 + r][k], w, acc[r]);
  }
  #pragma unroll 4
  for (int k = 0; k < 128; ++k) {
    float w = Wr[k * H + c];
    #pragma unroll
    for (int r = 0; r < 8; ++r) acc[r] = fmaf(As[half * 8 + r][128 + k], w, acc[r]);
  }
  const float bias = bl[c];
  #pragma unroll
  for (int r = 0; r < 8; ++r) acc[r] += bias;

  float sq[8];
  #pragma unroll
  for (int r = 0; r < 8; ++r) sq[r] = acc[r] * acc[r];
  #pragma unroll
  for (int off = 32; off > 0; off >>= 1) {
    #pragma unroll
    for (int r = 0; r < 8; ++r) sq[r] += __shfl_down(sq[r], off, 64);
  }
  const int wv = t >> 6;
  if ((t & 63) == 0) {
    #pragma unroll
    for (int r = 0; r < 8; ++r) rp[wv][r] = sq[r];
  }
  __syncthreads();
  if (t < 16) {
    int base = (t >> 3) * 2, rr = t & 7;
    float s = rp[base][rr] + rp[base + 1][rr];
    rscale[t] = 1.0f / fmaxf(sqrtf(s), 1e-12f);
  }
  __syncthreads();

  float csum = 0.0f, csq = 0.0f;
  #pragma unroll
  for (int r = 0; r < 8; ++r) {
    float v = fmaxf(acc[r] * rscale[half * 8 + r], 0.0f);
    out[(size_t)(i0 + half * 8 + r) * H + c] = v;
    csum += v;
    csq += v * v;
  }
  if (half == 1) { cs[c] = csum; cs2[c] = csq; }
  __syncthreads();
  if (half == 0) {
    atomicAdd(&colsum[c], csum + cs[c]);
    atomicAdd(&colsq[c], csq + cs2[c]);
  }
}

__global__ void bn_stats(const float* __restrict__ colsum, const float* __restrict__ colsq,
                         const float* __restrict__ gamma, const float* __restrict__ beta,
                         float* __restrict__ scale, float* __restrict__ shift, int n) {
  int c = threadIdx.x;
  if (c < H) {
    float inv_n = 1.0f / (float)n;
    float mean = colsum[c] * inv_n;
    float var = colsq[c] * inv_n - mean * mean;  // biased (torch BN)
    float istd = rsqrtf(var + 1e-5f);
    float sc = gamma[c] * istd;
    scale[c] = sc;
    shift[c] = beta[c] - mean * sc;
  }
}

__global__ __launch_bounds__(256) void bn_apply(
    float* __restrict__ out, const float* __restrict__ scale,
    const float* __restrict__ shift, long long n4) {
  long long i = (long long)blockIdx.x * blockDim.x + threadIdx.x;
  if (i >= n4) return;
  float4 v = ((float4*)out)[i];
  int c = (int)((i * 4) & (H - 1));
  v.x = fmaf(v.x, scale[c + 0], shift[c + 0]);
  v.y = fmaf(v.y, scale[c + 1], shift[c + 1]);
  v.z = fmaf(v.z, scale[c + 2], shift[c + 2]);
  v.w = fmaf(v.w, scale[c + 3], shift[c + 3]);
  ((float4*)out)[i] = v;
}

// reads pre-BN u (bf16 in ws), writes final f32 to out
__global__ __launch_bounds__(256) void bn_apply_lo(
    const unsigned short* __restrict__ U, float* __restrict__ out,
    const float* __restrict__ scale, const float* __restrict__ shift,
    long long n4) {
  long long i = (long long)blockIdx.x * blockDim.x + threadIdx.x;
  if (i >= n4) return;
  uint2 uv = ((const uint2*)U)[i];
  int c = (int)((i * 4) & (H - 1));
  float4 v;
  v.x = fmaf(bits2f(uv.x << 16),          scale[c + 0], shift[c + 0]);
  v.y = fmaf(bits2f(uv.x & 0xFFFF0000u),  scale[c + 1], shift[c + 1]);
  v.z = fmaf(bits2f(uv.y << 16),          scale[c + 2], shift[c + 2]);
  v.w = fmaf(bits2f(uv.y & 0xFFFF0000u),  scale[c + 3], shift[c + 3]);
  ((float4*)out)[i] = v;
}

extern "C" void kernel_launch(void* const* d_in, const int* in_sizes, int n_in,
                              void* d_out, int out_size, void* d_ws, size_t ws_size,
                              hipStream_t stream) {
  const float* x     = (const float*)d_in[0];
  const void*  ei    = d_in[1];
  const float* Wl    = (const float*)d_in[2];
  const float* bl    = (const float*)d_in[3];
  const float* Wr    = (const float*)d_in[4];
  const float* gamma = (const float*)d_in[5];
  const float* beta  = (const float*)d_in[6];
  float* out = (float*)d_out;

  const int n = in_sizes[0] / F;   // 100000
  const int E = in_sizes[1] / 2;   // 1600000
  const int nb = (n + 255) / 256;
  const int nbuck = (n + 63) >> 6; // 64-node buckets

  char* ws = (char*)d_ws;
  int* flag = (int*)ws;
  unsigned short* Wcat = (unsigned short*)(ws + 256);
  char* after_w = ws + 256 + 4 * 128 * 128 * 2;

  // ---- fast-path layout: partition + Y fp8 (+P,U bf16) ----
  int*   cmat    = (int*)after_w;
  int*   obuf    = cmat + 2048 * NPART;
  int*   bsum    = obuf + 2048 * NPART;
  int*   boff    = bsum + 1024;
  int*   bbase   = boff + 1024;
  float* fcs     = (float*)(bbase + 2049);
  float* fcq     = fcs + H;
  float* fsc     = fcq + H;
  float* fsh     = fsc + H;
  int*   ebuf    = (int*)(fsh + H);
  unsigned char*  Yf8 = (unsigned char*)(ebuf + E);
  unsigned short* Pws = (unsigned short*)(Yf8 + (size_t)n * H);
  unsigned short* Uws = Pws + (size_t)n * H;
  size_t need_fast  = (size_t)((char*)(Yf8 + (size_t)n * H) - ws);
  size_t need_fast2 = (size_t)((char*)(Uws + (size_t)n * H) - ws);

  // ---- mid-path layout: CSR ----
  int*   degi     = (int*)after_w;
  int*   offsets  = degi + n;
  int*   cursor   = offsets + n + 1;
  int*   blocksum = cursor + n;
  int*   blockoff = blocksum + nb;
  float* mcs      = (float*)(blockoff + nb);
  float* mcq      = mcs + H;
  float* msc      = mcq + H;
  float* msh      = msc + H;
  int*   csr_src  = (int*)(msh + H);
  size_t need_mid = (size_t)((char*)(csr_src + E) - ws);

  float *colsum, *colsq, *scale, *shift;

  const int eb = (E + 255) / 256;
  const int gb = (n + 63) / 64;
  const long long n4 = (long long)n * H / 4;

  if (ws_size >= need_fast && nbuck <= 2048) {
    const bool lowp = (ws_size >= need_fast2);
    colsum = fcs; colsq = fcq; scale = fsc; shift = fsh;

    prep_w<<<32, 256, 0, stream>>>(Wl, Wr, Wcat);
    if (lowp)
      dual_gemm<true><<<gb, 256, 0, stream>>>(x, Wcat, bl, Yf8, out, Pws, n);
    else
      dual_gemm<false><<<gb, 256, 0, stream>>>(x, Wcat, bl, Yf8, out, Pws, n);

    const int chunk = (E + NPART - 1) / NPART;
    const int L = nbuck * NPART;
    const int nb2 = (L + 255) / 256;   // <= 1024
    part_hist<<<NPART, 512, 0, stream>>>(ei, cmat, E, nbuck, chunk);
    scan1<<<nb2, 256, 0, stream>>>(cmat, obuf, bsum, L);
    scan2big<<<1, 1024, 0, stream>>>(bsum, boff, nb2);
    scan3p<<<nb2, 256, 0, stream>>>(obuf, boff, bbase, colsum, L, nbuck, E);
    part_scatter<<<NPART, 512, 0, stream>>>(ei, obuf, ebuf, E, nbuck, chunk);

    if (lowp)
      gather_bucket<true><<<nbuck, 256, 0, stream>>>(
          Yf8, ebuf, bbase, out, Pws, Uws, colsum, colsq, n);
    else
      gather_bucket<false><<<nbuck, 256, 0, stream>>>(
          Yf8, ebuf, bbase, out, Pws, Uws, colsum, colsq, n);

    bn_stats<<<1, 128, 0, stream>>>(colsum, colsq, gamma, beta, scale, shift, n);
    if (lowp)
      bn_apply_lo<<<(int)((n4 + 255) / 256), 256, 0, stream>>>(
          Uws, out, scale, shift, n4);
    else
      bn_apply<<<(int)((n4 + 255) / 256), 256, 0, stream>>>(out, scale, shift, n4);
  } else if (ws_size >= need_mid) {
    colsum = mcs; colsq = mcq; scale = msc; shift = msh;
    detect_dtype<<<1, 64, 0, stream>>>((const unsigned*)ei, flag);
    hipMemsetAsync(degi, 0, (size_t)n * 4, stream);
    hipMemsetAsync(colsum, 0, 2 * H * 4, stream);

    prep_w<<<32, 256, 0, stream>>>(Wl, Wr, Wcat);

    deg_count<<<eb, 256, 0, stream>>>(ei, flag, degi, E);
    scan1<<<nb, 256, 0, stream>>>(degi, offsets, blocksum, n);
    scan2big<<<1, 1024, 0, stream>>>(blocksum, blockoff, nb);
    scan3<<<nb, 256, 0, stream>>>(offsets, blockoff, cursor, n, E);
    bucket_fill<<<eb, 256, 0, stream>>>(ei, flag, cursor, csr_src, E);

    long long gthreads = (long long)n * 64;
    gather_mean<<<(int)((gthreads + 255) / 256), 256, 0, stream>>>(
        x, offsets, csr_src, out, n);

    mfma_gemm<<<gb, 256, 0, stream>>>(x, Wcat, bl, out, colsum, colsq, n);
    bn_stats<<<1, 128, 0, stream>>>(colsum, colsq, gamma, beta, scale, shift, n);
    bn_apply<<<(int)((n4 + 255) / 256), 256, 0, stream>>>(out, scale, shift, n4);
  } else {
    float* deg = (float*)(ws + 256);
    colsum = deg + n; colsq = colsum + H; scale = colsq + H; shift = scale + H;
    detect_dtype<<<1, 64, 0, stream>>>((const unsigned*)ei, flag);
    hipMemsetAsync(d_out, 0, (size_t)out_size * sizeof(float), stream);
    hipMemsetAsync(deg, 0, (size_t)n * 4 + 4 * H * 4, stream);
    long long sthreads = (long long)E * 32;
    scatter_mean<<<(int)((sthreads + 255) / 256), 256, 0, stream>>>(x, ei, flag, out, deg, E);
    long long n4f = (long long)n * H / 4;
    divide_deg<<<(int)((n4f + 255) / 256), 256, 0, stream>>>(out, deg, n4f);
    fused_gemm<<<n / 16, 256, 0, stream>>>(x, Wl, bl, Wr, out, colsum, colsq);
    bn_stats<<<1, 128, 0, stream>>>(colsum, colsq, gamma, beta, scale, shift, n);
    bn_apply<<<(int)((n4 + 255) / 256), 256, 0, stream>>>(out, scale, shift, n4);
  }
}

// Round 11
// 203.784 us; speedup vs baseline: 1.3024x; 1.1100x over previous
//
#include <hip/hip_runtime.h>
#include <hip/hip_bf16.h>

static constexpr int F = 128;
static constexpr int H = 128;
static constexpr int NPART = 128;   // partition blocks (contiguous edge chunks)

typedef __attribute__((ext_vector_type(8))) short short8;
typedef __attribute__((ext_vector_type(4))) float f32x4;

__device__ __forceinline__ unsigned short f2bf(float f) {
  union { float f; unsigned u; } a; a.f = f;
  unsigned r = a.u + 0x7FFF + ((a.u >> 16) & 1);
  return (unsigned short)(r >> 16);
}
__device__ __forceinline__ float bf2f(unsigned short h) {
  union { unsigned u; float f; } a; a.u = ((unsigned)h) << 16;
  return a.f;
}
__device__ __forceinline__ float bits2f(unsigned u) {
  union { unsigned u; float f; } a; a.u = u;
  return a.f;
}

// f32 -> fp8 e4m3fn (RNE, flush-to-zero below 2^-6, clamp to 448)
__device__ __forceinline__ unsigned f2fp8(float f) {
  union { float f; unsigned u; } a; a.f = f;
  unsigned s = (a.u >> 24) & 0x80u;
  unsigned m = a.u & 0x7FFFFFFFu;
  if (m < 0x3C800000u) return s;                 // |f| < 2^-6 -> signed zero code
  unsigned r = m + 0x7FFFFu + ((m >> 20) & 1u);  // RNE to 3 mantissa bits
  if (r > 0x43E00000u) r = 0x43E00000u;          // clamp to 448 (max finite)
  return s | ((((r >> 23) - 120u) & 15u) << 3) | ((r >> 20) & 7u);
}

// FAST packed decode: 4 fp8 e4m3 bytes -> 4 f32. Code 0/0x80 decodes to
// +/-2^-7 (0.0078) -- encode flushed |v|<2^-6, so error on flushed values is
// HALVED vs flush-to-zero (no per-value select needed).
// bf16 halfword = sign<<8 | (mag<<4) + 0x3C00; no carry across halves
// (max 0x43F0 < 0x10000) so two values convert per 32-bit op.
__device__ __forceinline__ void fp8x4_to_f32(unsigned w, float& f0, float& f1,
                                             float& f2, float& f3) {
  unsigned lo = w & 0x00FF00FFu;          // bytes 0,2 in halfword slots
  unsigned hi = (w >> 8) & 0x00FF00FFu;   // bytes 1,3
  unsigned p0 = (((lo << 4) & 0x07F007F0u) + 0x3C003C00u) | ((lo & 0x00800080u) << 8);
  unsigned p1 = (((hi << 4) & 0x07F007F0u) + 0x3C003C00u) | ((hi & 0x00800080u) << 8);
  f0 = bits2f(p0 << 16);
  f2 = bits2f(p0 & 0xFFFF0000u);
  f1 = bits2f(p1 << 16);
  f3 = bits2f(p1 & 0xFFFF0000u);
}

// int64-vs-int32 edge_index detection (values < 2^17 -> int64 hi words all 0)
__device__ __forceinline__ int detect64(const void* eiv) {
  const unsigned* u = (const unsigned*)eiv;
  int is64 = 1;
  for (int i = 0; i < 64; ++i) is64 &= (u[2 * i + 1] == 0u);
  return is64;
}

__global__ void detect_dtype(const unsigned* __restrict__ ei, int* __restrict__ flag) {
  if (blockIdx.x == 0 && threadIdx.x == 0) {
    int is64 = 1;
    for (int i = 0; i < 64; ++i) {
      if (ei[2 * i + 1] != 0u) { is64 = 0; break; }
    }
    *flag = is64;
  }
}

__device__ __forceinline__ int load_idx(const void* eiv, int is64, long long pos) {
  return is64 ? (int)((const long long*)eiv)[pos] : ((const int*)eiv)[pos];
}

// ---------------------------------------------------------------------------
// Two-pass atomic-free partition into 64-node dst buckets.
// pack = (src << 6) | (dst & 63)
// ---------------------------------------------------------------------------
__global__ __launch_bounds__(512) void part_hist(const void* __restrict__ eiv,
                                                 int* __restrict__ cmat,
                                                 int E, int nbuck, int chunk) {
  __shared__ int h[2048];
  const int t = threadIdx.x, b = blockIdx.x;
  for (int i = t; i < nbuck; i += 512) h[i] = 0;
  __syncthreads();
  int is64 = detect64(eiv);
  int s = b * chunk, e = min(E, s + chunk);
  for (int i = s + t; i < e; i += 512) {
    int dst = load_idx(eiv, is64, (long long)E + i);
    atomicAdd(&h[dst >> 6], 1);
  }
  __syncthreads();
  for (int i = t; i < nbuck; i += 512) cmat[i * NPART + b] = h[i];
}

__global__ __launch_bounds__(256) void scan1(const int* __restrict__ in,
                                             int* __restrict__ outx,
                                             int* __restrict__ blocksum, int n) {
  __shared__ int sm[256];
  int idx = blockIdx.x * 256 + threadIdx.x;
  int v = (idx < n) ? in[idx] : 0;
  sm[threadIdx.x] = v;
  __syncthreads();
  #pragma unroll
  for (int off = 1; off < 256; off <<= 1) {
    int t = (threadIdx.x >= off) ? sm[threadIdx.x - off] : 0;
    __syncthreads();
    sm[threadIdx.x] += t;
    __syncthreads();
  }
  if (idx < n) outx[idx] = sm[threadIdx.x] - v;
  if (threadIdx.x == 255) blocksum[blockIdx.x] = sm[255];
}

__global__ __launch_bounds__(1024) void scan2big(const int* __restrict__ blocksum,
                                                 int* __restrict__ blockoff, int nb) {
  __shared__ int sm[1024];
  int t = threadIdx.x;
  int v = (t < nb) ? blocksum[t] : 0;
  sm[t] = v;
  __syncthreads();
  for (int off = 1; off < 1024; off <<= 1) {
    int u = (t >= off) ? sm[t - off] : 0;
    __syncthreads();
    sm[t] += u;
    __syncthreads();
  }
  if (t < nb) blockoff[t] = sm[t] - v;
}

// finalize partition scan: base matrix in place + bucket segment starts.
// Block 0 also zeroes colsum/colsq (256 contiguous floats).
__global__ __launch_bounds__(256) void scan3p(int* __restrict__ obuf,
                                              const int* __restrict__ blockoff,
                                              int* __restrict__ bbase,
                                              float* __restrict__ colzero,
                                              int L, int nbuck, int E) {
  if (blockIdx.x == 0) colzero[threadIdx.x] = 0.0f;
  int idx = blockIdx.x * 256 + threadIdx.x;
  if (idx >= L) return;
  int v = obuf[idx] + blockoff[idx >> 8];
  obuf[idx] = v;
  if ((idx & (NPART - 1)) == 0) bbase[idx / NPART] = v;
  if (idx == 0) bbase[nbuck] = E;
}

__global__ __launch_bounds__(512) void part_scatter(const void* __restrict__ eiv,
                                                    const int* __restrict__ base,
                                                    int* __restrict__ ebuf,
                                                    int E, int nbuck, int chunk) {
  __shared__ int cur[2048];
  const int t = threadIdx.x, b = blockIdx.x;
  for (int i = t; i < nbuck; i += 512) cur[i] = base[i * NPART + b];
  __syncthreads();
  int is64 = detect64(eiv);
  int s = b * chunk, e = min(E, s + chunk);
  for (int i = s + t; i < e; i += 512) {
    int src = load_idx(eiv, is64, i);
    int dst = load_idx(eiv, is64, (long long)E + i);
    int pos = atomicAdd(&cur[dst >> 6], 1);
    ebuf[pos] = (src << 6) | (dst & 63);
  }
}

// ---------------------------------------------------------------------------
// gather_bucket<LOWP>: one block per 64-node bucket (round-8 proven layout:
// 2 nodes/wave, 32 lanes/node, 8-deep unroll). Y is fp8 e4m3 (4 B/lane/row),
// decoded with the packed fast path (fp8x4_to_f32).
// Fused epilogue: v = P + agg; row-L2-norm; ReLU; store u; BN col stats.
// LOWP=true : P read bf16 (Pbf), u written bf16 (Ubf).
// LOWP=false: P read / u write f32 in pio (d_out).
// ---------------------------------------------------------------------------
#define GCAP 2048
template <bool LOWP>
__global__ __launch_bounds__(256) void gather_bucket(
    const unsigned char* __restrict__ Yf8, const int* __restrict__ ebuf,
    const int* __restrict__ bbase, float* __restrict__ pio,
    const unsigned short* __restrict__ Pbf, unsigned short* __restrict__ Ubf,
    float* __restrict__ colsum, float* __restrict__ colsq, int n) {
  __shared__ int lsrc[GCAP];
  __shared__ int hist[65];
  __shared__ int loff[65];
  __shared__ int cur[64];
  __shared__ float csm[128], cqm[128];

  const int t = threadIdx.x;
  const int b = blockIdx.x;
  const int node0 = b << 6;
  const int s = bbase[b], e = bbase[b + 1];
  const int cnt = e - s;

  if (t < 65) hist[t] = 0;
  if (t < 128) { csm[t] = 0.f; cqm[t] = 0.f; }
  __syncthreads();

  const bool fast = (cnt <= GCAP);
  if (fast) {
    for (int i = s + t; i < e; i += 256)
      atomicAdd(&hist[ebuf[i] & 63], 1);
    __syncthreads();
    if (t < 64) loff[t] = hist[t];
    __syncthreads();
    #pragma unroll
    for (int off = 1; off < 64; off <<= 1) {
      int u = (t >= off && t < 64) ? loff[t - off] : 0;
      __syncthreads();
      if (t < 64) loff[t] += u;
      __syncthreads();
    }
    if (t < 64) cur[t] = loff[t] - hist[t];
    __syncthreads();
    for (int i = s + t; i < e; i += 256) {
      int p = ebuf[i];
      int pos = atomicAdd(&cur[p & 63], 1);
      lsrc[pos] = p >> 6;
    }
    __syncthreads();
  }

  const int lane = t & 63;
  const int w = t >> 6;
  const int half = lane >> 5;
  const int c = (lane & 31) * 4;   // element/byte column (4 per lane)

  float lcs[4] = {0.f, 0.f, 0.f, 0.f};
  float lcq[4] = {0.f, 0.f, 0.f, 0.f};

  #pragma unroll
  for (int it = 0; it < 8; ++it) {
    int ln = it * 8 + w * 2 + half;
    int node = node0 + ln;
    if (node >= n) continue;
    int ls, le;
    if (fast) { ls = loff[ln] - hist[ln]; le = loff[ln]; }
    else      { ls = 0; le = 0; }

    float acc[8][4];
    #pragma unroll
    for (int u = 0; u < 8; ++u)
      #pragma unroll
      for (int q = 0; q < 4; ++q) acc[u][q] = 0.0f;

    int j = ls;
    for (; j + 7 < le; j += 8) {
      #pragma unroll
      for (int u = 0; u < 8; ++u) {
        int sj = lsrc[j + u];
        unsigned wv = *(const unsigned*)(Yf8 + (size_t)sj * H + c);
        float f0, f1, f2, f3;
        fp8x4_to_f32(wv, f0, f1, f2, f3);
        acc[u][0] += f0; acc[u][1] += f1; acc[u][2] += f2; acc[u][3] += f3;
      }
    }
    for (; j + 1 < le; j += 2) {
      #pragma unroll
      for (int u = 0; u < 2; ++u) {
        int sj = lsrc[j + u];
        unsigned wv = *(const unsigned*)(Yf8 + (size_t)sj * H + c);
        float f0, f1, f2, f3;
        fp8x4_to_f32(wv, f0, f1, f2, f3);
        acc[u][0] += f0; acc[u][1] += f1; acc[u][2] += f2; acc[u][3] += f3;
      }
    }
    if (j < le) {
      int sj = lsrc[j];
      unsigned wv = *(const unsigned*)(Yf8 + (size_t)sj * H + c);
      float f0, f1, f2, f3;
      fp8x4_to_f32(wv, f0, f1, f2, f3);
      acc[0][0] += f0; acc[0][1] += f1; acc[0][2] += f2; acc[0][3] += f3;
    }

    float deg = 0.0f;
    float a0, a1, a2, a3;
    if (fast) {
      deg = (float)(le - ls);
      #pragma unroll
      for (int u = 4; u < 8; ++u) {
        acc[u - 4][0] += acc[u][0]; acc[u - 4][1] += acc[u][1];
        acc[u - 4][2] += acc[u][2]; acc[u - 4][3] += acc[u][3];
      }
      a0 = (acc[0][0] + acc[1][0]) + (acc[2][0] + acc[3][0]);
      a1 = (acc[0][1] + acc[1][1]) + (acc[2][1] + acc[3][1]);
      a2 = (acc[0][2] + acc[1][2]) + (acc[2][2] + acc[3][2]);
      a3 = (acc[0][3] + acc[1][3]) + (acc[2][3] + acc[3][3]);
    } else {
      // slow path (statistically unreachable): scan whole bucket
      a0 = a1 = a2 = a3 = 0.0f;
      for (int jj = s; jj < e; ++jj) {
        int p = ebuf[jj];
        if ((p & 63) == ln) {
          deg += 1.0f;
          unsigned wv = *(const unsigned*)(Yf8 + (size_t)(p >> 6) * H + c);
          float f0, f1, f2, f3;
          fp8x4_to_f32(wv, f0, f1, f2, f3);
          a0 += f0; a1 += f1; a2 += f2; a3 += f3;
        }
      }
    }

    float inv = 1.0f / fmaxf(deg, 1.0f);
    float p0, p1, p2, p3;
    if (LOWP) {
      uint2 pv = *(const uint2*)(Pbf + (size_t)node * H + c);
      p0 = bits2f(pv.x << 16);
      p1 = bits2f(pv.x & 0xFFFF0000u);
      p2 = bits2f(pv.y << 16);
      p3 = bits2f(pv.y & 0xFFFF0000u);
    } else {
      float4 p = *(const float4*)(pio + (size_t)node * H + c);
      p0 = p.x; p1 = p.y; p2 = p.z; p3 = p.w;
    }
    float v0 = p0 + a0 * inv;
    float v1 = p1 + a1 * inv;
    float v2 = p2 + a2 * inv;
    float v3 = p3 + a3 * inv;
    float sq = v0 * v0 + v1 * v1 + v2 * v2 + v3 * v3;
    sq += __shfl_xor(sq, 1, 64);
    sq += __shfl_xor(sq, 2, 64);
    sq += __shfl_xor(sq, 4, 64);
    sq += __shfl_xor(sq, 8, 64);
    sq += __shfl_xor(sq, 16, 64);
    float rs = 1.0f / fmaxf(sqrtf(sq), 1e-12f);
    float u0 = fmaxf(v0 * rs, 0.f), u1 = fmaxf(v1 * rs, 0.f);
    float u2 = fmaxf(v2 * rs, 0.f), u3 = fmaxf(v3 * rs, 0.f);
    if (LOWP) {
      uint2 ov;
      ov.x = (unsigned)f2bf(u0) | ((unsigned)f2bf(u1) << 16);
      ov.y = (unsigned)f2bf(u2) | ((unsigned)f2bf(u3) << 16);
      *(uint2*)(Ubf + (size_t)node * H + c) = ov;
    } else {
      float4 o = {u0, u1, u2, u3};
      *(float4*)(pio + (size_t)node * H + c) = o;
    }
    lcs[0] += u0; lcq[0] += u0 * u0;
    lcs[1] += u1; lcq[1] += u1 * u1;
    lcs[2] += u2; lcq[2] += u2 * u2;
    lcs[3] += u3; lcq[3] += u3 * u3;
  }

  #pragma unroll
  for (int q = 0; q < 4; ++q) {
    atomicAdd(&csm[c + q], lcs[q]);
    atomicAdd(&cqm[c + q], lcq[q]);
  }
  __syncthreads();
  if (t < 128) {
    atomicAdd(&colsum[t], csm[t]);
    atomicAdd(&colsq[t], cqm[t]);
  }
}

// ---------------------------------------------------------------------------
// CSR build (mid fallback path)
// ---------------------------------------------------------------------------
__global__ __launch_bounds__(256) void deg_count(const void* __restrict__ eiv,
                                                 const int* __restrict__ flag,
                                                 int* __restrict__ degi, int E) {
  int e = blockIdx.x * blockDim.x + threadIdx.x;
  if (e >= E) return;
  int dst = load_idx(eiv, *flag, (long long)E + e);
  atomicAdd(&degi[dst], 1);
}

__global__ __launch_bounds__(256) void scan3(int* __restrict__ offsets,
                                             const int* __restrict__ blockoff,
                                             int* __restrict__ cursor, int n, int E) {
  int idx = blockIdx.x * 256 + threadIdx.x;
  if (idx >= n) return;
  int off = offsets[idx] + blockoff[idx >> 8];
  offsets[idx] = off;
  cursor[idx] = off;
  if (idx == 0) offsets[n] = E;
}

__global__ __launch_bounds__(256) void bucket_fill(const void* __restrict__ eiv,
                                                   const int* __restrict__ flag,
                                                   int* __restrict__ cursor,
                                                   int* __restrict__ csr_src, int E) {
  int e = blockIdx.x * blockDim.x + threadIdx.x;
  if (e >= E) return;
  int is64 = *flag;
  int src = load_idx(eiv, is64, e);
  int dst = load_idx(eiv, is64, (long long)E + e);
  int pos = atomicAdd(&cursor[dst], 1);
  csr_src[pos] = src;
}

// ---------------------------------------------------------------------------
// prep_w: split Wl/Wr into bf16 hi/lo in MFMA fragment-blob order.
// ---------------------------------------------------------------------------
__global__ __launch_bounds__(256) void prep_w(const float* __restrict__ Wl,
                                              const float* __restrict__ Wr,
                                              unsigned short* __restrict__ Wcat) {
  int tid = blockIdx.x * 256 + threadIdx.x;
  if (tid >= 4 * 4 * 8 * 64) return;
  int lane = tid & 63;
  int nf   = (tid >> 6) & 7;
  int kc   = (tid >> 9) & 3;
  int part = tid >> 11;
  const float* W = (part < 2) ? Wl : Wr;
  bool lo = (part & 1);
  int ncol = nf * 16 + (lane & 15);
  int k0 = kc * 32 + (lane >> 4) * 8;
  unsigned short ov[8];
  #pragma unroll
  for (int j = 0; j < 8; ++j) {
    float v = W[(k0 + j) * H + ncol];
    unsigned short h = f2bf(v);
    ov[j] = lo ? f2bf(v - bf2f(h)) : h;
  }
  uint4 pack;
  pack.x = (unsigned)ov[0] | ((unsigned)ov[1] << 16);
  pack.y = (unsigned)ov[2] | ((unsigned)ov[3] << 16);
  pack.z = (unsigned)ov[4] | ((unsigned)ov[5] << 16);
  pack.w = (unsigned)ov[6] | ((unsigned)ov[7] << 16);
  *(uint4*)(Wcat + (size_t)tid * 8) = pack;
}

// ---------------------------------------------------------------------------
// dual_gemm<LOWP>: one pass over x computes BOTH
//   Y = fp8(x @ Wl)  -> Yf8 (ws)
//   P = x @ Wr + bl  -> bf16 Pbf (ws) if LOWP, else f32 pout (d_out)
// ---------------------------------------------------------------------------
template <bool LOWP>
__global__ __launch_bounds__(256) void dual_gemm(
    const float* __restrict__ x, const unsigned short* __restrict__ Wcat,
    const float* __restrict__ bl, unsigned char* __restrict__ Yf8,
    float* __restrict__ pout, unsigned short* __restrict__ Pbf, int n) {
  __shared__ unsigned short As[2][64][128];  // x_hi, x_lo

  const int t = threadIdx.x;
  const int i0 = blockIdx.x * 64;

  #pragma unroll
  for (int it = 0; it < 8; ++it) {
    int idx = it * 256 + t;
    int r = idx >> 5;
    int c4 = (idx & 31) * 4;
    int row_g = i0 + r; if (row_g >= n) row_g = n - 1;
    int boff = (((c4 >> 3) ^ (r & 7)) << 3) + (c4 & 7);
    float4 vx = *(const float4*)(x + (size_t)row_g * F + c4);
    unsigned short h0 = f2bf(vx.x), h1 = f2bf(vx.y), h2 = f2bf(vx.z), h3 = f2bf(vx.w);
    uint2 hv = { (unsigned)h0 | ((unsigned)h1 << 16), (unsigned)h2 | ((unsigned)h3 << 16) };
    *(uint2*)&As[0][r][boff] = hv;
    unsigned short l0 = f2bf(vx.x - bf2f(h0)), l1 = f2bf(vx.y - bf2f(h1));
    unsigned short l2 = f2bf(vx.z - bf2f(h2)), l3 = f2bf(vx.w - bf2f(h3));
    uint2 lv = { (unsigned)l0 | ((unsigned)l1 << 16), (unsigned)l2 | ((unsigned)l3 << 16) };
    *(uint2*)&As[1][r][boff] = lv;
  }
  __syncthreads();

  const int w = t >> 6;
  const int lane = t & 63;

  f32x4 accL[4][2], accR[4][2];
  #pragma unroll
  for (int rf = 0; rf < 4; ++rf)
    #pragma unroll
    for (int nfi = 0; nfi < 2; ++nfi) {
      accL[rf][nfi] = (f32x4){0.f, 0.f, 0.f, 0.f};
      accR[rf][nfi] = (f32x4){0.f, 0.f, 0.f, 0.f};
    }

  const int APM[3] = {0, 1, 0};
  const int BL[3]  = {0, 0, 1};   // Wl_hi, Wl_hi, Wl_lo
  const int BR[3]  = {2, 2, 3};   // Wr_hi, Wr_hi, Wr_lo

  #pragma unroll
  for (int pass = 0; pass < 3; ++pass) {
    const int ap = APM[pass];
    #pragma unroll
    for (int kc = 0; kc < 4; ++kc) {
      short8 afr[4];
      int chunk = kc * 4 + (lane >> 4);
      #pragma unroll
      for (int rf = 0; rf < 4; ++rf) {
        int row = rf * 16 + (lane & 15);
        afr[rf] = *(const short8*)(&As[ap][row][(chunk ^ (row & 7)) * 8]);
      }
      short8 bfrL[2], bfrR[2];
      #pragma unroll
      for (int nfi = 0; nfi < 2; ++nfi) {
        int blobL = (BL[pass] * 4 + kc) * 8 + (w * 2 + nfi);
        int blobR = (BR[pass] * 4 + kc) * 8 + (w * 2 + nfi);
        bfrL[nfi] = *(const short8*)(Wcat + (size_t)blobL * 512 + lane * 8);
        bfrR[nfi] = *(const short8*)(Wcat + (size_t)blobR * 512 + lane * 8);
      }
      #pragma unroll
      for (int rf = 0; rf < 4; ++rf)
        #pragma unroll
        for (int nfi = 0; nfi < 2; ++nfi) {
          accL[rf][nfi] = __builtin_amdgcn_mfma_f32_16x16x32_bf16(
              afr[rf], bfrL[nfi], accL[rf][nfi], 0, 0, 0);
          accR[rf][nfi] = __builtin_amdgcn_mfma_f32_16x16x32_bf16(
              afr[rf], bfrR[nfi], accR[rf][nfi], 0, 0, 0);
        }
    }
  }

  const float b0 = bl[w * 32 + (lane & 15)];
  const float b1 = bl[w * 32 + 16 + (lane & 15)];

  #pragma unroll
  for (int rf = 0; rf < 4; ++rf) {
    #pragma unroll
    for (int r4 = 0; r4 < 4; ++r4) {
      int rl = rf * 16 + (lane >> 4) * 4 + r4;
      int row = i0 + rl;
      if (row < n) {
        Yf8[(size_t)row * H + w * 32 + (lane & 15)]      = (unsigned char)f2fp8(accL[rf][0][r4]);
        Yf8[(size_t)row * H + w * 32 + 16 + (lane & 15)] = (unsigned char)f2fp8(accL[rf][1][r4]);
        if (LOWP) {
          Pbf[(size_t)row * H + w * 32 + (lane & 15)]      = f2bf(accR[rf][0][r4] + b0);
          Pbf[(size_t)row * H + w * 32 + 16 + (lane & 15)] = f2bf(accR[rf][1][r4] + b1);
        } else {
          pout[(size_t)row * H + w * 32 + (lane & 15)]      = accR[rf][0][r4] + b0;
          pout[(size_t)row * H + w * 32 + 16 + (lane & 15)] = accR[rf][1][r4] + b1;
        }
      }
    }
  }
}

// ---------------------------------------------------------------------------
// Mid path: f32 gather + double MFMA gemm.
// ---------------------------------------------------------------------------
__global__ __launch_bounds__(256) void gather_mean(const float* __restrict__ x,
                                                   const int* __restrict__ offsets,
                                                   const int* __restrict__ csr_src,
                                                   float* __restrict__ out, int n) {
  int node = (int)(((long long)blockIdx.x * blockDim.x + threadIdx.x) >> 6);
  int lane = threadIdx.x & 63;
  if (node >= n) return;
  int s = offsets[node], e = offsets[node + 1];
  float ax = 0.0f, ay = 0.0f, bx = 0.0f, by = 0.0f;
  int j = s;
  for (; j + 1 < e; j += 2) {
    int s0 = csr_src[j], s1 = csr_src[j + 1];
    float2 v0 = *(const float2*)(x + (size_t)s0 * F + lane * 2);
    float2 v1 = *(const float2*)(x + (size_t)s1 * F + lane * 2);
    ax += v0.x; ay += v0.y;
    bx += v1.x; by += v1.y;
  }
  if (j < e) {
    int s0 = csr_src[j];
    float2 v0 = *(const float2*)(x + (size_t)s0 * F + lane * 2);
    ax += v0.x; ay += v0.y;
  }
  float inv = 1.0f / fmaxf((float)(e - s), 1.0f);
  float2 r; r.x = (ax + bx) * inv; r.y = (ay + by) * inv;
  *(float2*)(out + (size_t)node * H + lane * 2) = r;
}

__global__ __launch_bounds__(256) void mfma_gemm(
    const float* __restrict__ x, const unsigned short* __restrict__ Wcat,
    const float* __restrict__ bl, float* __restrict__ out,
    float* __restrict__ colsum, float* __restrict__ colsq, int n) {
  __shared__ unsigned short As[4][64][128];
  __shared__ float rowsq[64][4];
  __shared__ float rscale[64];

  const int t = threadIdx.x;
  const int i0 = blockIdx.x * 64;

  #pragma unroll
  for (int it = 0; it < 8; ++it) {
    int idx = it * 256 + t;
    int r = idx >> 5;
    int c4 = (idx & 31) * 4;
    int row_g = i0 + r; if (row_g >= n) row_g = n - 1;
    int boff = (((c4 >> 3) ^ (r & 7)) << 3) + (c4 & 7);
    float4 va = *(const float4*)(out + (size_t)row_g * H + c4);
    float4 vx = *(const float4*)(x + (size_t)row_g * H + c4);
    unsigned short h0 = f2bf(va.x), h1 = f2bf(va.y), h2 = f2bf(va.z), h3 = f2bf(va.w);
    uint2 hv = { (unsigned)h0 | ((unsigned)h1 << 16), (unsigned)h2 | ((unsigned)h3 << 16) };
    *(uint2*)&As[0][r][boff] = hv;
    unsigned short l0 = f2bf(va.x - bf2f(h0)), l1 = f2bf(va.y - bf2f(h1));
    unsigned short l2 = f2bf(va.z - bf2f(h2)), l3 = f2bf(va.w - bf2f(h3));
    uint2 lv = { (unsigned)l0 | ((unsigned)l1 << 16), (unsigned)l2 | ((unsigned)l3 << 16) };
    *(uint2*)&As[1][r][boff] = lv;
    h0 = f2bf(vx.x); h1 = f2bf(vx.y); h2 = f2bf(vx.z); h3 = f2bf(vx.w);
    uint2 hx = { (unsigned)h0 | ((unsigned)h1 << 16), (unsigned)h2 | ((unsigned)h3 << 16) };
    *(uint2*)&As[2][r][boff] = hx;
    l0 = f2bf(vx.x - bf2f(h0)); l1 = f2bf(vx.y - bf2f(h1));
    l2 = f2bf(vx.z - bf2f(h2)); l3 = f2bf(vx.w - bf2f(h3));
    uint2 lx = { (unsigned)l0 | ((unsigned)l1 << 16), (unsigned)l2 | ((unsigned)l3 << 16) };
    *(uint2*)&As[3][r][boff] = lx;
  }
  __syncthreads();

  const int w = t >> 6;
  const int lane = t & 63;

  f32x4 acc[4][2];
  #pragma unroll
  for (int rf = 0; rf < 4; ++rf)
    #pragma unroll
    for (int nfi = 0; nfi < 2; ++nfi)
      acc[rf][nfi] = (f32x4){0.f, 0.f, 0.f, 0.f};

  const int APM[6] = {0, 1, 0, 2, 3, 2};
  const int BPM[6] = {0, 0, 1, 2, 2, 3};

  #pragma unroll
  for (int pass = 0; pass < 6; ++pass) {
    const int ap = APM[pass], bp = BPM[pass];
    #pragma unroll
    for (int kc = 0; kc < 4; ++kc) {
      short8 bfr[2];
      #pragma unroll
      for (int nfi = 0; nfi < 2; ++nfi) {
        int blob = (bp * 4 + kc) * 8 + (w * 2 + nfi);
        bfr[nfi] = *(const short8*)(Wcat + (size_t)blob * 512 + lane * 8);
      }
      short8 afr[4];
      int chunk = kc * 4 + (lane >> 4);
      #pragma unroll
      for (int rf = 0; rf < 4; ++rf) {
        int row = rf * 16 + (lane & 15);
        afr[rf] = *(const short8*)(&As[ap][row][(chunk ^ (row & 7)) * 8]);
      }
      #pragma unroll
      for (int rf = 0; rf < 4; ++rf)
        #pragma unroll
        for (int nfi = 0; nfi < 2; ++nfi)
          acc[rf][nfi] = __builtin_amdgcn_mfma_f32_16x16x32_bf16(
              afr[rf], bfr[nfi], acc[rf][nfi], 0, 0, 0);
    }
  }

  const float b0 = bl[w * 32 + (lane & 15)];
  const float b1 = bl[w * 32 + 16 + (lane & 15)];

  #pragma unroll
  for (int rf = 0; rf < 4; ++rf) {
    #pragma unroll
    for (int r4 = 0; r4 < 4; ++r4) {
      float v0 = acc[rf][0][r4] + b0;
      float v1 = acc[rf][1][r4] + b1;
      acc[rf][0][r4] = v0;
      acc[rf][1][r4] = v1;
      float sq = v0 * v0 + v1 * v1;
      sq += __shfl_xor(sq, 1, 64);
      sq += __shfl_xor(sq, 2, 64);
      sq += __shfl_xor(sq, 4, 64);
      sq += __shfl_xor(sq, 8, 64);
      if ((lane & 15) == 0) rowsq[rf * 16 + (lane >> 4) * 4 + r4][w] = sq;
    }
  }
  __syncthreads();
  if (t < 64) {
    float s = rowsq[t][0] + rowsq[t][1] + rowsq[t][2] + rowsq[t][3];
    rscale[t] = 1.0f / fmaxf(sqrtf(s), 1e-12f);
  }
  __syncthreads();

  float cs0 = 0.f, cq0 = 0.f, cs1 = 0.f, cq1 = 0.f;
  #pragma unroll
  for (int rf = 0; rf < 4; ++rf) {
    #pragma unroll
    for (int r4 = 0; r4 < 4; ++r4) {
      int rl = rf * 16 + (lane >> 4) * 4 + r4;
      int row = i0 + rl;
      float s = rscale[rl];
      float u0 = fmaxf(acc[rf][0][r4] * s, 0.f);
      float u1 = fmaxf(acc[rf][1][r4] * s, 0.f);
      if (row < n) {
        out[(size_t)row * H + w * 32 + (lane & 15)] = u0;
        out[(size_t)row * H + w * 32 + 16 + (lane & 15)] = u1;
        cs0 += u0; cq0 += u0 * u0;
        cs1 += u1; cq1 += u1 * u1;
      }
    }
  }
  cs0 += __shfl_xor(cs0, 16, 64); cs0 += __shfl_xor(cs0, 32, 64);
  cq0 += __shfl_xor(cq0, 16, 64); cq0 += __shfl_xor(cq0, 32, 64);
  cs1 += __shfl_xor(cs1, 16, 64); cs1 += __shfl_xor(cs1, 32, 64);
  cq1 += __shfl_xor(cq1, 16, 64); cq1 += __shfl_xor(cq1, 32, 64);
  if (lane < 16) {
    atomicAdd(&colsum[w * 32 + lane], cs0);
    atomicAdd(&colsq[w * 32 + lane], cq0);
    atomicAdd(&colsum[w * 32 + 16 + lane], cs1);
    atomicAdd(&colsq[w * 32 + 16 + lane], cq1);
  }
}

// ---------------------------------------------------------------------------
// Fallback path (tiny ws): atomic scatter + divide + scalar fused gemm.
// ---------------------------------------------------------------------------
__global__ __launch_bounds__(256) void scatter_mean(
    const float* __restrict__ x, const void* __restrict__ eiv,
    const int* __restrict__ flag, float* __restrict__ agg,
    float* __restrict__ deg, int E) {
  long long gid = (long long)blockIdx.x * blockDim.x + threadIdx.x;
  int e = (int)(gid >> 5);
  int ch = (int)(gid & 31);
  if (e >= E) return;
  int is64 = *flag;
  int src = load_idx(eiv, is64, e);
  int dst = load_idx(eiv, is64, (long long)E + e);
  float4 v = *(const float4*)(x + (size_t)src * F + ch * 4);
  float* a = agg + (size_t)dst * H + ch * 4;
  atomicAdd(a + 0, v.x);
  atomicAdd(a + 1, v.y);
  atomicAdd(a + 2, v.z);
  atomicAdd(a + 3, v.w);
  if (ch == 0) atomicAdd(deg + dst, 1.0f);
}

__global__ __launch_bounds__(256) void divide_deg(float* __restrict__ out,
                                                  const float* __restrict__ deg,
                                                  long long n4) {
  long long i = (long long)blockIdx.x * blockDim.x + threadIdx.x;
  if (i >= n4) return;
  int node = (int)(i >> 5);
  float s = 1.0f / fmaxf(deg[node], 1.0f);
  float4 v = ((float4*)out)[i];
  v.x *= s; v.y *= s; v.z *= s; v.w *= s;
  ((float4*)out)[i] = v;
}

__global__ __launch_bounds__(256) void fused_gemm(
    const float* __restrict__ x, const float* __restrict__ Wl,
    const float* __restrict__ bl, const float* __restrict__ Wr,
    float* __restrict__ out, float* __restrict__ colsum, float* __restrict__ colsq) {
  __shared__ float As[16][256];
  __shared__ float rp[4][8];
  __shared__ float rscale[16];
  __shared__ float cs[128], cs2[128];

  const int t = threadIdx.x;
  const int i0 = blockIdx.x * 16;

  #pragma unroll
  for (int it = 0; it < 2; ++it) {
    int idx = (it * 256 + t) * 4;
    int r = idx >> 7, c = idx & 127;
    float4 va = *(const float4*)(out + (size_t)(i0 + r) * H + c);
    As[r][c + 0] = va.x; As[r][c + 1] = va.y;
    As[r][c + 2] = va.z; As[r][c + 3] = va.w;
    float4 vx = *(const float4*)(x + (size_t)(i0 + r) * F + c);
    As[r][128 + c + 0] = vx.x; As[r][128 + c + 1] = vx.y;
    As[r][128 + c + 2] = vx.z; As[r][128 + c + 3] = vx.w;
  }
  __syncthreads();

  const int c = t & 127;
  const int half = t >> 7;
  float acc[8];
  #pragma unroll
  for (int r = 0; r < 8; ++r) acc[r] = 0.0f;

  #pragma unroll 4
  for (int k = 0; k < 128; ++k) {
    float w = Wl[k * H + c];
    #pragma unroll
    for (int r = 0; r < 8; ++r) acc[r] = fmaf(As[half * 8 + r][k], w, acc[r]);
  }
  #pragma unroll 4
  for (int k = 0; k < 128; ++k) {
    float w = Wr[k * H + c];
    #pragma unroll
    for (int r = 0; r < 8; ++r) acc[r] = fmaf(As[half * 8 + r][128 + k], w, acc[r]);
  }
  const float bias = bl[c];
  #pragma unroll
  for (int r = 0; r < 8; ++r) acc[r] += bias;

  float sq[8];
  #pragma unroll
  for (int r = 0; r < 8; ++r) sq[r] = acc[r] * acc[r];
  #pragma unroll
  for (int off = 32; off > 0; off >>= 1) {
    #pragma unroll
    for (int r = 0; r < 8; ++r) sq[r] += __shfl_down(sq[r], off, 64);
  }
  const int wv = t >> 6;
  if ((t & 63) == 0) {
    #pragma unroll
    for (int r = 0; r < 8; ++r) rp[wv][r] = sq[r];
  }
  __syncthreads();
  if (t < 16) {
    int base = (t >> 3) * 2, rr = t & 7;
    float s = rp[base][rr] + rp[base + 1][rr];
    rscale[t] = 1.0f / fmaxf(sqrtf(s), 1e-12f);
  }
  __syncthreads();

  float csum = 0.0f, csq = 0.0f;
  #pragma unroll
  for (int r = 0; r < 8; ++r) {
    float v = fmaxf(acc[r] * rscale[half * 8 + r], 0.0f);
    out[(size_t)(i0 + half * 8 + r) * H + c] = v;
    csum += v;
    csq += v * v;
  }
  if (half == 1) { cs[c] = csum; cs2[c] = csq; }
  __syncthreads();
  if (half == 0) {
    atomicAdd(&colsum[c], csum + cs[c]);
    atomicAdd(&colsq[c], csq + cs2[c]);
  }
}

__global__ void bn_stats(const float* __restrict__ colsum, const float* __restrict__ colsq,
                         const float* __restrict__ gamma, const float* __restrict__ beta,
                         float* __restrict__ scale, float* __restrict__ shift, int n) {
  int c = threadIdx.x;
  if (c < H) {
    float inv_n = 1.0f / (float)n;
    float mean = colsum[c] * inv_n;
    float var = colsq[c] * inv_n - mean * mean;  // biased (torch BN)
    float istd = rsqrtf(var + 1e-5f);
    float sc = gamma[c] * istd;
    scale[c] = sc;
    shift[c] = beta[c] - mean * sc;
  }
}

__global__ __launch_bounds__(256) void bn_apply(
    float* __restrict__ out, const float* __restrict__ scale,
    const float* __restrict__ shift, long long n4) {
  long long i = (long long)blockIdx.x * blockDim.x + threadIdx.x;
  if (i >= n4) return;
  float4 v = ((float4*)out)[i];
  int c = (int)((i * 4) & (H - 1));
  v.x = fmaf(v.x, scale[c + 0], shift[c + 0]);
  v.y = fmaf(v.y, scale[c + 1], shift[c + 1]);
  v.z = fmaf(v.z, scale[c + 2], shift[c + 2]);
  v.w = fmaf(v.w, scale[c + 3], shift[c + 3]);
  ((float4*)out)[i] = v;
}

// reads pre-BN u (bf16 in ws), writes final f32 to out
__global__ __launch_bounds__(256) void bn_apply_lo(
    const unsigned short* __restrict__ U, float* __restrict__ out,
    const float* __restrict__ scale, const float* __restrict__ shift,
    long long n4) {
  long long i = (long long)blockIdx.x * blockDim.x + threadIdx.x;
  if (i >= n4) return;
  uint2 uv = ((const uint2*)U)[i];
  int c = (int)((i * 4) & (H - 1));
  float4 v;
  v.x = fmaf(bits2f(uv.x << 16),          scale[c + 0], shift[c + 0]);
  v.y = fmaf(bits2f(uv.x & 0xFFFF0000u),  scale[c + 1], shift[c + 1]);
  v.z = fmaf(bits2f(uv.y << 16),          scale[c + 2], shift[c + 2]);
  v.w = fmaf(bits2f(uv.y & 0xFFFF0000u),  scale[c + 3], shift[c + 3]);
  ((float4*)out)[i] = v;
}

extern "C" void kernel_launch(void* const* d_in, const int* in_sizes, int n_in,
                              void* d_out, int out_size, void* d_ws, size_t ws_size,
                              hipStream_t stream) {
  const float* x     = (const float*)d_in[0];
  const void*  ei    = d_in[1];
  const float* Wl    = (const float*)d_in[2];
  const float* bl    = (const float*)d_in[3];
  const float* Wr    = (const float*)d_in[4];
  const float* gamma = (const float*)d_in[5];
  const float* beta  = (const float*)d_in[6];
  float* out = (float*)d_out;

  const int n = in_sizes[0] / F;   // 100000
  const int E = in_sizes[1] / 2;   // 1600000
  const int nb = (n + 255) / 256;
  const int nbuck = (n + 63) >> 6; // 64-node buckets

  char* ws = (char*)d_ws;
  int* flag = (int*)ws;
  unsigned short* Wcat = (unsigned short*)(ws + 256);
  char* after_w = ws + 256 + 4 * 128 * 128 * 2;

  // ---- fast-path layout: partition + Y fp8 (+P,U bf16) ----
  int*   cmat    = (int*)after_w;
  int*   obuf    = cmat + 2048 * NPART;
  int*   bsum    = obuf + 2048 * NPART;
  int*   boff    = bsum + 1024;
  int*   bbase   = boff + 1024;
  float* fcs     = (float*)(bbase + 2049);
  float* fcq     = fcs + H;
  float* fsc     = fcq + H;
  float* fsh     = fsc + H;
  int*   ebuf    = (int*)(fsh + H);
  unsigned char*  Yf8 = (unsigned char*)(ebuf + E);
  unsigned short* Pws = (unsigned short*)(Yf8 + (size_t)n * H);
  unsigned short* Uws = Pws + (size_t)n * H;
  size_t need_fast  = (size_t)((char*)(Yf8 + (size_t)n * H) - ws);
  size_t need_fast2 = (size_t)((char*)(Uws + (size_t)n * H) - ws);

  // ---- mid-path layout: CSR ----
  int*   degi     = (int*)after_w;
  int*   offsets  = degi + n;
  int*   cursor   = offsets + n + 1;
  int*   blocksum = cursor + n;
  int*   blockoff = blocksum + nb;
  float* mcs      = (float*)(blockoff + nb);
  float* mcq      = mcs + H;
  float* msc      = mcq + H;
  float* msh      = msc + H;
  int*   csr_src  = (int*)(msh + H);
  size_t need_mid = (size_t)((char*)(csr_src + E) - ws);

  float *colsum, *colsq, *scale, *shift;

  const int eb = (E + 255) / 256;
  const int gb = (n + 63) / 64;
  const long long n4 = (long long)n * H / 4;

  if (ws_size >= need_fast && nbuck <= 2048) {
    const bool lowp = (ws_size >= need_fast2);
    colsum = fcs; colsq = fcq; scale = fsc; shift = fsh;

    prep_w<<<32, 256, 0, stream>>>(Wl, Wr, Wcat);
    if (lowp)
      dual_gemm<true><<<gb, 256, 0, stream>>>(x, Wcat, bl, Yf8, out, Pws, n);
    else
      dual_gemm<false><<<gb, 256, 0, stream>>>(x, Wcat, bl, Yf8, out, Pws, n);

    const int chunk = (E + NPART - 1) / NPART;
    const int L = nbuck * NPART;
    const int nb2 = (L + 255) / 256;   // <= 1024
    part_hist<<<NPART, 512, 0, stream>>>(ei, cmat, E, nbuck, chunk);
    scan1<<<nb2, 256, 0, stream>>>(cmat, obuf, bsum, L);
    scan2big<<<1, 1024, 0, stream>>>(bsum, boff, nb2);
    scan3p<<<nb2, 256, 0, stream>>>(obuf, boff, bbase, colsum, L, nbuck, E);
    part_scatter<<<NPART, 512, 0, stream>>>(ei, obuf, ebuf, E, nbuck, chunk);

    if (lowp)
      gather_bucket<true><<<nbuck, 256, 0, stream>>>(
          Yf8, ebuf, bbase, out, Pws, Uws, colsum, colsq, n);
    else
      gather_bucket<false><<<nbuck, 256, 0, stream>>>(
          Yf8, ebuf, bbase, out, Pws, Uws, colsum, colsq, n);

    bn_stats<<<1, 128, 0, stream>>>(colsum, colsq, gamma, beta, scale, shift, n);
    if (lowp)
      bn_apply_lo<<<(int)((n4 + 255) / 256), 256, 0, stream>>>(
          Uws, out, scale, shift, n4);
    else
      bn_apply<<<(int)((n4 + 255) / 256), 256, 0, stream>>>(out, scale, shift, n4);
  } else if (ws_size >= need_mid) {
    colsum = mcs; colsq = mcq; scale = msc; shift = msh;
    detect_dtype<<<1, 64, 0, stream>>>((const unsigned*)ei, flag);
    hipMemsetAsync(degi, 0, (size_t)n * 4, stream);
    hipMemsetAsync(colsum, 0, 2 * H * 4, stream);

    prep_w<<<32, 256, 0, stream>>>(Wl, Wr, Wcat);

    deg_count<<<eb, 256, 0, stream>>>(ei, flag, degi, E);
    scan1<<<nb, 256, 0, stream>>>(degi, offsets, blocksum, n);
    scan2big<<<1, 1024, 0, stream>>>(blocksum, blockoff, nb);
    scan3<<<nb, 256, 0, stream>>>(offsets, blockoff, cursor, n, E);
    bucket_fill<<<eb, 256, 0, stream>>>(ei, flag, cursor, csr_src, E);

    long long gthreads = (long long)n * 64;
    gather_mean<<<(int)((gthreads + 255) / 256), 256, 0, stream>>>(
        x, offsets, csr_src, out, n);

    mfma_gemm<<<gb, 256, 0, stream>>>(x, Wcat, bl, out, colsum, colsq, n);
    bn_stats<<<1, 128, 0, stream>>>(colsum, colsq, gamma, beta, scale, shift, n);
    bn_apply<<<(int)((n4 + 255) / 256), 256, 0, stream>>>(out, scale, shift, n4);
  } else {
    float* deg = (float*)(ws + 256);
    colsum = deg + n; colsq = colsum + H; scale = colsq + H; shift = scale + H;
    detect_dtype<<<1, 64, 0, stream>>>((const unsigned*)ei, flag);
    hipMemsetAsync(d_out, 0, (size_t)out_size * sizeof(float), stream);
    hipMemsetAsync(deg, 0, (size_t)n * 4 + 4 * H * 4, stream);
    long long sthreads = (long long)E * 32;
    scatter_mean<<<(int)((sthreads + 255) / 256), 256, 0, stream>>>(x, ei, flag, out, deg, E);
    long long n4f = (long long)n * H / 4;
    divide_deg<<<(int)((n4f + 255) / 256), 256, 0, stream>>>(out, deg, n4f);
    fused_gemm<<<n / 16, 256, 0, stream>>>(x, Wl, bl, Wr, out, colsum, colsq);
    bn_stats<<<1, 128, 0, stream>>>(colsum, colsq, gamma, beta, scale, shift, n);
    bn_apply<<<(int)((n4 + 255) / 256), 256, 0, stream>>>(out, scale, shift, n4);
  }
}

// Round 12
// 190.617 us; speedup vs baseline: 1.3924x; 1.0691x over previous
//
#include <hip/hip_runtime.h>
#include <hip/hip_bf16.h>

static constexpr int F = 128;
static constexpr int H = 128;
static constexpr int NPART = 128;   // partition blocks (contiguous edge chunks)

typedef __attribute__((ext_vector_type(8))) short short8;
typedef __attribute__((ext_vector_type(4))) float f32x4;
typedef __attribute__((ext_vector_type(2))) _Float16 h2v;

__device__ __forceinline__ unsigned short f2bf(float f) {
  union { float f; unsigned u; } a; a.f = f;
  unsigned r = a.u + 0x7FFF + ((a.u >> 16) & 1);
  return (unsigned short)(r >> 16);
}
__device__ __forceinline__ float bf2f(unsigned short h) {
  union { unsigned u; float f; } a; a.u = ((unsigned)h) << 16;
  return a.f;
}
__device__ __forceinline__ float bits2f(unsigned u) {
  union { unsigned u; float f; } a; a.u = u;
  return a.f;
}
__device__ __forceinline__ h2v bits2h2(unsigned u) {
  union { unsigned u; h2v h; } a; a.u = u; return a.h;
}

// f32 -> fp8 e4m3fn (RNE, flush-to-zero below 2^-6, clamp to 448)
__device__ __forceinline__ unsigned f2fp8(float f) {
  union { float f; unsigned u; } a; a.f = f;
  unsigned s = (a.u >> 24) & 0x80u;
  unsigned m = a.u & 0x7FFFFFFFu;
  if (m < 0x3C800000u) return s;                 // |f| < 2^-6 -> signed zero code
  unsigned r = m + 0x7FFFFu + ((m >> 20) & 1u);  // RNE to 3 mantissa bits
  if (r > 0x43E00000u) r = 0x43E00000u;          // clamp to 448 (max finite)
  return s | ((((r >> 23) - 120u) & 15u) << 3) | ((r >> 20) & 7u);
}

// Packed decode: 4 fp8 bytes -> 2 packed-f16 pairs (v0,v2) and (v1,v3).
// f16 halfword = sign<<15 | (mag<<7) + 0x2000 (bias 7->15); code 0 -> +/-2^-7
// (same semantics as round-11 decode; no per-value select).
__device__ __forceinline__ void fp8x4_to_h2(unsigned w, h2v& p02, h2v& p13) {
  unsigned lo = w & 0x00FF00FFu;
  unsigned hi = (w >> 8) & 0x00FF00FFu;
  unsigned q0 = (((lo << 7) & 0x3F803F80u) + 0x20002000u) | ((lo & 0x00800080u) << 8);
  unsigned q1 = (((hi << 7) & 0x3F803F80u) + 0x20002000u) | ((hi & 0x00800080u) << 8);
  p02 = bits2h2(q0);
  p13 = bits2h2(q1);
}

// f32 decode (slow path only)
__device__ __forceinline__ void fp8x4_to_f32(unsigned w, float& f0, float& f1,
                                             float& f2, float& f3) {
  unsigned lo = w & 0x00FF00FFu;
  unsigned hi = (w >> 8) & 0x00FF00FFu;
  unsigned p0 = (((lo << 4) & 0x07F007F0u) + 0x3C003C00u) | ((lo & 0x00800080u) << 8);
  unsigned p1 = (((hi << 4) & 0x07F007F0u) + 0x3C003C00u) | ((hi & 0x00800080u) << 8);
  f0 = bits2f(p0 << 16);
  f2 = bits2f(p0 & 0xFFFF0000u);
  f1 = bits2f(p1 << 16);
  f3 = bits2f(p1 & 0xFFFF0000u);
}

// int64-vs-int32 edge_index detection (values < 2^17 -> int64 hi words all 0)
__device__ __forceinline__ int detect64(const void* eiv) {
  const unsigned* u = (const unsigned*)eiv;
  int is64 = 1;
  for (int i = 0; i < 64; ++i) is64 &= (u[2 * i + 1] == 0u);
  return is64;
}

__global__ void detect_dtype(const unsigned* __restrict__ ei, int* __restrict__ flag) {
  if (blockIdx.x == 0 && threadIdx.x == 0) {
    int is64 = 1;
    for (int i = 0; i < 64; ++i) {
      if (ei[2 * i + 1] != 0u) { is64 = 0; break; }
    }
    *flag = is64;
  }
}

__device__ __forceinline__ int load_idx(const void* eiv, int is64, long long pos) {
  return is64 ? (int)((const long long*)eiv)[pos] : ((const int*)eiv)[pos];
}

// ---------------------------------------------------------------------------
// scans for two-pass partition
// ---------------------------------------------------------------------------
__global__ __launch_bounds__(256) void scan1(const int* __restrict__ in,
                                             int* __restrict__ outx,
                                             int* __restrict__ blocksum, int n) {
  __shared__ int sm[256];
  int idx = blockIdx.x * 256 + threadIdx.x;
  int v = (idx < n) ? in[idx] : 0;
  sm[threadIdx.x] = v;
  __syncthreads();
  #pragma unroll
  for (int off = 1; off < 256; off <<= 1) {
    int t = (threadIdx.x >= off) ? sm[threadIdx.x - off] : 0;
    __syncthreads();
    sm[threadIdx.x] += t;
    __syncthreads();
  }
  if (idx < n) outx[idx] = sm[threadIdx.x] - v;
  if (threadIdx.x == 255) blocksum[blockIdx.x] = sm[255];
}

__global__ __launch_bounds__(1024) void scan2big(const int* __restrict__ blocksum,
                                                 int* __restrict__ blockoff, int nb) {
  __shared__ int sm[1024];
  int t = threadIdx.x;
  int v = (t < nb) ? blocksum[t] : 0;
  sm[t] = v;
  __syncthreads();
  for (int off = 1; off < 1024; off <<= 1) {
    int u = (t >= off) ? sm[t - off] : 0;
    __syncthreads();
    sm[t] += u;
    __syncthreads();
  }
  if (t < nb) blockoff[t] = sm[t] - v;
}

// finalize partition scan: base matrix in place + bucket segment starts.
// Block 0 also zeroes colsum/colsq (256 contiguous floats).
__global__ __launch_bounds__(256) void scan3p(int* __restrict__ obuf,
                                              const int* __restrict__ blockoff,
                                              int* __restrict__ bbase,
                                              float* __restrict__ colzero,
                                              int L, int nbuck, int E) {
  if (blockIdx.x == 0) colzero[threadIdx.x] = 0.0f;
  int idx = blockIdx.x * 256 + threadIdx.x;
  if (idx >= L) return;
  int v = obuf[idx] + blockoff[idx >> 8];
  obuf[idx] = v;
  if ((idx & (NPART - 1)) == 0) bbase[idx / NPART] = v;
  if (idx == 0) bbase[nbuck] = E;
}

__global__ __launch_bounds__(512) void part_scatter(const void* __restrict__ eiv,
                                                    const int* __restrict__ base,
                                                    int* __restrict__ ebuf,
                                                    int E, int nbuck, int chunk) {
  __shared__ int cur[2048];
  const int t = threadIdx.x, b = blockIdx.x;
  for (int i = t; i < nbuck; i += 512) cur[i] = base[i * NPART + b];
  __syncthreads();
  int is64 = detect64(eiv);
  int s = b * chunk, e = min(E, s + chunk);
  for (int i = s + t; i < e; i += 512) {
    int src = load_idx(eiv, is64, i);
    int dst = load_idx(eiv, is64, (long long)E + i);
    int pos = atomicAdd(&cur[dst >> 6], 1);
    ebuf[pos] = (src << 6) | (dst & 63);
  }
}

// ---------------------------------------------------------------------------
// prep_w: split Wl/Wr into bf16 hi/lo in MFMA fragment-blob order.
// ---------------------------------------------------------------------------
__global__ __launch_bounds__(256) void prep_w(const float* __restrict__ Wl,
                                              const float* __restrict__ Wr,
                                              unsigned short* __restrict__ Wcat) {
  int tid = blockIdx.x * 256 + threadIdx.x;
  if (tid >= 4 * 4 * 8 * 64) return;
  int lane = tid & 63;
  int nf   = (tid >> 6) & 7;
  int kc   = (tid >> 9) & 3;
  int part = tid >> 11;
  const float* W = (part < 2) ? Wl : Wr;
  bool lo = (part & 1);
  int ncol = nf * 16 + (lane & 15);
  int k0 = kc * 32 + (lane >> 4) * 8;
  unsigned short ov[8];
  #pragma unroll
  for (int j = 0; j < 8; ++j) {
    float v = W[(k0 + j) * H + ncol];
    unsigned short h = f2bf(v);
    ov[j] = lo ? f2bf(v - bf2f(h)) : h;
  }
  uint4 pack;
  pack.x = (unsigned)ov[0] | ((unsigned)ov[1] << 16);
  pack.y = (unsigned)ov[2] | ((unsigned)ov[3] << 16);
  pack.z = (unsigned)ov[4] | ((unsigned)ov[5] << 16);
  pack.w = (unsigned)ov[6] | ((unsigned)ov[7] << 16);
  *(uint4*)(Wcat + (size_t)tid * 8) = pack;
}

// ---------------------------------------------------------------------------
// fused_gemm_hist<LOWP>: UNION kernel.
//   blocks [0, NPART)      : part_hist (dst-bucket histogram per edge chunk)
//   blocks [NPART, NPART+gb): dual_gemm  Y=fp8(x@Wl) -> Yf8; P=x@Wr+bl -> Pbf/pout
// Overlaps the (independent) histogram with the GEMM in one dispatch.
// ---------------------------------------------------------------------------
template <bool LOWP>
__global__ __launch_bounds__(256) void fused_gemm_hist(
    const float* __restrict__ x, const unsigned short* __restrict__ Wcat,
    const float* __restrict__ bl, unsigned char* __restrict__ Yf8,
    float* __restrict__ pout, unsigned short* __restrict__ Pbf, int n,
    const void* __restrict__ eiv, int* __restrict__ cmat, int E, int nbuck,
    int chunk) {
  __shared__ unsigned short As[2][64][128];  // 32KB; hist aliases first 8KB

  const int t = threadIdx.x;

  if (blockIdx.x < NPART) {
    // ---- part_hist ----
    int* h = (int*)&As[0][0][0];
    const int b = blockIdx.x;
    for (int i = t; i < nbuck; i += 256) h[i] = 0;
    __syncthreads();
    int is64 = detect64(eiv);
    int s = b * chunk, e = min(E, s + chunk);
    for (int i = s + t; i < e; i += 256) {
      int dst = load_idx(eiv, is64, (long long)E + i);
      atomicAdd(&h[dst >> 6], 1);
    }
    __syncthreads();
    for (int i = t; i < nbuck; i += 256) cmat[i * NPART + b] = h[i];
    return;
  }

  // ---- dual_gemm ----
  const int i0 = (blockIdx.x - NPART) * 64;

  #pragma unroll
  for (int it = 0; it < 8; ++it) {
    int idx = it * 256 + t;
    int r = idx >> 5;
    int c4 = (idx & 31) * 4;
    int row_g = i0 + r; if (row_g >= n) row_g = n - 1;
    int boff = (((c4 >> 3) ^ (r & 7)) << 3) + (c4 & 7);
    float4 vx = *(const float4*)(x + (size_t)row_g * F + c4);
    unsigned short h0 = f2bf(vx.x), h1 = f2bf(vx.y), h2 = f2bf(vx.z), h3 = f2bf(vx.w);
    uint2 hv = { (unsigned)h0 | ((unsigned)h1 << 16), (unsigned)h2 | ((unsigned)h3 << 16) };
    *(uint2*)&As[0][r][boff] = hv;
    unsigned short l0 = f2bf(vx.x - bf2f(h0)), l1 = f2bf(vx.y - bf2f(h1));
    unsigned short l2 = f2bf(vx.z - bf2f(h2)), l3 = f2bf(vx.w - bf2f(h3));
    uint2 lv = { (unsigned)l0 | ((unsigned)l1 << 16), (unsigned)l2 | ((unsigned)l3 << 16) };
    *(uint2*)&As[1][r][boff] = lv;
  }
  __syncthreads();

  const int w = t >> 6;
  const int lane = t & 63;

  f32x4 accL[4][2], accR[4][2];
  #pragma unroll
  for (int rf = 0; rf < 4; ++rf)
    #pragma unroll
    for (int nfi = 0; nfi < 2; ++nfi) {
      accL[rf][nfi] = (f32x4){0.f, 0.f, 0.f, 0.f};
      accR[rf][nfi] = (f32x4){0.f, 0.f, 0.f, 0.f};
    }

  const int APM[3] = {0, 1, 0};
  const int BL[3]  = {0, 0, 1};   // Wl_hi, Wl_hi, Wl_lo
  const int BR[3]  = {2, 2, 3};   // Wr_hi, Wr_hi, Wr_lo

  #pragma unroll
  for (int pass = 0; pass < 3; ++pass) {
    const int ap = APM[pass];
    #pragma unroll
    for (int kc = 0; kc < 4; ++kc) {
      short8 afr[4];
      int chunk2 = kc * 4 + (lane >> 4);
      #pragma unroll
      for (int rf = 0; rf < 4; ++rf) {
        int row = rf * 16 + (lane & 15);
        afr[rf] = *(const short8*)(&As[ap][row][(chunk2 ^ (row & 7)) * 8]);
      }
      short8 bfrL[2], bfrR[2];
      #pragma unroll
      for (int nfi = 0; nfi < 2; ++nfi) {
        int blobL = (BL[pass] * 4 + kc) * 8 + (w * 2 + nfi);
        int blobR = (BR[pass] * 4 + kc) * 8 + (w * 2 + nfi);
        bfrL[nfi] = *(const short8*)(Wcat + (size_t)blobL * 512 + lane * 8);
        bfrR[nfi] = *(const short8*)(Wcat + (size_t)blobR * 512 + lane * 8);
      }
      #pragma unroll
      for (int rf = 0; rf < 4; ++rf)
        #pragma unroll
        for (int nfi = 0; nfi < 2; ++nfi) {
          accL[rf][nfi] = __builtin_amdgcn_mfma_f32_16x16x32_bf16(
              afr[rf], bfrL[nfi], accL[rf][nfi], 0, 0, 0);
          accR[rf][nfi] = __builtin_amdgcn_mfma_f32_16x16x32_bf16(
              afr[rf], bfrR[nfi], accR[rf][nfi], 0, 0, 0);
        }
    }
  }

  const float b0 = bl[w * 32 + (lane & 15)];
  const float b1 = bl[w * 32 + 16 + (lane & 15)];

  #pragma unroll
  for (int rf = 0; rf < 4; ++rf) {
    #pragma unroll
    for (int r4 = 0; r4 < 4; ++r4) {
      int rl = rf * 16 + (lane >> 4) * 4 + r4;
      int row = i0 + rl;
      if (row < n) {
        Yf8[(size_t)row * H + w * 32 + (lane & 15)]      = (unsigned char)f2fp8(accL[rf][0][r4]);
        Yf8[(size_t)row * H + w * 32 + 16 + (lane & 15)] = (unsigned char)f2fp8(accL[rf][1][r4]);
        if (LOWP) {
          Pbf[(size_t)row * H + w * 32 + (lane & 15)]      = f2bf(accR[rf][0][r4] + b0);
          Pbf[(size_t)row * H + w * 32 + 16 + (lane & 15)] = f2bf(accR[rf][1][r4] + b1);
        } else {
          pout[(size_t)row * H + w * 32 + (lane & 15)]      = accR[rf][0][r4] + b0;
          pout[(size_t)row * H + w * 32 + 16 + (lane & 15)] = accR[rf][1][r4] + b1;
        }
      }
    }
  }
}

// ---------------------------------------------------------------------------
// gather_bucket<LOWP>: one block per 64-node bucket (2 nodes/wave, 32
// lanes/node, 8-deep unroll). Y fp8 decoded to packed f16; accumulation via
// v_pk_add_f16 (2 adds/instr). Fused epilogue: v = P + agg; row-L2-norm;
// ReLU; store u; BN col stats.
// ---------------------------------------------------------------------------
#define GCAP 2048
template <bool LOWP>
__global__ __launch_bounds__(256) void gather_bucket(
    const unsigned char* __restrict__ Yf8, const int* __restrict__ ebuf,
    const int* __restrict__ bbase, float* __restrict__ pio,
    const unsigned short* __restrict__ Pbf, unsigned short* __restrict__ Ubf,
    float* __restrict__ colsum, float* __restrict__ colsq, int n) {
  __shared__ int lsrc[GCAP];
  __shared__ int hist[65];
  __shared__ int loff[65];
  __shared__ int cur[64];
  __shared__ float csm[128], cqm[128];

  const int t = threadIdx.x;
  const int b = blockIdx.x;
  const int node0 = b << 6;
  const int s = bbase[b], e = bbase[b + 1];
  const int cnt = e - s;

  if (t < 65) hist[t] = 0;
  if (t < 128) { csm[t] = 0.f; cqm[t] = 0.f; }
  __syncthreads();

  const bool fast = (cnt <= GCAP);
  if (fast) {
    for (int i = s + t; i < e; i += 256)
      atomicAdd(&hist[ebuf[i] & 63], 1);
    __syncthreads();
    if (t < 64) loff[t] = hist[t];
    __syncthreads();
    #pragma unroll
    for (int off = 1; off < 64; off <<= 1) {
      int u = (t >= off && t < 64) ? loff[t - off] : 0;
      __syncthreads();
      if (t < 64) loff[t] += u;
      __syncthreads();
    }
    if (t < 64) cur[t] = loff[t] - hist[t];
    __syncthreads();
    for (int i = s + t; i < e; i += 256) {
      int p = ebuf[i];
      int pos = atomicAdd(&cur[p & 63], 1);
      lsrc[pos] = p >> 6;
    }
    __syncthreads();
  }

  const int lane = t & 63;
  const int w = t >> 6;
  const int half = lane >> 5;
  const int c = (lane & 31) * 4;   // byte column (4 fp8 per lane)

  float lcs[4] = {0.f, 0.f, 0.f, 0.f};
  float lcq[4] = {0.f, 0.f, 0.f, 0.f};

  #pragma unroll
  for (int it = 0; it < 8; ++it) {
    int ln = it * 8 + w * 2 + half;
    int node = node0 + ln;
    if (node >= n) continue;
    int ls, le;
    if (fast) { ls = loff[ln] - hist[ln]; le = loff[ln]; }
    else      { ls = 0; le = 0; }

    h2v a02[8], a13[8];
    #pragma unroll
    for (int u = 0; u < 8; ++u) {
      a02[u] = (h2v)(_Float16)0;
      a13[u] = (h2v)(_Float16)0;
    }

    int j = ls;
    for (; j + 7 < le; j += 8) {
      #pragma unroll
      for (int u = 0; u < 8; ++u) {
        int sj = lsrc[j + u];
        unsigned wv = *(const unsigned*)(Yf8 + (size_t)sj * H + c);
        h2v p02, p13;
        fp8x4_to_h2(wv, p02, p13);
        a02[u] += p02;
        a13[u] += p13;
      }
    }
    for (; j + 1 < le; j += 2) {
      #pragma unroll
      for (int u = 0; u < 2; ++u) {
        int sj = lsrc[j + u];
        unsigned wv = *(const unsigned*)(Yf8 + (size_t)sj * H + c);
        h2v p02, p13;
        fp8x4_to_h2(wv, p02, p13);
        a02[u] += p02;
        a13[u] += p13;
      }
    }
    if (j < le) {
      int sj = lsrc[j];
      unsigned wv = *(const unsigned*)(Yf8 + (size_t)sj * H + c);
      h2v p02, p13;
      fp8x4_to_h2(wv, p02, p13);
      a02[0] += p02;
      a13[0] += p13;
    }

    float deg = 0.0f;
    float a0, a1, a2, a3;
    if (fast) {
      deg = (float)(le - ls);
      h2v s02 = ((a02[0] + a02[1]) + (a02[2] + a02[3])) +
                ((a02[4] + a02[5]) + (a02[6] + a02[7]));
      h2v s13 = ((a13[0] + a13[1]) + (a13[2] + a13[3])) +
                ((a13[4] + a13[5]) + (a13[6] + a13[7]));
      a0 = (float)s02[0]; a2 = (float)s02[1];
      a1 = (float)s13[0]; a3 = (float)s13[1];
    } else {
      // slow path (statistically unreachable): scan whole bucket in f32
      a0 = a1 = a2 = a3 = 0.0f;
      for (int jj = s; jj < e; ++jj) {
        int p = ebuf[jj];
        if ((p & 63) == ln) {
          deg += 1.0f;
          unsigned wv = *(const unsigned*)(Yf8 + (size_t)(p >> 6) * H + c);
          float f0, f1, f2, f3;
          fp8x4_to_f32(wv, f0, f1, f2, f3);
          a0 += f0; a1 += f1; a2 += f2; a3 += f3;
        }
      }
    }

    float inv = 1.0f / fmaxf(deg, 1.0f);
    float p0, p1, p2, p3;
    if (LOWP) {
      uint2 pv = *(const uint2*)(Pbf + (size_t)node * H + c);
      p0 = bits2f(pv.x << 16);
      p1 = bits2f(pv.x & 0xFFFF0000u);
      p2 = bits2f(pv.y << 16);
      p3 = bits2f(pv.y & 0xFFFF0000u);
    } else {
      float4 p = *(const float4*)(pio + (size_t)node * H + c);
      p0 = p.x; p1 = p.y; p2 = p.z; p3 = p.w;
    }
    float v0 = p0 + a0 * inv;
    float v1 = p1 + a1 * inv;
    float v2 = p2 + a2 * inv;
    float v3 = p3 + a3 * inv;
    float sq = v0 * v0 + v1 * v1 + v2 * v2 + v3 * v3;
    sq += __shfl_xor(sq, 1, 64);
    sq += __shfl_xor(sq, 2, 64);
    sq += __shfl_xor(sq, 4, 64);
    sq += __shfl_xor(sq, 8, 64);
    sq += __shfl_xor(sq, 16, 64);
    float rs = 1.0f / fmaxf(sqrtf(sq), 1e-12f);
    float u0 = fmaxf(v0 * rs, 0.f), u1 = fmaxf(v1 * rs, 0.f);
    float u2 = fmaxf(v2 * rs, 0.f), u3 = fmaxf(v3 * rs, 0.f);
    if (LOWP) {
      uint2 ov;
      ov.x = (unsigned)f2bf(u0) | ((unsigned)f2bf(u1) << 16);
      ov.y = (unsigned)f2bf(u2) | ((unsigned)f2bf(u3) << 16);
      *(uint2*)(Ubf + (size_t)node * H + c) = ov;
    } else {
      float4 o = {u0, u1, u2, u3};
      *(float4*)(pio + (size_t)node * H + c) = o;
    }
    lcs[0] += u0; lcq[0] += u0 * u0;
    lcs[1] += u1; lcq[1] += u1 * u1;
    lcs[2] += u2; lcq[2] += u2 * u2;
    lcs[3] += u3; lcq[3] += u3 * u3;
  }

  #pragma unroll
  for (int q = 0; q < 4; ++q) {
    atomicAdd(&csm[c + q], lcs[q]);
    atomicAdd(&cqm[c + q], lcq[q]);
  }
  __syncthreads();
  if (t < 128) {
    atomicAdd(&colsum[t], csm[t]);
    atomicAdd(&colsq[t], cqm[t]);
  }
}

// ---------------------------------------------------------------------------
// CSR build (mid fallback path)
// ---------------------------------------------------------------------------
__global__ __launch_bounds__(256) void deg_count(const void* __restrict__ eiv,
                                                 const int* __restrict__ flag,
                                                 int* __restrict__ degi, int E) {
  int e = blockIdx.x * blockDim.x + threadIdx.x;
  if (e >= E) return;
  int dst = load_idx(eiv, *flag, (long long)E + e);
  atomicAdd(&degi[dst], 1);
}

__global__ __launch_bounds__(256) void scan3(int* __restrict__ offsets,
                                             const int* __restrict__ blockoff,
                                             int* __restrict__ cursor, int n, int E) {
  int idx = blockIdx.x * 256 + threadIdx.x;
  if (idx >= n) return;
  int off = offsets[idx] + blockoff[idx >> 8];
  offsets[idx] = off;
  cursor[idx] = off;
  if (idx == 0) offsets[n] = E;
}

__global__ __launch_bounds__(256) void bucket_fill(const void* __restrict__ eiv,
                                                   const int* __restrict__ flag,
                                                   int* __restrict__ cursor,
                                                   int* __restrict__ csr_src, int E) {
  int e = blockIdx.x * blockDim.x + threadIdx.x;
  if (e >= E) return;
  int is64 = *flag;
  int src = load_idx(eiv, is64, e);
  int dst = load_idx(eiv, is64, (long long)E + e);
  int pos = atomicAdd(&cursor[dst], 1);
  csr_src[pos] = src;
}

// ---------------------------------------------------------------------------
// Mid path: f32 gather + double MFMA gemm.
// ---------------------------------------------------------------------------
__global__ __launch_bounds__(256) void gather_mean(const float* __restrict__ x,
                                                   const int* __restrict__ offsets,
                                                   const int* __restrict__ csr_src,
                                                   float* __restrict__ out, int n) {
  int node = (int)(((long long)blockIdx.x * blockDim.x + threadIdx.x) >> 6);
  int lane = threadIdx.x & 63;
  if (node >= n) return;
  int s = offsets[node], e = offsets[node + 1];
  float ax = 0.0f, ay = 0.0f, bx = 0.0f, by = 0.0f;
  int j = s;
  for (; j + 1 < e; j += 2) {
    int s0 = csr_src[j], s1 = csr_src[j + 1];
    float2 v0 = *(const float2*)(x + (size_t)s0 * F + lane * 2);
    float2 v1 = *(const float2*)(x + (size_t)s1 * F + lane * 2);
    ax += v0.x; ay += v0.y;
    bx += v1.x; by += v1.y;
  }
  if (j < e) {
    int s0 = csr_src[j];
    float2 v0 = *(const float2*)(x + (size_t)s0 * F + lane * 2);
    ax += v0.x; ay += v0.y;
  }
  float inv = 1.0f / fmaxf((float)(e - s), 1.0f);
  float2 r; r.x = (ax + bx) * inv; r.y = (ay + by) * inv;
  *(float2*)(out + (size_t)node * H + lane * 2) = r;
}

__global__ __launch_bounds__(256) void mfma_gemm(
    const float* __restrict__ x, const unsigned short* __restrict__ Wcat,
    const float* __restrict__ bl, float* __restrict__ out,
    float* __restrict__ colsum, float* __restrict__ colsq, int n) {
  __shared__ unsigned short As[4][64][128];
  __shared__ float rowsq[64][4];
  __shared__ float rscale[64];

  const int t = threadIdx.x;
  const int i0 = blockIdx.x * 64;

  #pragma unroll
  for (int it = 0; it < 8; ++it) {
    int idx = it * 256 + t;
    int r = idx >> 5;
    int c4 = (idx & 31) * 4;
    int row_g = i0 + r; if (row_g >= n) row_g = n - 1;
    int boff = (((c4 >> 3) ^ (r & 7)) << 3) + (c4 & 7);
    float4 va = *(const float4*)(out + (size_t)row_g * H + c4);
    float4 vx = *(const float4*)(x + (size_t)row_g * H + c4);
    unsigned short h0 = f2bf(va.x), h1 = f2bf(va.y), h2 = f2bf(va.z), h3 = f2bf(va.w);
    uint2 hv = { (unsigned)h0 | ((unsigned)h1 << 16), (unsigned)h2 | ((unsigned)h3 << 16) };
    *(uint2*)&As[0][r][boff] = hv;
    unsigned short l0 = f2bf(va.x - bf2f(h0)), l1 = f2bf(va.y - bf2f(h1));
    unsigned short l2 = f2bf(va.z - bf2f(h2)), l3 = f2bf(va.w - bf2f(h3));
    uint2 lv = { (unsigned)l0 | ((unsigned)l1 << 16), (unsigned)l2 | ((unsigned)l3 << 16) };
    *(uint2*)&As[1][r][boff] = lv;
    h0 = f2bf(vx.x); h1 = f2bf(vx.y); h2 = f2bf(vx.z); h3 = f2bf(vx.w);
    uint2 hx = { (unsigned)h0 | ((unsigned)h1 << 16), (unsigned)h2 | ((unsigned)h3 << 16) };
    *(uint2*)&As[2][r][boff] = hx;
    l0 = f2bf(vx.x - bf2f(h0)); l1 = f2bf(vx.y - bf2f(h1));
    l2 = f2bf(vx.z - bf2f(h2)); l3 = f2bf(vx.w - bf2f(h3));
    uint2 lx = { (unsigned)l0 | ((unsigned)l1 << 16), (unsigned)l2 | ((unsigned)l3 << 16) };
    *(uint2*)&As[3][r][boff] = lx;
  }
  __syncthreads();

  const int w = t >> 6;
  const int lane = t & 63;

  f32x4 acc[4][2];
  #pragma unroll
  for (int rf = 0; rf < 4; ++rf)
    #pragma unroll
    for (int nfi = 0; nfi < 2; ++nfi)
      acc[rf][nfi] = (f32x4){0.f, 0.f, 0.f, 0.f};

  const int APM[6] = {0, 1, 0, 2, 3, 2};
  const int BPM[6] = {0, 0, 1, 2, 2, 3};

  #pragma unroll
  for (int pass = 0; pass < 6; ++pass) {
    const int ap = APM[pass], bp = BPM[pass];
    #pragma unroll
    for (int kc = 0; kc < 4; ++kc) {
      short8 bfr[2];
      #pragma unroll
      for (int nfi = 0; nfi < 2; ++nfi) {
        int blob = (bp * 4 + kc) * 8 + (w * 2 + nfi);
        bfr[nfi] = *(const short8*)(Wcat + (size_t)blob * 512 + lane * 8);
      }
      short8 afr[4];
      int chunk = kc * 4 + (lane >> 4);
      #pragma unroll
      for (int rf = 0; rf < 4; ++rf) {
        int row = rf * 16 + (lane & 15);
        afr[rf] = *(const short8*)(&As[ap][row][(chunk ^ (row & 7)) * 8]);
      }
      #pragma unroll
      for (int rf = 0; rf < 4; ++rf)
        #pragma unroll
        for (int nfi = 0; nfi < 2; ++nfi)
          acc[rf][nfi] = __builtin_amdgcn_mfma_f32_16x16x32_bf16(
              afr[rf], bfr[nfi], acc[rf][nfi], 0, 0, 0);
    }
  }

  const float b0 = bl[w * 32 + (lane & 15)];
  const float b1 = bl[w * 32 + 16 + (lane & 15)];

  #pragma unroll
  for (int rf = 0; rf < 4; ++rf) {
    #pragma unroll
    for (int r4 = 0; r4 < 4; ++r4) {
      float v0 = acc[rf][0][r4] + b0;
      float v1 = acc[rf][1][r4] + b1;
      acc[rf][0][r4] = v0;
      acc[rf][1][r4] = v1;
      float sq = v0 * v0 + v1 * v1;
      sq += __shfl_xor(sq, 1, 64);
      sq += __shfl_xor(sq, 2, 64);
      sq += __shfl_xor(sq, 4, 64);
      sq += __shfl_xor(sq, 8, 64);
      if ((lane & 15) == 0) rowsq[rf * 16 + (lane >> 4) * 4 + r4][w] = sq;
    }
  }
  __syncthreads();
  if (t < 64) {
    float s = rowsq[t][0] + rowsq[t][1] + rowsq[t][2] + rowsq[t][3];
    rscale[t] = 1.0f / fmaxf(sqrtf(s), 1e-12f);
  }
  __syncthreads();

  float cs0 = 0.f, cq0 = 0.f, cs1 = 0.f, cq1 = 0.f;
  #pragma unroll
  for (int rf = 0; rf < 4; ++rf) {
    #pragma unroll
    for (int r4 = 0; r4 < 4; ++r4) {
      int rl = rf * 16 + (lane >> 4) * 4 + r4;
      int row = i0 + rl;
      float s = rscale[rl];
      float u0 = fmaxf(acc[rf][0][r4] * s, 0.f);
      float u1 = fmaxf(acc[rf][1][r4] * s, 0.f);
      if (row < n) {
        out[(size_t)row * H + w * 32 + (lane & 15)] = u0;
        out[(size_t)row * H + w * 32 + 16 + (lane & 15)] = u1;
        cs0 += u0; cq0 += u0 * u0;
        cs1 += u1; cq1 += u1 * u1;
      }
    }
  }
  cs0 += __shfl_xor(cs0, 16, 64); cs0 += __shfl_xor(cs0, 32, 64);
  cq0 += __shfl_xor(cq0, 16, 64); cq0 += __shfl_xor(cq0, 32, 64);
  cs1 += __shfl_xor(cs1, 16, 64); cs1 += __shfl_xor(cs1, 32, 64);
  cq1 += __shfl_xor(cq1, 16, 64); cq1 += __shfl_xor(cq1, 32, 64);
  if (lane < 16) {
    atomicAdd(&colsum[w * 32 + lane], cs0);
    atomicAdd(&colsq[w * 32 + lane], cq0);
    atomicAdd(&colsum[w * 32 + 16 + lane], cs1);
    atomicAdd(&colsq[w * 32 + 16 + lane], cq1);
  }
}

// ---------------------------------------------------------------------------
// Fallback path (tiny ws): atomic scatter + divide + scalar fused gemm.
// ---------------------------------------------------------------------------
__global__ __launch_bounds__(256) void scatter_mean(
    const float* __restrict__ x, const void* __restrict__ eiv,
    const int* __restrict__ flag, float* __restrict__ agg,
    float* __restrict__ deg, int E) {
  long long gid = (long long)blockIdx.x * blockDim.x + threadIdx.x;
  int e = (int)(gid >> 5);
  int ch = (int)(gid & 31);
  if (e >= E) return;
  int is64 = *flag;
  int src = load_idx(eiv, is64, e);
  int dst = load_idx(eiv, is64, (long long)E + e);
  float4 v = *(const float4*)(x + (size_t)src * F + ch * 4);
  float* a = agg + (size_t)dst * H + ch * 4;
  atomicAdd(a + 0, v.x);
  atomicAdd(a + 1, v.y);
  atomicAdd(a + 2, v.z);
  atomicAdd(a + 3, v.w);
  if (ch == 0) atomicAdd(deg + dst, 1.0f);
}

__global__ __launch_bounds__(256) void divide_deg(float* __restrict__ out,
                                                  const float* __restrict__ deg,
                                                  long long n4) {
  long long i = (long long)blockIdx.x * blockDim.x + threadIdx.x;
  if (i >= n4) return;
  int node = (int)(i >> 5);
  float s = 1.0f / fmaxf(deg[node], 1.0f);
  float4 v = ((float4*)out)[i];
  v.x *= s; v.y *= s; v.z *= s; v.w *= s;
  ((float4*)out)[i] = v;
}

__global__ __launch_bounds__(256) void fused_gemm(
    const float* __restrict__ x, const float* __restrict__ Wl,
    const float* __restrict__ bl, const float* __restrict__ Wr,
    float* __restrict__ out, float* __restrict__ colsum, float* __restrict__ colsq) {
  __shared__ float As[16][256];
  __shared__ float rp[4][8];
  __shared__ float rscale[16];
  __shared__ float cs[128], cs2[128];

  const int t = threadIdx.x;
  const int i0 = blockIdx.x * 16;

  #pragma unroll
  for (int it = 0; it < 2; ++it) {
    int idx = (it * 256 + t) * 4;
    int r = idx >> 7, c = idx & 127;
    float4 va = *(const float4*)(out + (size_t)(i0 + r) * H + c);
    As[r][c + 0] = va.x; As[r][c + 1] = va.y;
    As[r][c + 2] = va.z; As[r][c + 3] = va.w;
    float4 vx = *(const float4*)(x + (size_t)(i0 + r) * F + c);
    As[r][128 + c + 0] = vx.x; As[r][128 + c + 1] = vx.y;
    As[r][128 + c + 2] = vx.z; As[r][128 + c + 3] = vx.w;
  }
  __syncthreads();

  const int c = t & 127;
  const int half = t >> 7;
  float acc[8];
  #pragma unroll
  for (int r = 0; r < 8; ++r) acc[r] = 0.0f;

  #pragma unroll 4
  for (int k = 0; k < 128; ++k) {
    float w = Wl[k * H + c];
    #pragma unroll
    for (int r = 0; r < 8; ++r) acc[r] = fmaf(As[half * 8 + r][k], w, acc[r]);
  }
  #pragma unroll 4
  for (int k = 0; k < 128; ++k) {
    float w = Wr[k * H + c];
    #pragma unroll
    for (int r = 0; r < 8; ++r) acc[r] = fmaf(As[half * 8 + r][128 + k], w, acc[r]);
  }
  const float bias = bl[c];
  #pragma unroll
  for (int r = 0; r < 8; ++r) acc[r] += bias;

  float sq[8];
  #pragma unroll
  for (int r = 0; r < 8; ++r) sq[r] = acc[r] * acc[r];
  #pragma unroll
  for (int off = 32; off > 0; off >>= 1) {
    #pragma unroll
    for (int r = 0; r < 8; ++r) sq[r] += __shfl_down(sq[r], off, 64);
  }
  const int wv = t >> 6;
  if ((t & 63) == 0) {
    #pragma unroll
    for (int r = 0; r < 8; ++r) rp[wv][r] = sq[r];
  }
  __syncthreads();
  if (t < 16) {
    int base = (t >> 3) * 2, rr = t & 7;
    float s = rp[base][rr] + rp[base + 1][rr];
    rscale[t] = 1.0f / fmaxf(sqrtf(s), 1e-12f);
  }
  __syncthreads();

  float csum = 0.0f, csq = 0.0f;
  #pragma unroll
  for (int r = 0; r < 8; ++r) {
    float v = fmaxf(acc[r] * rscale[half * 8 + r], 0.0f);
    out[(size_t)(i0 + half * 8 + r) * H + c] = v;
    csum += v;
    csq += v * v;
  }
  if (half == 1) { cs[c] = csum; cs2[c] = csq; }
  __syncthreads();
  if (half == 0) {
    atomicAdd(&colsum[c], csum + cs[c]);
    atomicAdd(&colsq[c], csq + cs2[c]);
  }
}

__global__ void bn_stats(const float* __restrict__ colsum, const float* __restrict__ colsq,
                         const float* __restrict__ gamma, const float* __restrict__ beta,
                         float* __restrict__ scale, float* __restrict__ shift, int n) {
  int c = threadIdx.x;
  if (c < H) {
    float inv_n = 1.0f / (float)n;
    float mean = colsum[c] * inv_n;
    float var = colsq[c] * inv_n - mean * mean;  // biased (torch BN)
    float istd = rsqrtf(var + 1e-5f);
    float sc = gamma[c] * istd;
    scale[c] = sc;
    shift[c] = beta[c] - mean * sc;
  }
}

__global__ __launch_bounds__(256) void bn_apply(
    float* __restrict__ out, const float* __restrict__ scale,
    const float* __restrict__ shift, long long n4) {
  long long i = (long long)blockIdx.x * blockDim.x + threadIdx.x;
  if (i >= n4) return;
  float4 v = ((float4*)out)[i];
  int c = (int)((i * 4) & (H - 1));
  v.x = fmaf(v.x, scale[c + 0], shift[c + 0]);
  v.y = fmaf(v.y, scale[c + 1], shift[c + 1]);
  v.z = fmaf(v.z, scale[c + 2], shift[c + 2]);
  v.w = fmaf(v.w, scale[c + 3], shift[c + 3]);
  ((float4*)out)[i] = v;
}

// reads pre-BN u (bf16 in ws), writes final f32 to out
__global__ __launch_bounds__(256) void bn_apply_lo(
    const unsigned short* __restrict__ U, float* __restrict__ out,
    const float* __restrict__ scale, const float* __restrict__ shift,
    long long n4) {
  long long i = (long long)blockIdx.x * blockDim.x + threadIdx.x;
  if (i >= n4) return;
  uint2 uv = ((const uint2*)U)[i];
  int c = (int)((i * 4) & (H - 1));
  float4 v;
  v.x = fmaf(bits2f(uv.x << 16),          scale[c + 0], shift[c + 0]);
  v.y = fmaf(bits2f(uv.x & 0xFFFF0000u),  scale[c + 1], shift[c + 1]);
  v.z = fmaf(bits2f(uv.y << 16),          scale[c + 2], shift[c + 2]);
  v.w = fmaf(bits2f(uv.y & 0xFFFF0000u),  scale[c + 3], shift[c + 3]);
  ((float4*)out)[i] = v;
}

extern "C" void kernel_launch(void* const* d_in, const int* in_sizes, int n_in,
                              void* d_out, int out_size, void* d_ws, size_t ws_size,
                              hipStream_t stream) {
  const float* x     = (const float*)d_in[0];
  const void*  ei    = d_in[1];
  const float* Wl    = (const float*)d_in[2];
  const float* bl    = (const float*)d_in[3];
  const float* Wr    = (const float*)d_in[4];
  const float* gamma = (const float*)d_in[5];
  const float* beta  = (const float*)d_in[6];
  float* out = (float*)d_out;

  const int n = in_sizes[0] / F;   // 100000
  const int E = in_sizes[1] / 2;   // 1600000
  const int nb = (n + 255) / 256;
  const int nbuck = (n + 63) >> 6; // 64-node buckets

  char* ws = (char*)d_ws;
  int* flag = (int*)ws;
  unsigned short* Wcat = (unsigned short*)(ws + 256);
  char* after_w = ws + 256 + 4 * 128 * 128 * 2;

  // ---- fast-path layout: partition + Y fp8 (+P,U bf16) ----
  int*   cmat    = (int*)after_w;
  int*   obuf    = cmat + 2048 * NPART;
  int*   bsum    = obuf + 2048 * NPART;
  int*   boff    = bsum + 1024;
  int*   bbase   = boff + 1024;
  float* fcs     = (float*)(bbase + 2049);
  float* fcq     = fcs + H;
  float* fsc     = fcq + H;
  float* fsh     = fsc + H;
  int*   ebuf    = (int*)(fsh + H);
  unsigned char*  Yf8 = (unsigned char*)(ebuf + E);
  unsigned short* Pws = (unsigned short*)(Yf8 + (size_t)n * H);
  unsigned short* Uws = Pws + (size_t)n * H;
  size_t need_fast  = (size_t)((char*)(Yf8 + (size_t)n * H) - ws);
  size_t need_fast2 = (size_t)((char*)(Uws + (size_t)n * H) - ws);

  // ---- mid-path layout: CSR ----
  int*   degi     = (int*)after_w;
  int*   offsets  = degi + n;
  int*   cursor   = offsets + n + 1;
  int*   blocksum = cursor + n;
  int*   blockoff = blocksum + nb;
  float* mcs      = (float*)(blockoff + nb);
  float* mcq      = mcs + H;
  float* msc      = mcq + H;
  float* msh      = msc + H;
  int*   csr_src  = (int*)(msh + H);
  size_t need_mid = (size_t)((char*)(csr_src + E) - ws);

  float *colsum, *colsq, *scale, *shift;

  const int eb = (E + 255) / 256;
  const int gb = (n + 63) / 64;
  const long long n4 = (long long)n * H / 4;

  if (ws_size >= need_fast && nbuck <= 2048) {
    const bool lowp = (ws_size >= need_fast2);
    colsum = fcs; colsq = fcq; scale = fsc; shift = fsh;

    const int chunk = (E + NPART - 1) / NPART;
    const int L = nbuck * NPART;
    const int nb2 = (L + 255) / 256;   // <= 1024

    prep_w<<<32, 256, 0, stream>>>(Wl, Wr, Wcat);
    if (lowp)
      fused_gemm_hist<true><<<NPART + gb, 256, 0, stream>>>(
          x, Wcat, bl, Yf8, out, Pws, n, ei, cmat, E, nbuck, chunk);
    else
      fused_gemm_hist<false><<<NPART + gb, 256, 0, stream>>>(
          x, Wcat, bl, Yf8, out, Pws, n, ei, cmat, E, nbuck, chunk);

    scan1<<<nb2, 256, 0, stream>>>(cmat, obuf, bsum, L);
    scan2big<<<1, 1024, 0, stream>>>(bsum, boff, nb2);
    scan3p<<<nb2, 256, 0, stream>>>(obuf, boff, bbase, colsum, L, nbuck, E);
    part_scatter<<<NPART, 512, 0, stream>>>(ei, obuf, ebuf, E, nbuck, chunk);

    if (lowp)
      gather_bucket<true><<<nbuck, 256, 0, stream>>>(
          Yf8, ebuf, bbase, out, Pws, Uws, colsum, colsq, n);
    else
      gather_bucket<false><<<nbuck, 256, 0, stream>>>(
          Yf8, ebuf, bbase, out, Pws, Uws, colsum, colsq, n);

    bn_stats<<<1, 128, 0, stream>>>(colsum, colsq, gamma, beta, scale, shift, n);
    if (lowp)
      bn_apply_lo<<<(int)((n4 + 255) / 256), 256, 0, stream>>>(
          Uws, out, scale, shift, n4);
    else
      bn_apply<<<(int)((n4 + 255) / 256), 256, 0, stream>>>(out, scale, shift, n4);
  } else if (ws_size >= need_mid) {
    colsum = mcs; colsq = mcq; scale = msc; shift = msh;
    detect_dtype<<<1, 64, 0, stream>>>((const unsigned*)ei, flag);
    hipMemsetAsync(degi, 0, (size_t)n * 4, stream);
    hipMemsetAsync(colsum, 0, 2 * H * 4, stream);

    prep_w<<<32, 256, 0, stream>>>(Wl, Wr, Wcat);

    deg_count<<<eb, 256, 0, stream>>>(ei, flag, degi, E);
    scan1<<<nb, 256, 0, stream>>>(degi, offsets, blocksum, n);
    scan2big<<<1, 1024, 0, stream>>>(blocksum, blockoff, nb);
    scan3<<<nb, 256, 0, stream>>>(offsets, blockoff, cursor, n, E);
    bucket_fill<<<eb, 256, 0, stream>>>(ei, flag, cursor, csr_src, E);

    long long gthreads = (long long)n * 64;
    gather_mean<<<(int)((gthreads + 255) / 256), 256, 0, stream>>>(
        x, offsets, csr_src, out, n);

    mfma_gemm<<<gb, 256, 0, stream>>>(x, Wcat, bl, out, colsum, colsq, n);
    bn_stats<<<1, 128, 0, stream>>>(colsum, colsq, gamma, beta, scale, shift, n);
    bn_apply<<<(int)((n4 + 255) / 256), 256, 0, stream>>>(out, scale, shift, n4);
  } else {
    float* deg = (float*)(ws + 256);
    colsum = deg + n; colsq = colsum + H; scale = colsq + H; shift = scale + H;
    detect_dtype<<<1, 64, 0, stream>>>((const unsigned*)ei, flag);
    hipMemsetAsync(d_out, 0, (size_t)out_size * sizeof(float), stream);
    hipMemsetAsync(deg, 0, (size_t)n * 4 + 4 * H * 4, stream);
    long long sthreads = (long long)E * 32;
    scatter_mean<<<(int)((sthreads + 255) / 256), 256, 0, stream>>>(x, ei, flag, out, deg, E);
    long long n4f = (long long)n * H / 4;
    divide_deg<<<(int)((n4f + 255) / 256), 256, 0, stream>>>(out, deg, n4f);
    fused_gemm<<<n / 16, 256, 0, stream>>>(x, Wl, bl, Wr, out, colsum, colsq);
    bn_stats<<<1, 128, 0, stream>>>(colsum, colsq, gamma, beta, scale, shift, n);
    bn_apply<<<(int)((n4 + 255) / 256), 256, 0, stream>>>(out, scale, shift, n4);
  }
}

// Round 13
// 188.815 us; speedup vs baseline: 1.4056x; 1.0095x over previous
//
#include <hip/hip_runtime.h>
#include <hip/hip_bf16.h>

static constexpr int F = 128;
static constexpr int H = 128;
static constexpr int NPART = 128;   // partition blocks (contiguous edge chunks)

typedef __attribute__((ext_vector_type(8))) short short8;
typedef __attribute__((ext_vector_type(4))) float f32x4;
typedef __attribute__((ext_vector_type(2))) _Float16 h2v;

__device__ __forceinline__ unsigned short f2bf(float f) {
  union { float f; unsigned u; } a; a.f = f;
  unsigned r = a.u + 0x7FFF + ((a.u >> 16) & 1);
  return (unsigned short)(r >> 16);
}
__device__ __forceinline__ float bf2f(unsigned short h) {
  union { unsigned u; float f; } a; a.u = ((unsigned)h) << 16;
  return a.f;
}
__device__ __forceinline__ float bits2f(unsigned u) {
  union { unsigned u; float f; } a; a.u = u;
  return a.f;
}
__device__ __forceinline__ h2v bits2h2(unsigned u) {
  union { unsigned u; h2v h; } a; a.u = u; return a.h;
}

// f32 -> fp8 e4m3fn (RNE, flush-to-zero below 2^-6, clamp to 448)
__device__ __forceinline__ unsigned f2fp8(float f) {
  union { float f; unsigned u; } a; a.f = f;
  unsigned s = (a.u >> 24) & 0x80u;
  unsigned m = a.u & 0x7FFFFFFFu;
  if (m < 0x3C800000u) return s;                 // |f| < 2^-6 -> signed zero code
  unsigned r = m + 0x7FFFFu + ((m >> 20) & 1u);  // RNE to 3 mantissa bits
  if (r > 0x43E00000u) r = 0x43E00000u;          // clamp to 448 (max finite)
  return s | ((((r >> 23) - 120u) & 15u) << 3) | ((r >> 20) & 7u);
}

// Packed decode: 4 fp8 bytes -> 2 packed-f16 pairs (v0,v2) and (v1,v3).
// f16 halfword = sign<<15 | (mag<<7) + 0x2000 (bias 7->15); code 0 -> +/-2^-7.
__device__ __forceinline__ void fp8x4_to_h2(unsigned w, h2v& p02, h2v& p13) {
  unsigned lo = w & 0x00FF00FFu;
  unsigned hi = (w >> 8) & 0x00FF00FFu;
  unsigned q0 = (((lo << 7) & 0x3F803F80u) + 0x20002000u) | ((lo & 0x00800080u) << 8);
  unsigned q1 = (((hi << 7) & 0x3F803F80u) + 0x20002000u) | ((hi & 0x00800080u) << 8);
  p02 = bits2h2(q0);
  p13 = bits2h2(q1);
}

// f32 decode (slow path only)
__device__ __forceinline__ void fp8x4_to_f32(unsigned w, float& f0, float& f1,
                                             float& f2, float& f3) {
  unsigned lo = w & 0x00FF00FFu;
  unsigned hi = (w >> 8) & 0x00FF00FFu;
  unsigned p0 = (((lo << 4) & 0x07F007F0u) + 0x3C003C00u) | ((lo & 0x00800080u) << 8);
  unsigned p1 = (((hi << 4) & 0x07F007F0u) + 0x3C003C00u) | ((hi & 0x00800080u) << 8);
  f0 = bits2f(p0 << 16);
  f2 = bits2f(p0 & 0xFFFF0000u);
  f1 = bits2f(p1 << 16);
  f3 = bits2f(p1 & 0xFFFF0000u);
}

// int64-vs-int32 edge_index detection (values < 2^17 -> int64 hi words all 0)
__device__ __forceinline__ int detect64(const void* eiv) {
  const unsigned* u = (const unsigned*)eiv;
  int is64 = 1;
  for (int i = 0; i < 64; ++i) is64 &= (u[2 * i + 1] == 0u);
  return is64;
}

__global__ void detect_dtype(const unsigned* __restrict__ ei, int* __restrict__ flag) {
  if (blockIdx.x == 0 && threadIdx.x == 0) {
    int is64 = 1;
    for (int i = 0; i < 64; ++i) {
      if (ei[2 * i + 1] != 0u) { is64 = 0; break; }
    }
    *flag = is64;
  }
}

__device__ __forceinline__ int load_idx(const void* eiv, int is64, long long pos) {
  return is64 ? (int)((const long long*)eiv)[pos] : ((const int*)eiv)[pos];
}

// ---------------------------------------------------------------------------
// scans for two-pass partition
// ---------------------------------------------------------------------------
__global__ __launch_bounds__(256) void scan1(const int* __restrict__ in,
                                             int* __restrict__ outx,
                                             int* __restrict__ blocksum, int n) {
  __shared__ int sm[256];
  int idx = blockIdx.x * 256 + threadIdx.x;
  int v = (idx < n) ? in[idx] : 0;
  sm[threadIdx.x] = v;
  __syncthreads();
  #pragma unroll
  for (int off = 1; off < 256; off <<= 1) {
    int t = (threadIdx.x >= off) ? sm[threadIdx.x - off] : 0;
    __syncthreads();
    sm[threadIdx.x] += t;
    __syncthreads();
  }
  if (idx < n) outx[idx] = sm[threadIdx.x] - v;
  if (threadIdx.x == 255) blocksum[blockIdx.x] = sm[255];
}

__global__ __launch_bounds__(1024) void scan2big(const int* __restrict__ blocksum,
                                                 int* __restrict__ blockoff, int nb) {
  __shared__ int sm[1024];
  int t = threadIdx.x;
  int v = (t < nb) ? blocksum[t] : 0;
  sm[t] = v;
  __syncthreads();
  for (int off = 1; off < 1024; off <<= 1) {
    int u = (t >= off) ? sm[t - off] : 0;
    __syncthreads();
    sm[t] += u;
    __syncthreads();
  }
  if (t < nb) blockoff[t] = sm[t] - v;
}

// finalize partition scan: base matrix in place + bucket segment starts.
// Block 0 also zeroes colsum/colsq (256 contiguous floats).
__global__ __launch_bounds__(256) void scan3p(int* __restrict__ obuf,
                                              const int* __restrict__ blockoff,
                                              int* __restrict__ bbase,
                                              float* __restrict__ colzero,
                                              int L, int nbuck, int E) {
  if (blockIdx.x == 0) colzero[threadIdx.x] = 0.0f;
  int idx = blockIdx.x * 256 + threadIdx.x;
  if (idx >= L) return;
  int v = obuf[idx] + blockoff[idx >> 8];
  obuf[idx] = v;
  if ((idx & (NPART - 1)) == 0) bbase[idx / NPART] = v;
  if (idx == 0) bbase[nbuck] = E;
}

// ---------------------------------------------------------------------------
// unionA: blocks [0,NPART) = part_hist; blocks [NPART,NPART+32) = prep_w.
// Both independent; overlapped in one dispatch.
// ---------------------------------------------------------------------------
__global__ __launch_bounds__(256) void union_hist_prep(
    const void* __restrict__ eiv, int* __restrict__ cmat, int E, int nbuck,
    int chunk, const float* __restrict__ Wl, const float* __restrict__ Wr,
    unsigned short* __restrict__ Wcat) {
  __shared__ int h[2048];
  const int t = threadIdx.x;

  if (blockIdx.x < NPART) {
    const int b = blockIdx.x;
    for (int i = t; i < nbuck; i += 256) h[i] = 0;
    __syncthreads();
    int is64 = detect64(eiv);
    int s = b * chunk, e = min(E, s + chunk);
    for (int i = s + t; i < e; i += 256) {
      int dst = load_idx(eiv, is64, (long long)E + i);
      atomicAdd(&h[dst >> 6], 1);
    }
    __syncthreads();
    for (int i = t; i < nbuck; i += 256) cmat[i * NPART + b] = h[i];
    return;
  }

  // ---- prep_w: split Wl/Wr into bf16 hi/lo in MFMA fragment-blob order ----
  int tid = (blockIdx.x - NPART) * 256 + t;
  if (tid >= 4 * 4 * 8 * 64) return;
  int lane = tid & 63;
  int nf   = (tid >> 6) & 7;
  int kc   = (tid >> 9) & 3;
  int part = tid >> 11;
  const float* W = (part < 2) ? Wl : Wr;
  bool lo = (part & 1);
  int ncol = nf * 16 + (lane & 15);
  int k0 = kc * 32 + (lane >> 4) * 8;
  unsigned short ov[8];
  #pragma unroll
  for (int j = 0; j < 8; ++j) {
    float v = W[(k0 + j) * H + ncol];
    unsigned short hh = f2bf(v);
    ov[j] = lo ? f2bf(v - bf2f(hh)) : hh;
  }
  uint4 pack;
  pack.x = (unsigned)ov[0] | ((unsigned)ov[1] << 16);
  pack.y = (unsigned)ov[2] | ((unsigned)ov[3] << 16);
  pack.z = (unsigned)ov[4] | ((unsigned)ov[5] << 16);
  pack.w = (unsigned)ov[6] | ((unsigned)ov[7] << 16);
  *(uint4*)(Wcat + (size_t)tid * 8) = pack;
}

// ---------------------------------------------------------------------------
// unionB<LOWP>: blocks [0,NPART) = part_scatter; blocks [NPART,..) = dual_gemm.
// Scatter (needs scans) and GEMM (needs Wcat) are independent -> overlapped.
// ---------------------------------------------------------------------------
template <bool LOWP>
__global__ __launch_bounds__(256) void union_scatter_gemm(
    const void* __restrict__ eiv, const int* __restrict__ base,
    int* __restrict__ ebuf, int E, int nbuck, int chunk,
    const float* __restrict__ x, const unsigned short* __restrict__ Wcat,
    const float* __restrict__ bl, unsigned char* __restrict__ Yf8,
    float* __restrict__ pout, unsigned short* __restrict__ Pbf, int n) {
  __shared__ unsigned short As[2][64][128];  // 32KB; scatter aliases first 8KB

  const int t = threadIdx.x;

  if (blockIdx.x < NPART) {
    // ---- part_scatter ----
    int* cur = (int*)&As[0][0][0];
    const int b = blockIdx.x;
    for (int i = t; i < nbuck; i += 256) cur[i] = base[i * NPART + b];
    __syncthreads();
    int is64 = detect64(eiv);
    int s = b * chunk, e = min(E, s + chunk);
    for (int i = s + t; i < e; i += 256) {
      int src = load_idx(eiv, is64, i);
      int dst = load_idx(eiv, is64, (long long)E + i);
      int pos = atomicAdd(&cur[dst >> 6], 1);
      ebuf[pos] = (src << 6) | (dst & 63);
    }
    return;
  }

  // ---- dual_gemm ----
  const int i0 = (blockIdx.x - NPART) * 64;

  #pragma unroll
  for (int it = 0; it < 8; ++it) {
    int idx = it * 256 + t;
    int r = idx >> 5;
    int c4 = (idx & 31) * 4;
    int row_g = i0 + r; if (row_g >= n) row_g = n - 1;
    int boff = (((c4 >> 3) ^ (r & 7)) << 3) + (c4 & 7);
    float4 vx = *(const float4*)(x + (size_t)row_g * F + c4);
    unsigned short h0 = f2bf(vx.x), h1 = f2bf(vx.y), h2 = f2bf(vx.z), h3 = f2bf(vx.w);
    uint2 hv = { (unsigned)h0 | ((unsigned)h1 << 16), (unsigned)h2 | ((unsigned)h3 << 16) };
    *(uint2*)&As[0][r][boff] = hv;
    unsigned short l0 = f2bf(vx.x - bf2f(h0)), l1 = f2bf(vx.y - bf2f(h1));
    unsigned short l2 = f2bf(vx.z - bf2f(h2)), l3 = f2bf(vx.w - bf2f(h3));
    uint2 lv = { (unsigned)l0 | ((unsigned)l1 << 16), (unsigned)l2 | ((unsigned)l3 << 16) };
    *(uint2*)&As[1][r][boff] = lv;
  }
  __syncthreads();

  const int w = t >> 6;
  const int lane = t & 63;

  f32x4 accL[4][2], accR[4][2];
  #pragma unroll
  for (int rf = 0; rf < 4; ++rf)
    #pragma unroll
    for (int nfi = 0; nfi < 2; ++nfi) {
      accL[rf][nfi] = (f32x4){0.f, 0.f, 0.f, 0.f};
      accR[rf][nfi] = (f32x4){0.f, 0.f, 0.f, 0.f};
    }

  const int APM[3] = {0, 1, 0};
  const int BL[3]  = {0, 0, 1};   // Wl_hi, Wl_hi, Wl_lo
  const int BR[3]  = {2, 2, 3};   // Wr_hi, Wr_hi, Wr_lo

  #pragma unroll
  for (int pass = 0; pass < 3; ++pass) {
    const int ap = APM[pass];
    #pragma unroll
    for (int kc = 0; kc < 4; ++kc) {
      short8 afr[4];
      int chunk2 = kc * 4 + (lane >> 4);
      #pragma unroll
      for (int rf = 0; rf < 4; ++rf) {
        int row = rf * 16 + (lane & 15);
        afr[rf] = *(const short8*)(&As[ap][row][(chunk2 ^ (row & 7)) * 8]);
      }
      short8 bfrL[2], bfrR[2];
      #pragma unroll
      for (int nfi = 0; nfi < 2; ++nfi) {
        int blobL = (BL[pass] * 4 + kc) * 8 + (w * 2 + nfi);
        int blobR = (BR[pass] * 4 + kc) * 8 + (w * 2 + nfi);
        bfrL[nfi] = *(const short8*)(Wcat + (size_t)blobL * 512 + lane * 8);
        bfrR[nfi] = *(const short8*)(Wcat + (size_t)blobR * 512 + lane * 8);
      }
      #pragma unroll
      for (int rf = 0; rf < 4; ++rf)
        #pragma unroll
        for (int nfi = 0; nfi < 2; ++nfi) {
          accL[rf][nfi] = __builtin_amdgcn_mfma_f32_16x16x32_bf16(
              afr[rf], bfrL[nfi], accL[rf][nfi], 0, 0, 0);
          accR[rf][nfi] = __builtin_amdgcn_mfma_f32_16x16x32_bf16(
              afr[rf], bfrR[nfi], accR[rf][nfi], 0, 0, 0);
        }
    }
  }

  const float b0 = bl[w * 32 + (lane & 15)];
  const float b1 = bl[w * 32 + 16 + (lane & 15)];

  #pragma unroll
  for (int rf = 0; rf < 4; ++rf) {
    #pragma unroll
    for (int r4 = 0; r4 < 4; ++r4) {
      int rl = rf * 16 + (lane >> 4) * 4 + r4;
      int row = i0 + rl;
      if (row < n) {
        Yf8[(size_t)row * H + w * 32 + (lane & 15)]      = (unsigned char)f2fp8(accL[rf][0][r4]);
        Yf8[(size_t)row * H + w * 32 + 16 + (lane & 15)] = (unsigned char)f2fp8(accL[rf][1][r4]);
        if (LOWP) {
          Pbf[(size_t)row * H + w * 32 + (lane & 15)]      = f2bf(accR[rf][0][r4] + b0);
          Pbf[(size_t)row * H + w * 32 + 16 + (lane & 15)] = f2bf(accR[rf][1][r4] + b1);
        } else {
          pout[(size_t)row * H + w * 32 + (lane & 15)]      = accR[rf][0][r4] + b0;
          pout[(size_t)row * H + w * 32 + 16 + (lane & 15)] = accR[rf][1][r4] + b1;
        }
      }
    }
  }
}

// ---------------------------------------------------------------------------
// gather_bucket<LOWP>: one block per 64-node bucket (2 nodes/wave, 32
// lanes/node, 8-deep unroll). Y fp8 decoded to packed f16; accumulation via
// v_pk_add_f16. Fused epilogue: v = P + agg; row-L2-norm; ReLU; store u;
// BN col stats.  (Byte-identical to round-12 proven version.)
// ---------------------------------------------------------------------------
#define GCAP 2048
template <bool LOWP>
__global__ __launch_bounds__(256) void gather_bucket(
    const unsigned char* __restrict__ Yf8, const int* __restrict__ ebuf,
    const int* __restrict__ bbase, float* __restrict__ pio,
    const unsigned short* __restrict__ Pbf, unsigned short* __restrict__ Ubf,
    float* __restrict__ colsum, float* __restrict__ colsq, int n) {
  __shared__ int lsrc[GCAP];
  __shared__ int hist[65];
  __shared__ int loff[65];
  __shared__ int cur[64];
  __shared__ float csm[128], cqm[128];

  const int t = threadIdx.x;
  const int b = blockIdx.x;
  const int node0 = b << 6;
  const int s = bbase[b], e = bbase[b + 1];
  const int cnt = e - s;

  if (t < 65) hist[t] = 0;
  if (t < 128) { csm[t] = 0.f; cqm[t] = 0.f; }
  __syncthreads();

  const bool fast = (cnt <= GCAP);
  if (fast) {
    for (int i = s + t; i < e; i += 256)
      atomicAdd(&hist[ebuf[i] & 63], 1);
    __syncthreads();
    if (t < 64) loff[t] = hist[t];
    __syncthreads();
    #pragma unroll
    for (int off = 1; off < 64; off <<= 1) {
      int u = (t >= off && t < 64) ? loff[t - off] : 0;
      __syncthreads();
      if (t < 64) loff[t] += u;
      __syncthreads();
    }
    if (t < 64) cur[t] = loff[t] - hist[t];
    __syncthreads();
    for (int i = s + t; i < e; i += 256) {
      int p = ebuf[i];
      int pos = atomicAdd(&cur[p & 63], 1);
      lsrc[pos] = p >> 6;
    }
    __syncthreads();
  }

  const int lane = t & 63;
  const int w = t >> 6;
  const int half = lane >> 5;
  const int c = (lane & 31) * 4;   // byte column (4 fp8 per lane)

  float lcs[4] = {0.f, 0.f, 0.f, 0.f};
  float lcq[4] = {0.f, 0.f, 0.f, 0.f};

  #pragma unroll
  for (int it = 0; it < 8; ++it) {
    int ln = it * 8 + w * 2 + half;
    int node = node0 + ln;
    if (node >= n) continue;
    int ls, le;
    if (fast) { ls = loff[ln] - hist[ln]; le = loff[ln]; }
    else      { ls = 0; le = 0; }

    h2v a02[8], a13[8];
    #pragma unroll
    for (int u = 0; u < 8; ++u) {
      a02[u] = (h2v)(_Float16)0;
      a13[u] = (h2v)(_Float16)0;
    }

    int j = ls;
    for (; j + 7 < le; j += 8) {
      #pragma unroll
      for (int u = 0; u < 8; ++u) {
        int sj = lsrc[j + u];
        unsigned wv = *(const unsigned*)(Yf8 + (size_t)sj * H + c);
        h2v p02, p13;
        fp8x4_to_h2(wv, p02, p13);
        a02[u] += p02;
        a13[u] += p13;
      }
    }
    for (; j + 1 < le; j += 2) {
      #pragma unroll
      for (int u = 0; u < 2; ++u) {
        int sj = lsrc[j + u];
        unsigned wv = *(const unsigned*)(Yf8 + (size_t)sj * H + c);
        h2v p02, p13;
        fp8x4_to_h2(wv, p02, p13);
        a02[u] += p02;
        a13[u] += p13;
      }
    }
    if (j < le) {
      int sj = lsrc[j];
      unsigned wv = *(const unsigned*)(Yf8 + (size_t)sj * H + c);
      h2v p02, p13;
      fp8x4_to_h2(wv, p02, p13);
      a02[0] += p02;
      a13[0] += p13;
    }

    float deg = 0.0f;
    float a0, a1, a2, a3;
    if (fast) {
      deg = (float)(le - ls);
      h2v s02 = ((a02[0] + a02[1]) + (a02[2] + a02[3])) +
                ((a02[4] + a02[5]) + (a02[6] + a02[7]));
      h2v s13 = ((a13[0] + a13[1]) + (a13[2] + a13[3])) +
                ((a13[4] + a13[5]) + (a13[6] + a13[7]));
      a0 = (float)s02[0]; a2 = (float)s02[1];
      a1 = (float)s13[0]; a3 = (float)s13[1];
    } else {
      // slow path (statistically unreachable): scan whole bucket in f32
      a0 = a1 = a2 = a3 = 0.0f;
      for (int jj = s; jj < e; ++jj) {
        int p = ebuf[jj];
        if ((p & 63) == ln) {
          deg += 1.0f;
          unsigned wv = *(const unsigned*)(Yf8 + (size_t)(p >> 6) * H + c);
          float f0, f1, f2, f3;
          fp8x4_to_f32(wv, f0, f1, f2, f3);
          a0 += f0; a1 += f1; a2 += f2; a3 += f3;
        }
      }
    }

    float inv = 1.0f / fmaxf(deg, 1.0f);
    float p0, p1, p2, p3;
    if (LOWP) {
      uint2 pv = *(const uint2*)(Pbf + (size_t)node * H + c);
      p0 = bits2f(pv.x << 16);
      p1 = bits2f(pv.x & 0xFFFF0000u);
      p2 = bits2f(pv.y << 16);
      p3 = bits2f(pv.y & 0xFFFF0000u);
    } else {
      float4 p = *(const float4*)(pio + (size_t)node * H + c);
      p0 = p.x; p1 = p.y; p2 = p.z; p3 = p.w;
    }
    float v0 = p0 + a0 * inv;
    float v1 = p1 + a1 * inv;
    float v2 = p2 + a2 * inv;
    float v3 = p3 + a3 * inv;
    float sq = v0 * v0 + v1 * v1 + v2 * v2 + v3 * v3;
    sq += __shfl_xor(sq, 1, 64);
    sq += __shfl_xor(sq, 2, 64);
    sq += __shfl_xor(sq, 4, 64);
    sq += __shfl_xor(sq, 8, 64);
    sq += __shfl_xor(sq, 16, 64);
    float rs = 1.0f / fmaxf(sqrtf(sq), 1e-12f);
    float u0 = fmaxf(v0 * rs, 0.f), u1 = fmaxf(v1 * rs, 0.f);
    float u2 = fmaxf(v2 * rs, 0.f), u3 = fmaxf(v3 * rs, 0.f);
    if (LOWP) {
      uint2 ov;
      ov.x = (unsigned)f2bf(u0) | ((unsigned)f2bf(u1) << 16);
      ov.y = (unsigned)f2bf(u2) | ((unsigned)f2bf(u3) << 16);
      *(uint2*)(Ubf + (size_t)node * H + c) = ov;
    } else {
      float4 o = {u0, u1, u2, u3};
      *(float4*)(pio + (size_t)node * H + c) = o;
    }
    lcs[0] += u0; lcq[0] += u0 * u0;
    lcs[1] += u1; lcq[1] += u1 * u1;
    lcs[2] += u2; lcq[2] += u2 * u2;
    lcs[3] += u3; lcq[3] += u3 * u3;
  }

  #pragma unroll
  for (int q = 0; q < 4; ++q) {
    atomicAdd(&csm[c + q], lcs[q]);
    atomicAdd(&cqm[c + q], lcq[q]);
  }
  __syncthreads();
  if (t < 128) {
    atomicAdd(&colsum[t], csm[t]);
    atomicAdd(&colsq[t], cqm[t]);
  }
}

// ---------------------------------------------------------------------------
// CSR build (mid fallback path)
// ---------------------------------------------------------------------------
__global__ __launch_bounds__(256) void deg_count(const void* __restrict__ eiv,
                                                 const int* __restrict__ flag,
                                                 int* __restrict__ degi, int E) {
  int e = blockIdx.x * blockDim.x + threadIdx.x;
  if (e >= E) return;
  int dst = load_idx(eiv, *flag, (long long)E + e);
  atomicAdd(&degi[dst], 1);
}

__global__ __launch_bounds__(256) void scan3(int* __restrict__ offsets,
                                             const int* __restrict__ blockoff,
                                             int* __restrict__ cursor, int n, int E) {
  int idx = blockIdx.x * 256 + threadIdx.x;
  if (idx >= n) return;
  int off = offsets[idx] + blockoff[idx >> 8];
  offsets[idx] = off;
  cursor[idx] = off;
  if (idx == 0) offsets[n] = E;
}

__global__ __launch_bounds__(256) void bucket_fill(const void* __restrict__ eiv,
                                                   const int* __restrict__ flag,
                                                   int* __restrict__ cursor,
                                                   int* __restrict__ csr_src, int E) {
  int e = blockIdx.x * blockDim.x + threadIdx.x;
  if (e >= E) return;
  int is64 = *flag;
  int src = load_idx(eiv, is64, e);
  int dst = load_idx(eiv, is64, (long long)E + e);
  int pos = atomicAdd(&cursor[dst], 1);
  csr_src[pos] = src;
}

// ---------------------------------------------------------------------------
// prep_w standalone (fallback paths)
// ---------------------------------------------------------------------------
__global__ __launch_bounds__(256) void prep_w(const float* __restrict__ Wl,
                                              const float* __restrict__ Wr,
                                              unsigned short* __restrict__ Wcat) {
  int tid = blockIdx.x * 256 + threadIdx.x;
  if (tid >= 4 * 4 * 8 * 64) return;
  int lane = tid & 63;
  int nf   = (tid >> 6) & 7;
  int kc   = (tid >> 9) & 3;
  int part = tid >> 11;
  const float* W = (part < 2) ? Wl : Wr;
  bool lo = (part & 1);
  int ncol = nf * 16 + (lane & 15);
  int k0 = kc * 32 + (lane >> 4) * 8;
  unsigned short ov[8];
  #pragma unroll
  for (int j = 0; j < 8; ++j) {
    float v = W[(k0 + j) * H + ncol];
    unsigned short h = f2bf(v);
    ov[j] = lo ? f2bf(v - bf2f(h)) : h;
  }
  uint4 pack;
  pack.x = (unsigned)ov[0] | ((unsigned)ov[1] << 16);
  pack.y = (unsigned)ov[2] | ((unsigned)ov[3] << 16);
  pack.z = (unsigned)ov[4] | ((unsigned)ov[5] << 16);
  pack.w = (unsigned)ov[6] | ((unsigned)ov[7] << 16);
  *(uint4*)(Wcat + (size_t)tid * 8) = pack;
}

// ---------------------------------------------------------------------------
// Mid path: f32 gather + double MFMA gemm.
// ---------------------------------------------------------------------------
__global__ __launch_bounds__(256) void gather_mean(const float* __restrict__ x,
                                                   const int* __restrict__ offsets,
                                                   const int* __restrict__ csr_src,
                                                   float* __restrict__ out, int n) {
  int node = (int)(((long long)blockIdx.x * blockDim.x + threadIdx.x) >> 6);
  int lane = threadIdx.x & 63;
  if (node >= n) return;
  int s = offsets[node], e = offsets[node + 1];
  float ax = 0.0f, ay = 0.0f, bx = 0.0f, by = 0.0f;
  int j = s;
  for (; j + 1 < e; j += 2) {
    int s0 = csr_src[j], s1 = csr_src[j + 1];
    float2 v0 = *(const float2*)(x + (size_t)s0 * F + lane * 2);
    float2 v1 = *(const float2*)(x + (size_t)s1 * F + lane * 2);
    ax += v0.x; ay += v0.y;
    bx += v1.x; by += v1.y;
  }
  if (j < e) {
    int s0 = csr_src[j];
    float2 v0 = *(const float2*)(x + (size_t)s0 * F + lane * 2);
    ax += v0.x; ay += v0.y;
  }
  float inv = 1.0f / fmaxf((float)(e - s), 1.0f);
  float2 r; r.x = (ax + bx) * inv; r.y = (ay + by) * inv;
  *(float2*)(out + (size_t)node * H + lane * 2) = r;
}

__global__ __launch_bounds__(256) void mfma_gemm(
    const float* __restrict__ x, const unsigned short* __restrict__ Wcat,
    const float* __restrict__ bl, float* __restrict__ out,
    float* __restrict__ colsum, float* __restrict__ colsq, int n) {
  __shared__ unsigned short As[4][64][128];
  __shared__ float rowsq[64][4];
  __shared__ float rscale[64];

  const int t = threadIdx.x;
  const int i0 = blockIdx.x * 64;

  #pragma unroll
  for (int it = 0; it < 8; ++it) {
    int idx = it * 256 + t;
    int r = idx >> 5;
    int c4 = (idx & 31) * 4;
    int row_g = i0 + r; if (row_g >= n) row_g = n - 1;
    int boff = (((c4 >> 3) ^ (r & 7)) << 3) + (c4 & 7);
    float4 va = *(const float4*)(out + (size_t)row_g * H + c4);
    float4 vx = *(const float4*)(x + (size_t)row_g * H + c4);
    unsigned short h0 = f2bf(va.x), h1 = f2bf(va.y), h2 = f2bf(va.z), h3 = f2bf(va.w);
    uint2 hv = { (unsigned)h0 | ((unsigned)h1 << 16), (unsigned)h2 | ((unsigned)h3 << 16) };
    *(uint2*)&As[0][r][boff] = hv;
    unsigned short l0 = f2bf(va.x - bf2f(h0)), l1 = f2bf(va.y - bf2f(h1));
    unsigned short l2 = f2bf(va.z - bf2f(h2)), l3 = f2bf(va.w - bf2f(h3));
    uint2 lv = { (unsigned)l0 | ((unsigned)l1 << 16), (unsigned)l2 | ((unsigned)l3 << 16) };
    *(uint2*)&As[1][r][boff] = lv;
    h0 = f2bf(vx.x); h1 = f2bf(vx.y); h2 = f2bf(vx.z); h3 = f2bf(vx.w);
    uint2 hx = { (unsigned)h0 | ((unsigned)h1 << 16), (unsigned)h2 | ((unsigned)h3 << 16) };
    *(uint2*)&As[2][r][boff] = hx;
    l0 = f2bf(vx.x - bf2f(h0)); l1 = f2bf(vx.y - bf2f(h1));
    l2 = f2bf(vx.z - bf2f(h2)); l3 = f2bf(vx.w - bf2f(h3));
    uint2 lx = { (unsigned)l0 | ((unsigned)l1 << 16), (unsigned)l2 | ((unsigned)l3 << 16) };
    *(uint2*)&As[3][r][boff] = lx;
  }
  __syncthreads();

  const int w = t >> 6;
  const int lane = t & 63;

  f32x4 acc[4][2];
  #pragma unroll
  for (int rf = 0; rf < 4; ++rf)
    #pragma unroll
    for (int nfi = 0; nfi < 2; ++nfi)
      acc[rf][nfi] = (f32x4){0.f, 0.f, 0.f, 0.f};

  const int APM[6] = {0, 1, 0, 2, 3, 2};
  const int BPM[6] = {0, 0, 1, 2, 2, 3};

  #pragma unroll
  for (int pass = 0; pass < 6; ++pass) {
    const int ap = APM[pass], bp = BPM[pass];
    #pragma unroll
    for (int kc = 0; kc < 4; ++kc) {
      short8 bfr[2];
      #pragma unroll
      for (int nfi = 0; nfi < 2; ++nfi) {
        int blob = (bp * 4 + kc) * 8 + (w * 2 + nfi);
        bfr[nfi] = *(const short8*)(Wcat + (size_t)blob * 512 + lane * 8);
      }
      short8 afr[4];
      int chunk = kc * 4 + (lane >> 4);
      #pragma unroll
      for (int rf = 0; rf < 4; ++rf) {
        int row = rf * 16 + (lane & 15);
        afr[rf] = *(const short8*)(&As[ap][row][(chunk ^ (row & 7)) * 8]);
      }
      #pragma unroll
      for (int rf = 0; rf < 4; ++rf)
        #pragma unroll
        for (int nfi = 0; nfi < 2; ++nfi)
          acc[rf][nfi] = __builtin_amdgcn_mfma_f32_16x16x32_bf16(
              afr[rf], bfr[nfi], acc[rf][nfi], 0, 0, 0);
    }
  }

  const float b0 = bl[w * 32 + (lane & 15)];
  const float b1 = bl[w * 32 + 16 + (lane & 15)];

  #pragma unroll
  for (int rf = 0; rf < 4; ++rf) {
    #pragma unroll
    for (int r4 = 0; r4 < 4; ++r4) {
      float v0 = acc[rf][0][r4] + b0;
      float v1 = acc[rf][1][r4] + b1;
      acc[rf][0][r4] = v0;
      acc[rf][1][r4] = v1;
      float sq = v0 * v0 + v1 * v1;
      sq += __shfl_xor(sq, 1, 64);
      sq += __shfl_xor(sq, 2, 64);
      sq += __shfl_xor(sq, 4, 64);
      sq += __shfl_xor(sq, 8, 64);
      if ((lane & 15) == 0) rowsq[rf * 16 + (lane >> 4) * 4 + r4][w] = sq;
    }
  }
  __syncthreads();
  if (t < 64) {
    float s = rowsq[t][0] + rowsq[t][1] + rowsq[t][2] + rowsq[t][3];
    rscale[t] = 1.0f / fmaxf(sqrtf(s), 1e-12f);
  }
  __syncthreads();

  float cs0 = 0.f, cq0 = 0.f, cs1 = 0.f, cq1 = 0.f;
  #pragma unroll
  for (int rf = 0; rf < 4; ++rf) {
    #pragma unroll
    for (int r4 = 0; r4 < 4; ++r4) {
      int rl = rf * 16 + (lane >> 4) * 4 + r4;
      int row = i0 + rl;
      float s = rscale[rl];
      float u0 = fmaxf(acc[rf][0][r4] * s, 0.f);
      float u1 = fmaxf(acc[rf][1][r4] * s, 0.f);
      if (row < n) {
        out[(size_t)row * H + w * 32 + (lane & 15)] = u0;
        out[(size_t)row * H + w * 32 + 16 + (lane & 15)] = u1;
        cs0 += u0; cq0 += u0 * u0;
        cs1 += u1; cq1 += u1 * u1;
      }
    }
  }
  cs0 += __shfl_xor(cs0, 16, 64); cs0 += __shfl_xor(cs0, 32, 64);
  cq0 += __shfl_xor(cq0, 16, 64); cq0 += __shfl_xor(cq0, 32, 64);
  cs1 += __shfl_xor(cs1, 16, 64); cs1 += __shfl_xor(cs1, 32, 64);
  cq1 += __shfl_xor(cq1, 16, 64); cq1 += __shfl_xor(cq1, 32, 64);
  if (lane < 16) {
    atomicAdd(&colsum[w * 32 + lane], cs0);
    atomicAdd(&colsq[w * 32 + lane], cq0);
    atomicAdd(&colsum[w * 32 + 16 + lane], cs1);
    atomicAdd(&colsq[w * 32 + 16 + lane], cq1);
  }
}

// ---------------------------------------------------------------------------
// Fallback path (tiny ws): atomic scatter + divide + scalar fused gemm.
// ---------------------------------------------------------------------------
__global__ __launch_bounds__(256) void scatter_mean(
    const float* __restrict__ x, const void* __restrict__ eiv,
    const int* __restrict__ flag, float* __restrict__ agg,
    float* __restrict__ deg, int E) {
  long long gid = (long long)blockIdx.x * blockDim.x + threadIdx.x;
  int e = (int)(gid >> 5);
  int ch = (int)(gid & 31);
  if (e >= E) return;
  int is64 = *flag;
  int src = load_idx(eiv, is64, e);
  int dst = load_idx(eiv, is64, (long long)E + e);
  float4 v = *(const float4*)(x + (size_t)src * F + ch * 4);
  float* a = agg + (size_t)dst * H + ch * 4;
  atomicAdd(a + 0, v.x);
  atomicAdd(a + 1, v.y);
  atomicAdd(a + 2, v.z);
  atomicAdd(a + 3, v.w);
  if (ch == 0) atomicAdd(deg + dst, 1.0f);
}

__global__ __launch_bounds__(256) void divide_deg(float* __restrict__ out,
                                                  const float* __restrict__ deg,
                                                  long long n4) {
  long long i = (long long)blockIdx.x * blockDim.x + threadIdx.x;
  if (i >= n4) return;
  int node = (int)(i >> 5);
  float s = 1.0f / fmaxf(deg[node], 1.0f);
  float4 v = ((float4*)out)[i];
  v.x *= s; v.y *= s; v.z *= s; v.w *= s;
  ((float4*)out)[i] = v;
}

__global__ __launch_bounds__(256) void fused_gemm(
    const float* __restrict__ x, const float* __restrict__ Wl,
    const float* __restrict__ bl, const float* __restrict__ Wr,
    float* __restrict__ out, float* __restrict__ colsum, float* __restrict__ colsq) {
  __shared__ float As[16][256];
  __shared__ float rp[4][8];
  __shared__ float rscale[16];
  __shared__ float cs[128], cs2[128];

  const int t = threadIdx.x;
  const int i0 = blockIdx.x * 16;

  #pragma unroll
  for (int it = 0; it < 2; ++it) {
    int idx = (it * 256 + t) * 4;
    int r = idx >> 7, c = idx & 127;
    float4 va = *(const float4*)(out + (size_t)(i0 + r) * H + c);
    As[r][c + 0] = va.x; As[r][c + 1] = va.y;
    As[r][c + 2] = va.z; As[r][c + 3] = va.w;
    float4 vx = *(const float4*)(x + (size_t)(i0 + r) * F + c);
    As[r][128 + c + 0] = vx.x; As[r][128 + c + 1] = vx.y;
    As[r][128 + c + 2] = vx.z; As[r][128 + c + 3] = vx.w;
  }
  __syncthreads();

  const int c = t & 127;
  const int half = t >> 7;
  float acc[8];
  #pragma unroll
  for (int r = 0; r < 8; ++r) acc[r] = 0.0f;

  #pragma unroll 4
  for (int k = 0; k < 128; ++k) {
    float w = Wl[k * H + c];
    #pragma unroll
    for (int r = 0; r < 8; ++r) acc[r] = fmaf(As[half * 8 + r][k], w, acc[r]);
  }
  #pragma unroll 4
  for (int k = 0; k < 128; ++k) {
    float w = Wr[k * H + c];
    #pragma unroll
    for (int r = 0; r < 8; ++r) acc[r] = fmaf(As[half * 8 + r][128 + k], w, acc[r]);
  }
  const float bias = bl[c];
  #pragma unroll
  for (int r = 0; r < 8; ++r) acc[r] += bias;

  float sq[8];
  #pragma unroll
  for (int r = 0; r < 8; ++r) sq[r] = acc[r] * acc[r];
  #pragma unroll
  for (int off = 32; off > 0; off >>= 1) {
    #pragma unroll
    for (int r = 0; r < 8; ++r) sq[r] += __shfl_down(sq[r], off, 64);
  }
  const int wv = t >> 6;
  if ((t & 63) == 0) {
    #pragma unroll
    for (int r = 0; r < 8; ++r) rp[wv][r] = sq[r];
  }
  __syncthreads();
  if (t < 16) {
    int base = (t >> 3) * 2, rr = t & 7;
    float s = rp[base][rr] + rp[base + 1][rr];
    rscale[t] = 1.0f / fmaxf(sqrtf(s), 1e-12f);
  }
  __syncthreads();

  float csum = 0.0f, csq = 0.0f;
  #pragma unroll
  for (int r = 0; r < 8; ++r) {
    float v = fmaxf(acc[r] * rscale[half * 8 + r], 0.0f);
    out[(size_t)(i0 + half * 8 + r) * H + c] = v;
    csum += v;
    csq += v * v;
  }
  if (half == 1) { cs[c] = csum; cs2[c] = csq; }
  __syncthreads();
  if (half == 0) {
    atomicAdd(&colsum[c], csum + cs[c]);
    atomicAdd(&colsq[c], csq + cs2[c]);
  }
}

__global__ void bn_stats(const float* __restrict__ colsum, const float* __restrict__ colsq,
                         const float* __restrict__ gamma, const float* __restrict__ beta,
                         float* __restrict__ scale, float* __restrict__ shift, int n) {
  int c = threadIdx.x;
  if (c < H) {
    float inv_n = 1.0f / (float)n;
    float mean = colsum[c] * inv_n;
    float var = colsq[c] * inv_n - mean * mean;  // biased (torch BN)
    float istd = rsqrtf(var + 1e-5f);
    float sc = gamma[c] * istd;
    scale[c] = sc;
    shift[c] = beta[c] - mean * sc;
  }
}

__global__ __launch_bounds__(256) void bn_apply(
    float* __restrict__ out, const float* __restrict__ scale,
    const float* __restrict__ shift, long long n4) {
  long long i = (long long)blockIdx.x * blockDim.x + threadIdx.x;
  if (i >= n4) return;
  float4 v = ((float4*)out)[i];
  int c = (int)((i * 4) & (H - 1));
  v.x = fmaf(v.x, scale[c + 0], shift[c + 0]);
  v.y = fmaf(v.y, scale[c + 1], shift[c + 1]);
  v.z = fmaf(v.z, scale[c + 2], shift[c + 2]);
  v.w = fmaf(v.w, scale[c + 3], shift[c + 3]);
  ((float4*)out)[i] = v;
}

// reads pre-BN u (bf16 in ws), writes final f32 to out
__global__ __launch_bounds__(256) void bn_apply_lo(
    const unsigned short* __restrict__ U, float* __restrict__ out,
    const float* __restrict__ scale, const float* __restrict__ shift,
    long long n4) {
  long long i = (long long)blockIdx.x * blockDim.x + threadIdx.x;
  if (i >= n4) return;
  uint2 uv = ((const uint2*)U)[i];
  int c = (int)((i * 4) & (H - 1));
  float4 v;
  v.x = fmaf(bits2f(uv.x << 16),          scale[c + 0], shift[c + 0]);
  v.y = fmaf(bits2f(uv.x & 0xFFFF0000u),  scale[c + 1], shift[c + 1]);
  v.z = fmaf(bits2f(uv.y << 16),          scale[c + 2], shift[c + 2]);
  v.w = fmaf(bits2f(uv.y & 0xFFFF0000u),  scale[c + 3], shift[c + 3]);
  ((float4*)out)[i] = v;
}

extern "C" void kernel_launch(void* const* d_in, const int* in_sizes, int n_in,
                              void* d_out, int out_size, void* d_ws, size_t ws_size,
                              hipStream_t stream) {
  const float* x     = (const float*)d_in[0];
  const void*  ei    = d_in[1];
  const float* Wl    = (const float*)d_in[2];
  const float* bl    = (const float*)d_in[3];
  const float* Wr    = (const float*)d_in[4];
  const float* gamma = (const float*)d_in[5];
  const float* beta  = (const float*)d_in[6];
  float* out = (float*)d_out;

  const int n = in_sizes[0] / F;   // 100000
  const int E = in_sizes[1] / 2;   // 1600000
  const int nb = (n + 255) / 256;
  const int nbuck = (n + 63) >> 6; // 64-node buckets

  char* ws = (char*)d_ws;
  int* flag = (int*)ws;
  unsigned short* Wcat = (unsigned short*)(ws + 256);
  char* after_w = ws + 256 + 4 * 128 * 128 * 2;

  // ---- fast-path layout: partition + Y fp8 (+P,U bf16) ----
  int*   cmat    = (int*)after_w;
  int*   obuf    = cmat + 2048 * NPART;
  int*   bsum    = obuf + 2048 * NPART;
  int*   boff    = bsum + 1024;
  int*   bbase   = boff + 1024;
  float* fcs     = (float*)(bbase + 2049);
  float* fcq     = fcs + H;
  float* fsc     = fcq + H;
  float* fsh     = fsc + H;
  int*   ebuf    = (int*)(fsh + H);
  unsigned char*  Yf8 = (unsigned char*)(ebuf + E);
  unsigned short* Pws = (unsigned short*)(Yf8 + (size_t)n * H);
  unsigned short* Uws = Pws + (size_t)n * H;
  size_t need_fast  = (size_t)((char*)(Yf8 + (size_t)n * H) - ws);
  size_t need_fast2 = (size_t)((char*)(Uws + (size_t)n * H) - ws);

  // ---- mid-path layout: CSR ----
  int*   degi     = (int*)after_w;
  int*   offsets  = degi + n;
  int*   cursor   = offsets + n + 1;
  int*   blocksum = cursor + n;
  int*   blockoff = blocksum + nb;
  float* mcs      = (float*)(blockoff + nb);
  float* mcq      = mcs + H;
  float* msc      = mcq + H;
  float* msh      = msc + H;
  int*   csr_src  = (int*)(msh + H);
  size_t need_mid = (size_t)((char*)(csr_src + E) - ws);

  float *colsum, *colsq, *scale, *shift;

  const int eb = (E + 255) / 256;
  const int gb = (n + 63) / 64;
  const long long n4 = (long long)n * H / 4;

  if (ws_size >= need_fast && nbuck <= 2048) {
    const bool lowp = (ws_size >= need_fast2);
    colsum = fcs; colsq = fcq; scale = fsc; shift = fsh;

    const int chunk = (E + NPART - 1) / NPART;
    const int L = nbuck * NPART;
    const int nb2 = (L + 255) / 256;   // <= 1024

    // 1) hist || prep_w  (independent)
    union_hist_prep<<<NPART + 32, 256, 0, stream>>>(
        ei, cmat, E, nbuck, chunk, Wl, Wr, Wcat);

    // 2) hierarchical scan of cmat -> bases (+ zero col stats)
    scan1<<<nb2, 256, 0, stream>>>(cmat, obuf, bsum, L);
    scan2big<<<1, 1024, 0, stream>>>(bsum, boff, nb2);
    scan3p<<<nb2, 256, 0, stream>>>(obuf, boff, bbase, colsum, L, nbuck, E);

    // 3) part_scatter || dual_gemm  (independent)
    if (lowp)
      union_scatter_gemm<true><<<NPART + gb, 256, 0, stream>>>(
          ei, obuf, ebuf, E, nbuck, chunk, x, Wcat, bl, Yf8, out, Pws, n);
    else
      union_scatter_gemm<false><<<NPART + gb, 256, 0, stream>>>(
          ei, obuf, ebuf, E, nbuck, chunk, x, Wcat, bl, Yf8, out, Pws, n);

    // 4) gather + fused epilogue
    if (lowp)
      gather_bucket<true><<<nbuck, 256, 0, stream>>>(
          Yf8, ebuf, bbase, out, Pws, Uws, colsum, colsq, n);
    else
      gather_bucket<false><<<nbuck, 256, 0, stream>>>(
          Yf8, ebuf, bbase, out, Pws, Uws, colsum, colsq, n);

    // 5) BN
    bn_stats<<<1, 128, 0, stream>>>(colsum, colsq, gamma, beta, scale, shift, n);
    if (lowp)
      bn_apply_lo<<<(int)((n4 + 255) / 256), 256, 0, stream>>>(
          Uws, out, scale, shift, n4);
    else
      bn_apply<<<(int)((n4 + 255) / 256), 256, 0, stream>>>(out, scale, shift, n4);
  } else if (ws_size >= need_mid) {
    colsum = mcs; colsq = mcq; scale = msc; shift = msh;
    detect_dtype<<<1, 64, 0, stream>>>((const unsigned*)ei, flag);
    hipMemsetAsync(degi, 0, (size_t)n * 4, stream);
    hipMemsetAsync(colsum, 0, 2 * H * 4, stream);

    prep_w<<<32, 256, 0, stream>>>(Wl, Wr, Wcat);

    deg_count<<<eb, 256, 0, stream>>>(ei, flag, degi, E);
    scan1<<<nb, 256, 0, stream>>>(degi, offsets, blocksum, n);
    scan2big<<<1, 1024, 0, stream>>>(blocksum, blockoff, nb);
    scan3<<<nb, 256, 0, stream>>>(offsets, blockoff, cursor, n, E);
    bucket_fill<<<eb, 256, 0, stream>>>(ei, flag, cursor, csr_src, E);

    long long gthreads = (long long)n * 64;
    gather_mean<<<(int)((gthreads + 255) / 256), 256, 0, stream>>>(
        x, offsets, csr_src, out, n);

    mfma_gemm<<<gb, 256, 0, stream>>>(x, Wcat, bl, out, colsum, colsq, n);
    bn_stats<<<1, 128, 0, stream>>>(colsum, colsq, gamma, beta, scale, shift, n);
    bn_apply<<<(int)((n4 + 255) / 256), 256, 0, stream>>>(out, scale, shift, n4);
  } else {
    float* deg = (float*)(ws + 256);
    colsum = deg + n; colsq = colsum + H; scale = colsq + H; shift = scale + H;
    detect_dtype<<<1, 64, 0, stream>>>((const unsigned*)ei, flag);
    hipMemsetAsync(d_out, 0, (size_t)out_size * sizeof(float), stream);
    hipMemsetAsync(deg, 0, (size_t)n * 4 + 4 * H * 4, stream);
    long long sthreads = (long long)E * 32;
    scatter_mean<<<(int)((sthreads + 255) / 256), 256, 0, stream>>>(x, ei, flag, out, deg, E);
    long long n4f = (long long)n * H / 4;
    divide_deg<<<(int)((n4f + 255) / 256), 256, 0, stream>>>(out, deg, n4f);
    fused_gemm<<<n / 16, 256, 0, stream>>>(x, Wl, bl, Wr, out, colsum, colsq);
    bn_stats<<<1, 128, 0, stream>>>(colsum, colsq, gamma, beta, scale, shift, n);
    bn_apply<<<(int)((n4 + 255) / 256), 256, 0, stream>>>(out, scale, shift, n4);
  }
}